// Round 6
// baseline (1474.666 us; speedup 1.0000x reference)
//
#include <hip/hip_runtime.h>
#include <hip/hip_bf16.h>
#include <math.h>

// Problem constants
#define B_    64
#define T_    13
#define N_    325
#define H_    64
#define C_    4
#define L_    2
#define S_    4
#define P_    12
#define KCP   4            // checkpoints [4,7,10,13]
#define M_    (B_*N_)      // 20800
#define ADJLD 1300         // leading dim of combined adjacency inputs
#define NH_   (N_*H_)      // 20800
#define NNZCAP 64          // max nonzeros per adjacency row (3% density -> mean ~10)
#define WP    80           // ushort pitch for bf16 fragment tiles (16B aligned, 2-way banks)

typedef __attribute__((ext_vector_type(8))) short bfrag;    // 8 bf16 = 4 VGPRs
typedef __attribute__((ext_vector_type(4))) float f32x4;

#define FMA16 \
  acc[0][0]+=a0*b0; acc[0][1]+=a0*b1; acc[0][2]+=a0*b2; acc[0][3]+=a0*b3; \
  acc[1][0]+=a1*b0; acc[1][1]+=a1*b1; acc[1][2]+=a1*b2; acc[1][3]+=a1*b3; \
  acc[2][0]+=a2*b0; acc[2][1]+=a2*b1; acc[2][2]+=a2*b2; acc[2][3]+=a2*b3; \
  acc[3][0]+=a3*b0; acc[3][1]+=a3*b1; acc[3][2]+=a3*b2; acc[3][3]+=a3*b3;

// round-to-nearest-even fp32 -> bf16 (bits)
__device__ __forceinline__ ushort bf_rne(float f) {
    unsigned u = __float_as_uint(f);
    return (ushort)((u + 0x7FFFu + ((u >> 16) & 1u)) >> 16);
}
__device__ __forceinline__ void bf_split(float f, ushort& hi, ushort& lo) {
    unsigned u = __float_as_uint(f);
    unsigned h = (u + 0x7FFFu + ((u >> 16) & 1u)) >> 16;
    hi = (ushort)h;
    float fh = __uint_as_float(h << 16);
    lo = bf_rne(f - fh);
}

// ---------------------------------------------------------------------------
// Build padded sparse rows (column-ordered, deterministic) from the 325x325
// top-left block of a combined adjacency. One wave per row.
__global__ void k_build_sparse(const float* __restrict__ A,
                               int* __restrict__ cnt, int* __restrict__ cols,
                               float* __restrict__ vals) {
    int n    = blockIdx.x;       // row
    int lane = threadIdx.x;      // 0..63
    const float* row = A + (size_t)n * ADJLD;
    int c = 0;
    for (int c0 = 0; c0 < 384; c0 += 64) {
        int col = c0 + lane;
        float v = (col < N_) ? row[col] : 0.f;
        unsigned long long m = __ballot(v != 0.f);
        int idx = c + __popcll(m & ((1ull << lane) - 1ull));
        if (v != 0.f && idx < NNZCAP) {
            cols[n * NNZCAP + idx] = col;
            vals[n * NNZCAP + idx] = v;
        }
        c += __popcll(m);
    }
    if (c + lane < NNZCAP) {                 // zero-pad tail -> branch-free consumers
        cols[n * NNZCAP + c + lane] = 0;
        vals[n * NNZCAP + c + lane] = 0.f;
    }
    if (lane == 0) cnt[n] = (c < NNZCAP) ? c : NNZCAP;
}

// ---------------------------------------------------------------------------
// Precompute W01 = W[.,l,0]+W[.,l,1], transposed [h][k], split hi/lo bf16,
// pitch WP. 16 matrices: mat = stack*8 + c*2 + layer.
__global__ void k_prep_w(const float* __restrict__ gadj_w,
                         const float* __restrict__ gpea_w,
                         ushort* __restrict__ WTH, ushort* __restrict__ WTL) {
    int mat = blockIdx.x;
    int s = mat >> 3, c = (mat >> 1) & 3, l = mat & 1;
    const float* w0 = (s ? gpea_w : gadj_w) + (size_t)((c * L_ + l) * 2) * H_ * H_;
    const float* w1 = w0 + H_ * H_;
    ushort* oh = WTH + (size_t)mat * H_ * WP;
    ushort* ol = WTL + (size_t)mat * H_ * WP;
    for (int i = 0; i < 16; ++i) {
        int e = threadIdx.x + i * 256;       // e = k*64 + h
        int k = e >> 6, h = e & 63;
        ushort hi, lo;
        bf_split(w0[e] + w1[e], hi, lo);
        oh[h * WP + k] = hi;
        ol[h * WP + k] = lo;
    }
}

// ---------------------------------------------------------------------------
// K1: gf / residual / g_init in one pass.
__global__ void k_gf_res(const float* __restrict__ inp,
                         const float* __restrict__ w_in, const float* __restrict__ b_in,
                         const float* __restrict__ gconv_w, const float* __restrict__ gconv_b,
                         const float* __restrict__ res_w,   const float* __restrict__ res_b,
                         const float* __restrict__ last, int it,
                         float* __restrict__ gf, float* __restrict__ residual,
                         float* __restrict__ g_init) {
    int idx = blockIdx.x * 256 + threadIdx.x;   // over M_*H_
    if (idx >= M_ * H_) return;
    int h = idx & 63;
    int m = idx >> 6;
    int b = m / N_, n = m % N_;
    float wa = w_in[h], wb = w_in[H_ + h], bi = b_in[h];
    float gacc = gconv_b[0], racc = res_b[0];
    int left = (it == 0) ? 0 : (3 * it + 1);
    #pragma unroll
    for (int s = 0; s < 4; ++s) {
        float v;
        if (it > 0 && s == 0) {
            v = last[idx];
        } else {
            int tt = (it == 0) ? s : (left + s - 1);
            const float* ip = inp + ((size_t)(b * T_ + tt) * N_ + n) * 2;
            v = ip[0] * wa + ip[1] * wb + bi;
        }
        gacc += gconv_w[s] * v;
        racc += res_w[s] * v;
        if (s == 3) g_init[idx] = v;           // t = 3*it+3
    }
    gf[idx] = gacc;
    residual[idx] = racc;
}

// ---------------------------------------------------------------------------
// Unified GCN layer kernel (bf16x2-split MFMA).
//   v = relu((A_sparse @ IN) @ W01 + bias)   for one (batch, c, 64-row tile)
// MODE 0: layer 0, IN = g_init [M][64]   -> G1[m][c*64+h] = v
// MODE 1: layer 1 adj, IN = G1 [M][256]  -> gr[m][c*64+h] = gate * v
// MODE 2: layer 1 pea, IN = G1 [M][256]  -> gr[m][c*64+h] += (1-gate) * v
// Grid: 1536 blocks (xcd-swizzled (rowtile 6, b 64, c 4)); 256 threads.
template<int MODE>
__global__ __launch_bounds__(256, 3) void k_gcn(
    const int*   __restrict__ cnt,
    const int*   __restrict__ cols,
    const float* __restrict__ vals,
    const float* __restrict__ IN,
    const ushort* __restrict__ WTHg, const ushort* __restrict__ WTLg,
    const float* __restrict__ bbase,   // gcn_*_b [C][L][H]
    const float* __restrict__ gate,    // [M][256] (MODE 1/2)
    float* __restrict__ outp,          // G1 or gr, [M][256]
    int stack)
{
    __shared__ ushort WTHs[64 * WP];   // 10.24 KB each -> 41 KB total
    __shared__ ushort WTLs[64 * WP];
    __shared__ ushort MtH[64 * WP];
    __shared__ ushort MtL[64 * WP];

    const int layer = (MODE == 0) ? 0 : 1;
    int t = threadIdx.x, lane = t & 63, w = t >> 6;

    // XCD-aware decode: same-batch blocks co-locate on one XCD (lid%8 heuristic)
    int lid  = blockIdx.x;
    int xcd  = lid & 7;
    int slot = lid >> 3;                 // 0..191
    int b    = xcd + 8 * (slot / 24);
    int rem  = slot % 24;
    int c    = rem / 6;
    int rt   = rem % 6;                  // 64-row tile within batch

    // stage pre-split transposed W (coalesced copy)
    {
        int mat = stack * 8 + c * 2 + layer;
        const uint4* sh = (const uint4*)(WTHg + (size_t)mat * 64 * WP);
        const uint4* sl = (const uint4*)(WTLg + (size_t)mat * 64 * WP);
        uint4* dh = (uint4*)WTHs;
        uint4* dl = (uint4*)WTLs;
        for (int i = t; i < 64 * WP / 8; i += 256) { dh[i] = sh[i]; dl[i] = sl[i]; }
    }

    // ---- gather phase: wave w owns Mt rows w*16..w*16+15 (wave-private) ----
    const size_t base = (size_t)b * N_;
    for (int pp = 0; pp < 16; pp += 2) {
        int n0 = rt * 64 + w * 16 + pp;
        int n1 = n0 + 1;
        bool ok0 = n0 < N_, ok1 = n1 < N_;
        int nn0 = ok0 ? n0 : 0, nn1 = ok1 ? n1 : 0;
        const int   *c0p = cols + nn0 * NNZCAP, *c1p = cols + nn1 * NNZCAP;
        const float *v0p = vals + nn0 * NNZCAP, *v1p = vals + nn1 * NNZCAP;
        int jm = max(cnt[nn0], cnt[nn1]);
        float a0 = 0.f, a1 = 0.f;
        if (MODE == 0) {
            for (int j = 0; j < jm; j += 2) {
                a0 += v0p[j]   * IN[(base + c0p[j])   * H_ + lane]
                    + v0p[j+1] * IN[(base + c0p[j+1]) * H_ + lane];
                a1 += v1p[j]   * IN[(base + c1p[j])   * H_ + lane]
                    + v1p[j+1] * IN[(base + c1p[j+1]) * H_ + lane];
            }
        } else {
            const int co = c * 64 + lane;
            for (int j = 0; j < jm; j += 2) {
                a0 += v0p[j]   * IN[(base + c0p[j])   * 256 + co]
                    + v0p[j+1] * IN[(base + c0p[j+1]) * 256 + co];
                a1 += v1p[j]   * IN[(base + c1p[j])   * 256 + co]
                    + v1p[j+1] * IN[(base + c1p[j+1]) * 256 + co];
            }
        }
        if (!ok0) a0 = 0.f;
        if (!ok1) a1 = 0.f;
        ushort h0, l0, h1, l1;
        bf_split(a0, h0, l0);
        bf_split(a1, h1, l1);
        int r0 = (w * 16 + pp) * WP + lane;
        MtH[r0] = h0;  MtL[r0] = l0;
        MtH[r0 + WP] = h1;  MtL[r0 + WP] = l1;
    }

    __syncthreads();   // WT staging visible to all (Mt is wave-private)

    // ---- MFMA phase: 16x16x32 bf16, 2 k-blocks, 3 split terms ----
    int ml = lane & 15, q = lane >> 4;
    int arow = (w * 16 + ml) * WP + q * 8;
    bfrag AH0 = *(const bfrag*)&MtH[arow];
    bfrag AH1 = *(const bfrag*)&MtH[arow + 32];
    bfrag AL0 = *(const bfrag*)&MtL[arow];
    bfrag AL1 = *(const bfrag*)&MtL[arow + 32];
    const float* bias = bbase + (c * L_ + layer) * H_;

    for (int ct = 0; ct < 4; ++ct) {
        int brow = (ct * 16 + ml) * WP + q * 8;
        bfrag BH0 = *(const bfrag*)&WTHs[brow];
        bfrag BH1 = *(const bfrag*)&WTHs[brow + 32];
        bfrag BL0 = *(const bfrag*)&WTLs[brow];
        bfrag BL1 = *(const bfrag*)&WTLs[brow + 32];
        f32x4 acc = {0.f, 0.f, 0.f, 0.f};
        acc = __builtin_amdgcn_mfma_f32_16x16x32_bf16(AH0, BH0, acc, 0, 0, 0);
        acc = __builtin_amdgcn_mfma_f32_16x16x32_bf16(AH1, BH1, acc, 0, 0, 0);
        acc = __builtin_amdgcn_mfma_f32_16x16x32_bf16(AL0, BH0, acc, 0, 0, 0);
        acc = __builtin_amdgcn_mfma_f32_16x16x32_bf16(AL1, BH1, acc, 0, 0, 0);
        acc = __builtin_amdgcn_mfma_f32_16x16x32_bf16(AH0, BL0, acc, 0, 0, 0);
        acc = __builtin_amdgcn_mfma_f32_16x16x32_bf16(AH1, BL1, acc, 0, 0, 0);

        int colg = ct * 16 + ml;
        float bv = bias[colg];
        #pragma unroll
        for (int r = 0; r < 4; ++r) {
            int row = rt * 64 + w * 16 + q * 4 + r;   // C/D: row=(lane>>4)*4+reg
            if (row < N_) {
                float vv = acc[r] + bv;
                vv = vv > 0.f ? vv : 0.f;
                size_t o = (base + row) * 256 + c * 64 + colg;
                if (MODE == 0)      outp[o] = vv;
                else if (MODE == 1) outp[o] = gate[o] * vv;
                else { float g4 = gate[o]; outp[o] += (1.f - g4) * vv; }
            }
        }
    }
}

// ---------------------------------------------------------------------------
// K5: fused gate MLP: gate = sigmoid(relu(gf@W1 + b1) @ W2 + b2), grelu in LDS
__global__ __launch_bounds__(256, 3) void k_gate12(
    const float* __restrict__ gf,
    const float* __restrict__ W1, const float* __restrict__ b1,
    const float* __restrict__ W2, const float* __restrict__ b2,
    float* __restrict__ gate)
{
    __shared__ float Gf[64 * 68];
    __shared__ float Ws[64 * 68];
    __shared__ float Gr[64 * 68];
    int t = threadIdx.x, tx = t & 15, ty = t >> 4;
    int m0 = blockIdx.x * 64;
    #pragma unroll
    for (int i = 0; i < 4; ++i) {
        int f4 = t + i * 256;
        int row = f4 >> 4, col = (f4 & 15) * 4;
        *(float4*)&Gf[row * 68 + col] = *(const float4*)&gf[(size_t)(m0 + row) * 64 + col];
        *(float4*)&Ws[row * 68 + col] = *(const float4*)&W1[row * 64 + col];
    }
    __syncthreads();
    float acc[4][4];
    #pragma unroll
    for (int i = 0; i < 4; ++i)
        #pragma unroll
        for (int j = 0; j < 4; ++j) acc[i][j] = 0.f;
    #pragma unroll 16
    for (int k = 0; k < 64; ++k) {
        float a0 = Gf[ty * 68 + k];
        float a1 = Gf[(ty + 16) * 68 + k];
        float a2 = Gf[(ty + 32) * 68 + k];
        float a3 = Gf[(ty + 48) * 68 + k];
        float4 wv = *(const float4*)&Ws[k * 68 + 4 * tx];
        float b0 = wv.x, b1v = wv.y, b2v = wv.z, b3 = wv.w;
        { float b1 = b1v, b2 = b2v; FMA16 }
    }
    float4 bi1 = *(const float4*)&b1[4 * tx];
    #pragma unroll
    for (int i = 0; i < 4; ++i) {
        float v0 = acc[i][0] + bi1.x; v0 = v0 > 0.f ? v0 : 0.f;
        float v1 = acc[i][1] + bi1.y; v1 = v1 > 0.f ? v1 : 0.f;
        float v2 = acc[i][2] + bi1.z; v2 = v2 > 0.f ? v2 : 0.f;
        float v3 = acc[i][3] + bi1.w; v3 = v3 > 0.f ? v3 : 0.f;
        *(float4*)&Gr[(ty + 16 * i) * 68 + 4 * tx] = make_float4(v0, v1, v2, v3);
    }
    for (int ch = 0; ch < 4; ++ch) {
        __syncthreads();
        #pragma unroll
        for (int i = 0; i < 4; ++i) {
            int f4 = t + i * 256;
            int row = f4 >> 4, col = (f4 & 15) * 4;
            *(float4*)&Ws[row * 68 + col] =
                *(const float4*)&W2[(size_t)row * 256 + ch * 64 + col];
        }
        __syncthreads();
        float acc2[4][4];
        #pragma unroll
        for (int i = 0; i < 4; ++i)
            #pragma unroll
            for (int j = 0; j < 4; ++j) acc2[i][j] = 0.f;
        #pragma unroll 16
        for (int k = 0; k < 64; ++k) {
            float a0 = Gr[ty * 68 + k];
            float a1 = Gr[(ty + 16) * 68 + k];
            float a2 = Gr[(ty + 32) * 68 + k];
            float a3 = Gr[(ty + 48) * 68 + k];
            float4 wv = *(const float4*)&Ws[k * 68 + 4 * tx];
            float b0 = wv.x, b1v = wv.y, b2v = wv.z, b3 = wv.w;
            { float b1 = b1v, b2 = b2v; float (*acc)[4] = acc2; FMA16 }
        }
        float4 bi2 = *(const float4*)&b2[ch * 64 + 4 * tx];
        #pragma unroll
        for (int i = 0; i < 4; ++i) {
            int m = m0 + ty + 16 * i;
            float g0 = 1.f / (1.f + expf(-(acc2[i][0] + bi2.x)));
            float g1 = 1.f / (1.f + expf(-(acc2[i][1] + bi2.y)));
            float g2 = 1.f / (1.f + expf(-(acc2[i][2] + bi2.z)));
            float g3 = 1.f / (1.f + expf(-(acc2[i][3] + bi2.w)));
            *(float4*)&gate[(size_t)m * 256 + ch * 64 + 4 * tx] = make_float4(g0, g1, g2, g3);
        }
    }
}

// ---------------------------------------------------------------------------
// K6: cr = gr @ reduce_w + reduce_b + residual, with fused partial sums
__global__ __launch_bounds__(256) void k_reduce(const float* __restrict__ in,
                                                const float* __restrict__ W,
                                                const float* __restrict__ bias,
                                                const float* __restrict__ residual,
                                                float* __restrict__ cr,
                                                float* __restrict__ partials) {
    __shared__ float Is[64][17];
    __shared__ float Ws[16][65];
    __shared__ float r1[256], r2[256];
    int t = threadIdx.x, tx = t & 15, ty = t >> 4;
    int m0 = blockIdx.x * 64;
    float acc[4][4];
    #pragma unroll
    for (int i = 0; i < 4; ++i)
        #pragma unroll
        for (int j = 0; j < 4; ++j) acc[i][j] = 0.f;
    for (int kk = 0; kk < 256; kk += 16) {
        #pragma unroll
        for (int i = 0; i < 4; ++i) { int e = t + i*256; int r = e>>4, kc = e&15;
            Is[r][kc] = in[(size_t)(m0 + r) * 256 + kk + kc]; }
        #pragma unroll
        for (int i = 0; i < 4; ++i) { int e = t + i*256; int r = e>>6, cc = e&63;
            Ws[r][cc] = W[(size_t)(kk + r) * 64 + cc]; }
        __syncthreads();
        #pragma unroll
        for (int k = 0; k < 16; ++k) {
            float a0 = Is[ty][k], a1 = Is[ty+16][k], a2 = Is[ty+32][k], a3 = Is[ty+48][k];
            float b0 = Ws[k][tx], b1 = Ws[k][tx+16], b2 = Ws[k][tx+32], b3 = Ws[k][tx+48];
            FMA16
        }
        __syncthreads();
    }
    float s = 0.f, s2 = 0.f;
    #pragma unroll
    for (int i = 0; i < 4; ++i) {
        int r = m0 + ty + 16 * i;
        #pragma unroll
        for (int j = 0; j < 4; ++j) {
            int cc = tx + 16 * j;
            float v = acc[i][j] + bias[cc] + residual[(size_t)r * 64 + cc];
            cr[(size_t)r * 64 + cc] = v;
            s += v; s2 += v * v;
        }
    }
    r1[t] = s; r2[t] = s2;
    __syncthreads();
    for (int off = 128; off > 0; off >>= 1) {
        if (t < off) { r1[t] += r1[t + off]; r2[t] += r2[t + off]; }
        __syncthreads();
    }
    if (t == 0) { partials[blockIdx.x] = r1[0]; partials[325 + blockIdx.x] = r2[0]; }
}

// K7: finalize mu/var (redundantly per block) + normalize (grid 325)
__global__ void k_norm(const float* __restrict__ cr, const float* __restrict__ partials,
                       float* __restrict__ last) {
    __shared__ float s1[256], s2[256];
    int t = threadIdx.x;
    float a = 0.f, b = 0.f;
    for (int i = t; i < 325; i += 256) { a += partials[i]; b += partials[325 + i]; }
    s1[t] = a; s2[t] = b;
    __syncthreads();
    for (int off = 128; off > 0; off >>= 1) {
        if (t < off) { s1[t] += s1[t + off]; s2[t] += s2[t + off]; }
        __syncthreads();
    }
    const float inv = 1.f / (float)(M_ * H_);
    float mu  = s1[0] * inv;
    float var = s2[0] * inv - mu * mu;
    float rs  = rsqrtf(var + 1e-5f);
    int base = blockIdx.x * 4096 + t * 4;
    #pragma unroll
    for (int i = 0; i < 4; ++i) {
        float4 v = *(const float4*)&cr[base + i * 1024];
        *(float4*)&last[base + i * 1024] =
            make_float4((v.x - mu) * rs, (v.y - mu) * rs, (v.z - mu) * rs, (v.w - mu) * rs);
    }
}

// ---------------------------------------------------------------------------
// K8: out[b,p,n] = sum_h relu(ocw[p]*last[b,n,h] + ocb[p]) * olw[h] + olb
__global__ void k_out(const float* __restrict__ last,
                      const float* __restrict__ ocw, const float* __restrict__ ocb,
                      const float* __restrict__ olw, const float* __restrict__ olb,
                      float* __restrict__ out) {
    int m = blockIdx.x * 256 + threadIdx.x;   // b*N + n
    if (m >= M_) return;
    int b = m / N_, n = m % N_;
    float cw[P_], cb[P_], acc[P_];
    #pragma unroll
    for (int p = 0; p < P_; ++p) { cw[p] = ocw[p]; cb[p] = ocb[p]; acc[p] = 0.f; }
    const float* lr = last + (size_t)m * H_;
    for (int h = 0; h < H_; ++h) {
        float lv = lr[h], wv = olw[h];
        #pragma unroll
        for (int p = 0; p < P_; ++p) {
            float u = cw[p] * lv + cb[p];
            u = u > 0.f ? u : 0.f;
            acc[p] += u * wv;
        }
    }
    float ob = olb[0];
    #pragma unroll
    for (int p = 0; p < P_; ++p)
        out[(size_t)(b * P_ + p) * N_ + n] = acc[p] + ob;
}

// ---------------------------------------------------------------------------
extern "C" void kernel_launch(void* const* d_in, const int* in_sizes, int n_in,
                              void* d_out, int out_size, void* d_ws, size_t ws_size,
                              hipStream_t stream) {
    const float* inp      = (const float*)d_in[0];
    const float* adj_fwd  = (const float*)d_in[1];
    const float* pea_fwd  = (const float*)d_in[3];
    const float* w_in     = (const float*)d_in[5];
    const float* b_in     = (const float*)d_in[6];
    const float* res_w    = (const float*)d_in[7];
    const float* res_b    = (const float*)d_in[8];
    const float* gconv_w  = (const float*)d_in[9];
    const float* gconv_b  = (const float*)d_in[10];
    const float* gate1_w  = (const float*)d_in[11];
    const float* gate1_b  = (const float*)d_in[12];
    const float* gate2_w  = (const float*)d_in[13];
    const float* gate2_b  = (const float*)d_in[14];
    const float* reduce_w = (const float*)d_in[15];
    const float* reduce_b = (const float*)d_in[16];
    const float* gadj_w   = (const float*)d_in[17];
    const float* gadj_b   = (const float*)d_in[18];
    const float* gpea_w   = (const float*)d_in[19];
    const float* gpea_b   = (const float*)d_in[20];
    const float* ocw      = (const float*)d_in[21];
    const float* ocb      = (const float*)d_in[22];
    const float* olw      = (const float*)d_in[23];
    const float* olb      = (const float*)d_in[24];
    float* out = (float*)d_out;

    // workspace layout — pre-split W first (16B aligned), then fp32 buffers
    ushort* WTH = (ushort*)d_ws;                       // 16*64*80 = 81920 ushorts
    ushort* WTL = WTH + 16 * 64 * WP;                  // total 327,680 B
    float* g_init   = (float*)((char*)d_ws + 16 * 64 * WP * 2 * sizeof(ushort));
    float* G1       = g_init + (size_t)M_ * H_;        // M*256
    float* gate     = G1 + (size_t)M_ * 256;           // M*256
    float* gr       = gate + (size_t)M_ * 256;         // M*256
    float* gf       = gr + (size_t)M_ * 256;           // M*H (aliases cr)
    float* cr       = gf;
    float* residual = gf + (size_t)M_ * H_;            // M*H
    float* last     = residual + (size_t)M_ * H_;      // M*H
    float* partials = last + (size_t)M_ * H_;          // 650
    int*   scnt  = (int*)(partials + 650);             // 2*325
    int*   scols = scnt + 2 * N_;                      // 2*325*64
    float* svals = (float*)(scols + 2 * N_ * NNZCAP);  // 2*325*64

    k_build_sparse<<<N_, 64, 0, stream>>>(adj_fwd, scnt,      scols,              svals);
    k_build_sparse<<<N_, 64, 0, stream>>>(pea_fwd, scnt + N_, scols + N_*NNZCAP,  svals + N_*NNZCAP);
    k_prep_w<<<16, 256, 0, stream>>>(gadj_w, gpea_w, WTH, WTL);

    const int GBLK = 6 * B_ * C_;   // 1536
    for (int it = 0; it < KCP; ++it) {
        k_gf_res<<<(M_ * H_ + 255) / 256, 256, 0, stream>>>(
            inp, w_in, b_in, gconv_w, gconv_b, res_w, res_b, last, it, gf, residual, g_init);
        k_gate12<<<M_ / 64, 256, 0, stream>>>(gf, gate1_w, gate1_b, gate2_w, gate2_b, gate);

        // stack 0: adj
        k_gcn<0><<<GBLK, 256, 0, stream>>>(scnt, scols, svals, g_init,
                                           WTH, WTL, gadj_b, nullptr, G1, 0);
        k_gcn<1><<<GBLK, 256, 0, stream>>>(scnt, scols, svals, G1,
                                           WTH, WTL, gadj_b, gate, gr, 0);
        // stack 1: pea
        k_gcn<0><<<GBLK, 256, 0, stream>>>(scnt + N_, scols + N_*NNZCAP, svals + N_*NNZCAP,
                                           g_init, WTH, WTL, gpea_b, nullptr, G1, 1);
        k_gcn<2><<<GBLK, 256, 0, stream>>>(scnt + N_, scols + N_*NNZCAP, svals + N_*NNZCAP,
                                           G1, WTH, WTL, gpea_b, gate, gr, 1);

        k_reduce<<<M_ / 64, 256, 0, stream>>>(gr, reduce_w, reduce_b, residual, cr, partials);
        k_norm<<<M_ * H_ / 4096, 256, 0, stream>>>(cr, partials, last);
    }

    k_out<<<(M_ + 255) / 256, 256, 0, stream>>>(last, ocw, ocb, olw, olb, out);
}

// Round 7
// 1071.165 us; speedup vs baseline: 1.3767x; 1.3767x over previous
//
#include <hip/hip_runtime.h>
#include <hip/hip_bf16.h>
#include <math.h>

// Problem constants
#define B_    64
#define T_    13
#define N_    325
#define H_    64
#define C_    4
#define L_    2
#define S_    4
#define P_    12
#define KCP   4            // checkpoints [4,7,10,13]
#define M_    (B_*N_)      // 20800 (= 650*32 exactly)
#define ADJLD 1300         // leading dim of combined adjacency inputs
#define NNZCAP 64          // max nonzeros per adjacency row (3% density -> mean ~10)

#define FMA16 \
  acc[0][0]+=a0*b0; acc[0][1]+=a0*b1; acc[0][2]+=a0*b2; acc[0][3]+=a0*b3; \
  acc[1][0]+=a1*b0; acc[1][1]+=a1*b1; acc[1][2]+=a1*b2; acc[1][3]+=a1*b3; \
  acc[2][0]+=a2*b0; acc[2][1]+=a2*b1; acc[2][2]+=a2*b2; acc[2][3]+=a2*b3; \
  acc[3][0]+=a3*b0; acc[3][1]+=a3*b1; acc[3][2]+=a3*b2; acc[3][3]+=a3*b3;

// ---------------------------------------------------------------------------
// Build padded sparse rows (column-ordered, deterministic). One wave per row.
__global__ void k_build_sparse(const float* __restrict__ A,
                               int* __restrict__ cnt, int* __restrict__ cols,
                               float* __restrict__ vals) {
    int n    = blockIdx.x;
    int lane = threadIdx.x;
    const float* row = A + (size_t)n * ADJLD;
    int c = 0;
    for (int c0 = 0; c0 < 384; c0 += 64) {
        int col = c0 + lane;
        float v = (col < N_) ? row[col] : 0.f;
        unsigned long long m = __ballot(v != 0.f);
        int idx = c + __popcll(m & ((1ull << lane) - 1ull));
        if (v != 0.f && idx < NNZCAP) {
            cols[n * NNZCAP + idx] = col;
            vals[n * NNZCAP + idx] = v;
        }
        c += __popcll(m);
    }
    if (c + lane < NNZCAP) {                 // zero-pad tail -> branch-free consumers
        cols[n * NNZCAP + c + lane] = 0;
        vals[n * NNZCAP + c + lane] = 0.f;
    }
    if (lane == 0) cnt[n] = (c < NNZCAP) ? c : NNZCAP;
}

// ---------------------------------------------------------------------------
// K1: fused gf/residual/g_init + 2-layer gate MLP.
// Phase 0 computes gf (into LDS), residual, g_init for 64 rows.
// Then gate = sigmoid(relu(gf@W1+b1)@W2+b2) exactly as before.
__global__ __launch_bounds__(256, 3) void k_gate(
    const float* __restrict__ inp,
    const float* __restrict__ w_in, const float* __restrict__ b_in,
    const float* __restrict__ gconv_w, const float* __restrict__ gconv_b,
    const float* __restrict__ res_w,   const float* __restrict__ res_b,
    const float* __restrict__ last, int it,
    const float* __restrict__ W1, const float* __restrict__ b1,
    const float* __restrict__ W2, const float* __restrict__ b2,
    float* __restrict__ residual, float* __restrict__ g_init,
    float* __restrict__ gate)
{
    __shared__ float Gf[64 * 68];
    __shared__ float Ws[64 * 68];
    __shared__ float Gr[64 * 68];
    int t = threadIdx.x, lane = t & 63, w = t >> 6;
    int m0 = blockIdx.x * 64;

    // ---- phase 0: gf / residual / g_init ----
    {
        float wa = w_in[lane], wb = w_in[H_ + lane], bi = b_in[lane];
        float gw0 = gconv_w[0], gw1 = gconv_w[1], gw2 = gconv_w[2], gw3 = gconv_w[3];
        float rw0 = res_w[0],   rw1 = res_w[1],   rw2 = res_w[2],   rw3 = res_w[3];
        float gb = gconv_b[0],  rb = res_b[0];
        int left = (it == 0) ? 0 : (3 * it + 1);
        for (int i = 0; i < 16; ++i) {
            int r = i * 4 + w;                  // wave-uniform row
            int m = m0 + r;
            int b = m / N_, n = m % N_;
            const float* ipb = inp + ((size_t)b * T_ * N_ + n) * 2;
            float v0;
            if (it > 0) v0 = last[(size_t)m * H_ + lane];
            else        { const float* ip = ipb; v0 = ip[0] * wa + ip[1] * wb + bi; }
            int t1 = (it == 0) ? 1 : left;
            const float* ip1 = ipb + (size_t)t1 * N_ * 2;
            const float* ip2 = ip1 + (size_t)N_ * 2;
            const float* ip3 = ip2 + (size_t)N_ * 2;
            float v1 = ip1[0] * wa + ip1[1] * wb + bi;
            float v2 = ip2[0] * wa + ip2[1] * wb + bi;
            float v3 = ip3[0] * wa + ip3[1] * wb + bi;
            Gf[r * 68 + lane] = gb + gw0 * v0 + gw1 * v1 + gw2 * v2 + gw3 * v3;
            residual[(size_t)m * H_ + lane] = rb + rw0 * v0 + rw1 * v1 + rw2 * v2 + rw3 * v3;
            g_init[(size_t)m * H_ + lane] = v3;
        }
    }
    // stage W1
    #pragma unroll
    for (int i = 0; i < 4; ++i) {
        int f4 = t + i * 256;
        int row = f4 >> 4, col = (f4 & 15) * 4;
        *(float4*)&Ws[row * 68 + col] = *(const float4*)&W1[row * 64 + col];
    }
    __syncthreads();

    int tx = t & 15, ty = t >> 4;
    float acc[4][4];
    #pragma unroll
    for (int i = 0; i < 4; ++i)
        #pragma unroll
        for (int j = 0; j < 4; ++j) acc[i][j] = 0.f;
    #pragma unroll 16
    for (int k = 0; k < 64; ++k) {
        float a0 = Gf[ty * 68 + k];
        float a1 = Gf[(ty + 16) * 68 + k];
        float a2 = Gf[(ty + 32) * 68 + k];
        float a3 = Gf[(ty + 48) * 68 + k];
        float4 wv = *(const float4*)&Ws[k * 68 + 4 * tx];
        float b0 = wv.x, b1v = wv.y, b2v = wv.z, b3 = wv.w;
        { float b1 = b1v, b2 = b2v; FMA16 }
    }
    float4 bi1 = *(const float4*)&b1[4 * tx];
    #pragma unroll
    for (int i = 0; i < 4; ++i) {
        float v0 = acc[i][0] + bi1.x; v0 = v0 > 0.f ? v0 : 0.f;
        float v1 = acc[i][1] + bi1.y; v1 = v1 > 0.f ? v1 : 0.f;
        float v2 = acc[i][2] + bi1.z; v2 = v2 > 0.f ? v2 : 0.f;
        float v3 = acc[i][3] + bi1.w; v3 = v3 > 0.f ? v3 : 0.f;
        *(float4*)&Gr[(ty + 16 * i) * 68 + 4 * tx] = make_float4(v0, v1, v2, v3);
    }
    for (int ch = 0; ch < 4; ++ch) {
        __syncthreads();
        #pragma unroll
        for (int i = 0; i < 4; ++i) {
            int f4 = t + i * 256;
            int row = f4 >> 4, col = (f4 & 15) * 4;
            *(float4*)&Ws[row * 68 + col] =
                *(const float4*)&W2[(size_t)row * 256 + ch * 64 + col];
        }
        __syncthreads();
        float acc2[4][4];
        #pragma unroll
        for (int i = 0; i < 4; ++i)
            #pragma unroll
            for (int j = 0; j < 4; ++j) acc2[i][j] = 0.f;
        #pragma unroll 16
        for (int k = 0; k < 64; ++k) {
            float a0 = Gr[ty * 68 + k];
            float a1 = Gr[(ty + 16) * 68 + k];
            float a2 = Gr[(ty + 32) * 68 + k];
            float a3 = Gr[(ty + 48) * 68 + k];
            float4 wv = *(const float4*)&Ws[k * 68 + 4 * tx];
            float b0 = wv.x, b1v = wv.y, b2v = wv.z, b3 = wv.w;
            { float b1 = b1v, b2 = b2v; float (*acc)[4] = acc2; FMA16 }
        }
        float4 bi2 = *(const float4*)&b2[ch * 64 + 4 * tx];
        #pragma unroll
        for (int i = 0; i < 4; ++i) {
            int m = m0 + ty + 16 * i;
            float g0 = 1.f / (1.f + expf(-(acc2[i][0] + bi2.x)));
            float g1 = 1.f / (1.f + expf(-(acc2[i][1] + bi2.y)));
            float g2 = 1.f / (1.f + expf(-(acc2[i][2] + bi2.z)));
            float g3 = 1.f / (1.f + expf(-(acc2[i][3] + bi2.w)));
            *(float4*)&gate[(size_t)m * 256 + ch * 64 + 4 * tx] = make_float4(g0, g1, g2, g3);
        }
    }
}

// ---------------------------------------------------------------------------
// K2: layer 1 for BOTH stacks: gather A_adj@g and A_pea@g once (32-row tile),
// then 8 GEMMs (2 stacks x 4 c) -> G1a/G1p [M][256]. XCD-swizzled.
__global__ __launch_bounds__(256, 4) void k_layer1(
    const int*   __restrict__ cnt,    // [2N]  adj rows 0..N, pea rows N..2N
    const int*   __restrict__ cols,   // [2N][NNZCAP]
    const float* __restrict__ vals,
    const float* __restrict__ g_init, // [M][64]
    const float* __restrict__ wadj, const float* __restrict__ badj,
    const float* __restrict__ wpea, const float* __restrict__ bpea,
    float* __restrict__ G1a, float* __restrict__ G1p)   // [M][256]
{
    __shared__ float Ma[32 * 68];
    __shared__ float Mp[32 * 68];
    __shared__ float Ws[64 * 68];
    int t = threadIdx.x, lane = t & 63, w = t >> 6;
    // XCD swizzle: consecutive row-tiles on the same XCD
    int vb = (blockIdx.x & 7) * 82 + (blockIdx.x >> 3);
    if (vb >= 650) return;
    int m0 = vb * 32;

    // ---- gather: wave w owns rows w*8..w*8+7, both stacks, 2 rows in flight ----
    for (int pp = 0; pp < 8; pp += 2) {
        int ma = m0 + w * 8 + pp, mb = ma + 1;
        int na = ma % N_, nb = mb % N_;
        const float* ga = g_init + (size_t)(ma - na) * H_;
        const float* gb = g_init + (size_t)(mb - nb) * H_;
        const int   *cAa = cols + na * NNZCAP,        *cAb = cols + nb * NNZCAP;
        const float *vAa = vals + na * NNZCAP,        *vAb = vals + nb * NNZCAP;
        const int   *cPa = cols + (N_ + na) * NNZCAP, *cPb = cols + (N_ + nb) * NNZCAP;
        const float *vPa = vals + (N_ + na) * NNZCAP, *vPb = vals + (N_ + nb) * NNZCAP;
        int jm = max(max(cnt[na], cnt[nb]), max(cnt[N_ + na], cnt[N_ + nb]));
        float aA0 = 0.f, aA1 = 0.f, aP0 = 0.f, aP1 = 0.f;
        for (int j = 0; j < jm; j += 2) {     // zero-padded -> branch-free
            aA0 += vAa[j] * ga[cAa[j] * H_ + lane] + vAa[j+1] * ga[cAa[j+1] * H_ + lane];
            aA1 += vAb[j] * gb[cAb[j] * H_ + lane] + vAb[j+1] * gb[cAb[j+1] * H_ + lane];
            aP0 += vPa[j] * ga[cPa[j] * H_ + lane] + vPa[j+1] * ga[cPa[j+1] * H_ + lane];
            aP1 += vPb[j] * gb[cPb[j] * H_ + lane] + vPb[j+1] * gb[cPb[j+1] * H_ + lane];
        }
        int r0 = (w * 8 + pp) * 68 + lane;
        Ma[r0] = aA0;  Ma[r0 + 68] = aA1;
        Mp[r0] = aP0;  Mp[r0 + 68] = aP1;
    }

    int tx = t & 15, ty = t >> 4;
    for (int sc = 0; sc < 8; ++sc) {
        int stack = sc >> 2, c = sc & 3;
        const float* wb0 = (stack ? wpea : wadj) + (size_t)c * 16384;   // (c*2+0)*2*4096
        const float* wb1 = wb0 + 4096;
        __syncthreads();   // gather done (sc=0) / prev Ws reads done (sc>0)
        #pragma unroll
        for (int i = 0; i < 4; ++i) {
            int f4 = t + i * 256;
            int row = f4 >> 4, col = (f4 & 15) * 4;
            float4 x0 = *(const float4*)&wb0[row * 64 + col];
            float4 x1 = *(const float4*)&wb1[row * 64 + col];
            *(float4*)&Ws[row * 68 + col] = make_float4(x0.x + x1.x, x0.y + x1.y,
                                                        x0.z + x1.z, x0.w + x1.w);
        }
        __syncthreads();

        const float* Msrc = stack ? Mp : Ma;
        float4 acc0 = make_float4(0.f, 0.f, 0.f, 0.f);
        float4 acc1 = make_float4(0.f, 0.f, 0.f, 0.f);
        #pragma unroll 8
        for (int k4 = 0; k4 < 64; k4 += 4) {
            float4 A0 = *(const float4*)&Msrc[ty * 68 + k4];
            float4 A1 = *(const float4*)&Msrc[(ty + 16) * 68 + k4];
            float4 W0 = *(const float4*)&Ws[(k4 + 0) * 68 + 4 * tx];
            float4 W1 = *(const float4*)&Ws[(k4 + 1) * 68 + 4 * tx];
            float4 W2 = *(const float4*)&Ws[(k4 + 2) * 68 + 4 * tx];
            float4 W3 = *(const float4*)&Ws[(k4 + 3) * 68 + 4 * tx];
            acc0.x += A0.x*W0.x + A0.y*W1.x + A0.z*W2.x + A0.w*W3.x;
            acc0.y += A0.x*W0.y + A0.y*W1.y + A0.z*W2.y + A0.w*W3.y;
            acc0.z += A0.x*W0.z + A0.y*W1.z + A0.z*W2.z + A0.w*W3.z;
            acc0.w += A0.x*W0.w + A0.y*W1.w + A0.z*W2.w + A0.w*W3.w;
            acc1.x += A1.x*W0.x + A1.y*W1.x + A1.z*W2.x + A1.w*W3.x;
            acc1.y += A1.x*W0.y + A1.y*W1.y + A1.z*W2.y + A1.w*W3.y;
            acc1.z += A1.x*W0.z + A1.y*W1.z + A1.z*W2.z + A1.w*W3.z;
            acc1.w += A1.x*W0.w + A1.y*W1.w + A1.z*W2.w + A1.w*W3.w;
        }
        const float* bias = (stack ? bpea : badj) + c * L_ * H_;   // layer 0
        float4 bi = *(const float4*)&bias[4 * tx];
        float* Gout = stack ? G1p : G1a;
        #pragma unroll
        for (int r = 0; r < 2; ++r) {
            float4 a = r ? acc1 : acc0;
            float v0 = a.x + bi.x; v0 = v0 > 0.f ? v0 : 0.f;
            float v1 = a.y + bi.y; v1 = v1 > 0.f ? v1 : 0.f;
            float v2 = a.z + bi.z; v2 = v2 > 0.f ? v2 : 0.f;
            float v3 = a.w + bi.w; v3 = v3 > 0.f ? v3 : 0.f;
            *(float4*)&Gout[(size_t)(m0 + ty + 16 * r) * 256 + c * 64 + 4 * tx] =
                make_float4(v0, v1, v2, v3);
        }
    }
}

// ---------------------------------------------------------------------------
// K3: layer 2 + gate mix for BOTH stacks, one (32-row, c) tile per block.
// gr = gate * relu(Aa@G1a@WA + bA) + (1-gate) * relu(Ap@G1p@WP + bP)
__global__ __launch_bounds__(256, 3) void k_mix(
    const int*   __restrict__ cnt,
    const int*   __restrict__ cols,
    const float* __restrict__ vals,
    const float* __restrict__ G1a, const float* __restrict__ G1p,  // [M][256]
    const float* __restrict__ wadj, const float* __restrict__ badj,
    const float* __restrict__ wpea, const float* __restrict__ bpea,
    const float* __restrict__ gate,   // [M][256]
    float* __restrict__ gr)           // [M][256]
{
    __shared__ float Ma[32 * 68];
    __shared__ float Mp[32 * 68];
    __shared__ float WsA[64 * 68];
    __shared__ float WsP[64 * 68];
    int t = threadIdx.x, lane = t & 63, w = t >> 6;
    // XCD swizzle: 2600 = 8 * 325; consecutive row-tiles per XCD, all c local
    int v  = (blockIdx.x & 7) * 325 + (blockIdx.x >> 3);
    int rt = v >> 2, c = v & 3;
    int m0 = rt * 32;

    // stage both W (layer 1 of channel c)
    {
        const float* wA0 = wadj + (size_t)c * 16384 + 8192;   // (c*2+1)*2*4096
        const float* wA1 = wA0 + 4096;
        const float* wP0 = wpea + (size_t)c * 16384 + 8192;
        const float* wP1 = wP0 + 4096;
        #pragma unroll
        for (int i = 0; i < 4; ++i) {
            int f4 = t + i * 256;
            int row = f4 >> 4, col = (f4 & 15) * 4;
            float4 x0 = *(const float4*)&wA0[row * 64 + col];
            float4 x1 = *(const float4*)&wA1[row * 64 + col];
            *(float4*)&WsA[row * 68 + col] = make_float4(x0.x + x1.x, x0.y + x1.y,
                                                         x0.z + x1.z, x0.w + x1.w);
            float4 y0 = *(const float4*)&wP0[row * 64 + col];
            float4 y1 = *(const float4*)&wP1[row * 64 + col];
            *(float4*)&WsP[row * 68 + col] = make_float4(y0.x + y1.x, y0.y + y1.y,
                                                         y0.z + y1.z, y0.w + y1.w);
        }
    }

    // gather c-slice (64 cols) of A@G1 for both stacks
    const int co = c * 64 + lane;
    for (int pp = 0; pp < 8; pp += 2) {
        int ma = m0 + w * 8 + pp, mb = ma + 1;
        int na = ma % N_, nb = mb % N_;
        const float* baseA_a = G1a + (size_t)(ma - na) * 256;
        const float* baseA_b = G1a + (size_t)(mb - nb) * 256;
        const float* baseP_a = G1p + (size_t)(ma - na) * 256;
        const float* baseP_b = G1p + (size_t)(mb - nb) * 256;
        const int   *cAa = cols + na * NNZCAP,        *cAb = cols + nb * NNZCAP;
        const float *vAa = vals + na * NNZCAP,        *vAb = vals + nb * NNZCAP;
        const int   *cPa = cols + (N_ + na) * NNZCAP, *cPb = cols + (N_ + nb) * NNZCAP;
        const float *vPa = vals + (N_ + na) * NNZCAP, *vPb = vals + (N_ + nb) * NNZCAP;
        int jm = max(max(cnt[na], cnt[nb]), max(cnt[N_ + na], cnt[N_ + nb]));
        float aA0 = 0.f, aA1 = 0.f, aP0 = 0.f, aP1 = 0.f;
        for (int j = 0; j < jm; j += 2) {
            aA0 += vAa[j] * baseA_a[cAa[j] * 256 + co] + vAa[j+1] * baseA_a[cAa[j+1] * 256 + co];
            aA1 += vAb[j] * baseA_b[cAb[j] * 256 + co] + vAb[j+1] * baseA_b[cAb[j+1] * 256 + co];
            aP0 += vPa[j] * baseP_a[cPa[j] * 256 + co] + vPa[j+1] * baseP_a[cPa[j+1] * 256 + co];
            aP1 += vPb[j] * baseP_b[cPb[j] * 256 + co] + vPb[j+1] * baseP_b[cPb[j+1] * 256 + co];
        }
        int r0 = (w * 8 + pp) * 68 + lane;
        Ma[r0] = aA0;  Ma[r0 + 68] = aA1;
        Mp[r0] = aP0;  Mp[r0 + 68] = aP1;
    }
    __syncthreads();

    // two GEMMs 32x64x64 + mix epilogue
    int tx = t & 15, ty = t >> 4;
    float4 accA0 = make_float4(0.f,0.f,0.f,0.f), accA1 = make_float4(0.f,0.f,0.f,0.f);
    float4 accP0 = make_float4(0.f,0.f,0.f,0.f), accP1 = make_float4(0.f,0.f,0.f,0.f);
    #pragma unroll 4
    for (int k4 = 0; k4 < 64; k4 += 4) {
        float4 A0 = *(const float4*)&Ma[ty * 68 + k4];
        float4 A1 = *(const float4*)&Ma[(ty + 16) * 68 + k4];
        float4 P0 = *(const float4*)&Mp[ty * 68 + k4];
        float4 P1 = *(const float4*)&Mp[(ty + 16) * 68 + k4];
        #pragma unroll
        for (int kk = 0; kk < 4; ++kk) {
            float4 WA = *(const float4*)&WsA[(k4 + kk) * 68 + 4 * tx];
            float4 WP = *(const float4*)&WsP[(k4 + kk) * 68 + 4 * tx];
            float av0 = kk == 0 ? A0.x : kk == 1 ? A0.y : kk == 2 ? A0.z : A0.w;
            float av1 = kk == 0 ? A1.x : kk == 1 ? A1.y : kk == 2 ? A1.z : A1.w;
            float pv0 = kk == 0 ? P0.x : kk == 1 ? P0.y : kk == 2 ? P0.z : P0.w;
            float pv1 = kk == 0 ? P1.x : kk == 1 ? P1.y : kk == 2 ? P1.z : P1.w;
            accA0.x += av0 * WA.x; accA0.y += av0 * WA.y; accA0.z += av0 * WA.z; accA0.w += av0 * WA.w;
            accA1.x += av1 * WA.x; accA1.y += av1 * WA.y; accA1.z += av1 * WA.z; accA1.w += av1 * WA.w;
            accP0.x += pv0 * WP.x; accP0.y += pv0 * WP.y; accP0.z += pv0 * WP.z; accP0.w += pv0 * WP.w;
            accP1.x += pv1 * WP.x; accP1.y += pv1 * WP.y; accP1.z += pv1 * WP.z; accP1.w += pv1 * WP.w;
        }
    }
    float4 bA = *(const float4*)&badj[(c * L_ + 1) * H_ + 4 * tx];
    float4 bP = *(const float4*)&bpea[(c * L_ + 1) * H_ + 4 * tx];
    #pragma unroll
    for (int r = 0; r < 2; ++r) {
        float4 a = r ? accA1 : accA0;
        float4 p = r ? accP1 : accP0;
        float va0 = a.x + bA.x; va0 = va0 > 0.f ? va0 : 0.f;
        float va1 = a.y + bA.y; va1 = va1 > 0.f ? va1 : 0.f;
        float va2 = a.z + bA.z; va2 = va2 > 0.f ? va2 : 0.f;
        float va3 = a.w + bA.w; va3 = va3 > 0.f ? va3 : 0.f;
        float vp0 = p.x + bP.x; vp0 = vp0 > 0.f ? vp0 : 0.f;
        float vp1 = p.y + bP.y; vp1 = vp1 > 0.f ? vp1 : 0.f;
        float vp2 = p.z + bP.z; vp2 = vp2 > 0.f ? vp2 : 0.f;
        float vp3 = p.w + bP.w; vp3 = vp3 > 0.f ? vp3 : 0.f;
        size_t o = (size_t)(m0 + ty + 16 * r) * 256 + c * 64 + 4 * tx;
        float4 g = *(const float4*)&gate[o];
        *(float4*)&gr[o] = make_float4(g.x * va0 + (1.f - g.x) * vp0,
                                       g.y * va1 + (1.f - g.y) * vp1,
                                       g.z * va2 + (1.f - g.z) * vp2,
                                       g.w * va3 + (1.f - g.w) * vp3);
    }
}

// ---------------------------------------------------------------------------
// K4: cr = gr @ reduce_w + reduce_b + residual, with fused partial sums
__global__ __launch_bounds__(256) void k_reduce(const float* __restrict__ in,
                                                const float* __restrict__ W,
                                                const float* __restrict__ bias,
                                                const float* __restrict__ residual,
                                                float* __restrict__ cr,
                                                float* __restrict__ partials) {
    __shared__ float Is[64][17];
    __shared__ float Ws[16][65];
    __shared__ float r1[256], r2[256];
    int t = threadIdx.x, tx = t & 15, ty = t >> 4;
    int m0 = blockIdx.x * 64;
    float acc[4][4];
    #pragma unroll
    for (int i = 0; i < 4; ++i)
        #pragma unroll
        for (int j = 0; j < 4; ++j) acc[i][j] = 0.f;
    for (int kk = 0; kk < 256; kk += 16) {
        #pragma unroll
        for (int i = 0; i < 4; ++i) { int e = t + i*256; int r = e>>4, kc = e&15;
            Is[r][kc] = in[(size_t)(m0 + r) * 256 + kk + kc]; }
        #pragma unroll
        for (int i = 0; i < 4; ++i) { int e = t + i*256; int r = e>>6, cc = e&63;
            Ws[r][cc] = W[(size_t)(kk + r) * 64 + cc]; }
        __syncthreads();
        #pragma unroll
        for (int k = 0; k < 16; ++k) {
            float a0 = Is[ty][k], a1 = Is[ty+16][k], a2 = Is[ty+32][k], a3 = Is[ty+48][k];
            float b0 = Ws[k][tx], b1 = Ws[k][tx+16], b2 = Ws[k][tx+32], b3 = Ws[k][tx+48];
            FMA16
        }
        __syncthreads();
    }
    float s = 0.f, s2 = 0.f;
    #pragma unroll
    for (int i = 0; i < 4; ++i) {
        int r = m0 + ty + 16 * i;
        #pragma unroll
        for (int j = 0; j < 4; ++j) {
            int cc = tx + 16 * j;
            float v = acc[i][j] + bias[cc] + residual[(size_t)r * 64 + cc];
            cr[(size_t)r * 64 + cc] = v;
            s += v; s2 += v * v;
        }
    }
    r1[t] = s; r2[t] = s2;
    __syncthreads();
    for (int off = 128; off > 0; off >>= 1) {
        if (t < off) { r1[t] += r1[t + off]; r2[t] += r2[t + off]; }
        __syncthreads();
    }
    if (t == 0) { partials[blockIdx.x] = r1[0]; partials[325 + blockIdx.x] = r2[0]; }
}

// K5: finalize mu/var (redundantly per block) + normalize (grid 325)
__global__ void k_norm(const float* __restrict__ cr, const float* __restrict__ partials,
                       float* __restrict__ last) {
    __shared__ float s1[256], s2[256];
    int t = threadIdx.x;
    float a = 0.f, b = 0.f;
    for (int i = t; i < 325; i += 256) { a += partials[i]; b += partials[325 + i]; }
    s1[t] = a; s2[t] = b;
    __syncthreads();
    for (int off = 128; off > 0; off >>= 1) {
        if (t < off) { s1[t] += s1[t + off]; s2[t] += s2[t + off]; }
        __syncthreads();
    }
    const float inv = 1.f / (float)(M_ * H_);
    float mu  = s1[0] * inv;
    float var = s2[0] * inv - mu * mu;
    float rs  = rsqrtf(var + 1e-5f);
    int base = blockIdx.x * 4096 + t * 4;
    #pragma unroll
    for (int i = 0; i < 4; ++i) {
        float4 v = *(const float4*)&cr[base + i * 1024];
        *(float4*)&last[base + i * 1024] =
            make_float4((v.x - mu) * rs, (v.y - mu) * rs, (v.z - mu) * rs, (v.w - mu) * rs);
    }
}

// ---------------------------------------------------------------------------
// K6: out[b,p,n] = sum_h relu(ocw[p]*last[b,n,h] + ocb[p]) * olw[h] + olb
__global__ void k_out(const float* __restrict__ last,
                      const float* __restrict__ ocw, const float* __restrict__ ocb,
                      const float* __restrict__ olw, const float* __restrict__ olb,
                      float* __restrict__ out) {
    int m = blockIdx.x * 256 + threadIdx.x;
    if (m >= M_) return;
    int b = m / N_, n = m % N_;
    float cw[P_], cb[P_], acc[P_];
    #pragma unroll
    for (int p = 0; p < P_; ++p) { cw[p] = ocw[p]; cb[p] = ocb[p]; acc[p] = 0.f; }
    const float* lr = last + (size_t)m * H_;
    for (int h = 0; h < H_; ++h) {
        float lv = lr[h], wv = olw[h];
        #pragma unroll
        for (int p = 0; p < P_; ++p) {
            float u = cw[p] * lv + cb[p];
            u = u > 0.f ? u : 0.f;
            acc[p] += u * wv;
        }
    }
    float ob = olb[0];
    #pragma unroll
    for (int p = 0; p < P_; ++p)
        out[(size_t)(b * P_ + p) * N_ + n] = acc[p] + ob;
}

// ---------------------------------------------------------------------------
extern "C" void kernel_launch(void* const* d_in, const int* in_sizes, int n_in,
                              void* d_out, int out_size, void* d_ws, size_t ws_size,
                              hipStream_t stream) {
    const float* inp      = (const float*)d_in[0];
    const float* adj_fwd  = (const float*)d_in[1];
    const float* pea_fwd  = (const float*)d_in[3];
    const float* w_in     = (const float*)d_in[5];
    const float* b_in     = (const float*)d_in[6];
    const float* res_w    = (const float*)d_in[7];
    const float* res_b    = (const float*)d_in[8];
    const float* gconv_w  = (const float*)d_in[9];
    const float* gconv_b  = (const float*)d_in[10];
    const float* gate1_w  = (const float*)d_in[11];
    const float* gate1_b  = (const float*)d_in[12];
    const float* gate2_w  = (const float*)d_in[13];
    const float* gate2_b  = (const float*)d_in[14];
    const float* reduce_w = (const float*)d_in[15];
    const float* reduce_b = (const float*)d_in[16];
    const float* gadj_w   = (const float*)d_in[17];
    const float* gadj_b   = (const float*)d_in[18];
    const float* gpea_w   = (const float*)d_in[19];
    const float* gpea_b   = (const float*)d_in[20];
    const float* ocw      = (const float*)d_in[21];
    const float* ocb      = (const float*)d_in[22];
    const float* olw      = (const float*)d_in[23];
    const float* olb      = (const float*)d_in[24];
    float* out = (float*)d_out;

    // workspace layout (floats) — ~96 MB
    float* ws       = (float*)d_ws;
    float* g_init   = ws;                              // M*64
    float* G1a      = g_init + (size_t)M_ * H_;        // M*256  (aliases `last`)
    float* G1p      = G1a + (size_t)M_ * 256;          // M*256
    float* gate     = G1p + (size_t)M_ * 256;          // M*256  (aliases `cr`)
    float* gr       = gate + (size_t)M_ * 256;         // M*256
    float* residual = gr + (size_t)M_ * 256;           // M*64
    float* partials = residual + (size_t)M_ * H_;      // 650
    int*   scnt  = (int*)(partials + 650);             // 2*325
    int*   scols = scnt + 2 * N_;                      // 2*325*64
    float* svals = (float*)(scols + 2 * N_ * NNZCAP);  // 2*325*64
    float* last = G1a;    // norm(it) -> k_gate(it+1) reads it -> k_layer1 overwrites
    float* cr   = gate;   // gate dead after k_mix; reduce writes, norm reads

    k_build_sparse<<<N_, 64, 0, stream>>>(adj_fwd, scnt,      scols,              svals);
    k_build_sparse<<<N_, 64, 0, stream>>>(pea_fwd, scnt + N_, scols + N_*NNZCAP,  svals + N_*NNZCAP);

    for (int it = 0; it < KCP; ++it) {
        k_gate<<<M_ / 64, 256, 0, stream>>>(
            inp, w_in, b_in, gconv_w, gconv_b, res_w, res_b, last, it,
            gate1_w, gate1_b, gate2_w, gate2_b, residual, g_init, gate);
        k_layer1<<<656, 256, 0, stream>>>(
            scnt, scols, svals, g_init, gadj_w, gadj_b, gpea_w, gpea_b, G1a, G1p);
        k_mix<<<2600, 256, 0, stream>>>(
            scnt, scols, svals, G1a, G1p, gadj_w, gadj_b, gpea_w, gpea_b, gate, gr);
        k_reduce<<<M_ / 64, 256, 0, stream>>>(gr, reduce_w, reduce_b, residual, cr, partials);
        k_norm<<<325, 256, 0, stream>>>(cr, partials, last);
    }

    k_out<<<(M_ + 255) / 256, 256, 0, stream>>>(last, ocw, ocb, olw, olb, out);
}

// Round 8
// 897.284 us; speedup vs baseline: 1.6435x; 1.1938x over previous
//
#include <hip/hip_runtime.h>
#include <hip/hip_bf16.h>
#include <math.h>

// Problem constants
#define B_    64
#define T_    13
#define N_    325
#define H_    64
#define C_    4
#define L_    2
#define S_    4
#define P_    12
#define KCP   4            // checkpoints [4,7,10,13]
#define M_    (B_*N_)      // 20800 (= 650*32 exactly)
#define ADJLD 1300         // leading dim of combined adjacency inputs
#define NNZCAP 64          // max nonzeros per adjacency row (3% density -> mean ~10)

#define FMA16 \
  acc[0][0]+=a0*b0; acc[0][1]+=a0*b1; acc[0][2]+=a0*b2; acc[0][3]+=a0*b3; \
  acc[1][0]+=a1*b0; acc[1][1]+=a1*b1; acc[1][2]+=a1*b2; acc[1][3]+=a1*b3; \
  acc[2][0]+=a2*b0; acc[2][1]+=a2*b1; acc[2][2]+=a2*b2; acc[2][3]+=a2*b3; \
  acc[3][0]+=a3*b0; acc[3][1]+=a3*b1; acc[3][2]+=a3*b2; acc[3][3]+=a3*b3;

// ---------------------------------------------------------------------------
// Build padded sparse rows (column-ordered, deterministic). One wave per row.
__global__ void k_build_sparse(const float* __restrict__ A,
                               int* __restrict__ cnt, int* __restrict__ cols,
                               float* __restrict__ vals) {
    int n    = blockIdx.x;
    int lane = threadIdx.x;
    const float* row = A + (size_t)n * ADJLD;
    int c = 0;
    for (int c0 = 0; c0 < 384; c0 += 64) {
        int col = c0 + lane;
        float v = (col < N_) ? row[col] : 0.f;
        unsigned long long m = __ballot(v != 0.f);
        int idx = c + __popcll(m & ((1ull << lane) - 1ull));
        if (v != 0.f && idx < NNZCAP) {
            cols[n * NNZCAP + idx] = col;
            vals[n * NNZCAP + idx] = v;
        }
        c += __popcll(m);
    }
    if (c + lane < NNZCAP) {                 // zero-pad tail -> branch-free consumers
        cols[n * NNZCAP + c + lane] = 0;
        vals[n * NNZCAP + c + lane] = 0.f;
    }
    if (lane == 0) cnt[n] = (c < NNZCAP) ? c : NNZCAP;
}

// ---------------------------------------------------------------------------
// K1: fused gf/residual/g_init + 2-layer gate MLP.
__global__ __launch_bounds__(256, 3) void k_gate(
    const float* __restrict__ inp,
    const float* __restrict__ w_in, const float* __restrict__ b_in,
    const float* __restrict__ gconv_w, const float* __restrict__ gconv_b,
    const float* __restrict__ res_w,   const float* __restrict__ res_b,
    const float* __restrict__ last, int it,
    const float* __restrict__ W1, const float* __restrict__ b1,
    const float* __restrict__ W2, const float* __restrict__ b2,
    float* __restrict__ residual, float* __restrict__ g_init,
    float* __restrict__ gate)
{
    __shared__ float Gf[64 * 68];
    __shared__ float Ws[64 * 68];
    __shared__ float Gr[64 * 68];
    int t = threadIdx.x, lane = t & 63, w = t >> 6;
    int m0 = blockIdx.x * 64;

    // ---- phase 0: gf / residual / g_init ----
    {
        float wa = w_in[lane], wb = w_in[H_ + lane], bi = b_in[lane];
        float gw0 = gconv_w[0], gw1 = gconv_w[1], gw2 = gconv_w[2], gw3 = gconv_w[3];
        float rw0 = res_w[0],   rw1 = res_w[1],   rw2 = res_w[2],   rw3 = res_w[3];
        float gb = gconv_b[0],  rb = res_b[0];
        int left = (it == 0) ? 0 : (3 * it + 1);
        for (int i = 0; i < 16; ++i) {
            int r = i * 4 + w;                  // wave-uniform row
            int m = m0 + r;
            int b = m / N_, n = m % N_;
            const float* ipb = inp + ((size_t)b * T_ * N_ + n) * 2;
            float v0;
            if (it > 0) v0 = last[(size_t)m * H_ + lane];
            else        { const float* ip = ipb; v0 = ip[0] * wa + ip[1] * wb + bi; }
            int t1 = (it == 0) ? 1 : left;
            const float* ip1 = ipb + (size_t)t1 * N_ * 2;
            const float* ip2 = ip1 + (size_t)N_ * 2;
            const float* ip3 = ip2 + (size_t)N_ * 2;
            float v1 = ip1[0] * wa + ip1[1] * wb + bi;
            float v2 = ip2[0] * wa + ip2[1] * wb + bi;
            float v3 = ip3[0] * wa + ip3[1] * wb + bi;
            Gf[r * 68 + lane] = gb + gw0 * v0 + gw1 * v1 + gw2 * v2 + gw3 * v3;
            residual[(size_t)m * H_ + lane] = rb + rw0 * v0 + rw1 * v1 + rw2 * v2 + rw3 * v3;
            g_init[(size_t)m * H_ + lane] = v3;
        }
    }
    // stage W1
    #pragma unroll
    for (int i = 0; i < 4; ++i) {
        int f4 = t + i * 256;
        int row = f4 >> 4, col = (f4 & 15) * 4;
        *(float4*)&Ws[row * 68 + col] = *(const float4*)&W1[row * 64 + col];
    }
    __syncthreads();

    int tx = t & 15, ty = t >> 4;
    float acc[4][4];
    #pragma unroll
    for (int i = 0; i < 4; ++i)
        #pragma unroll
        for (int j = 0; j < 4; ++j) acc[i][j] = 0.f;
    #pragma unroll 16
    for (int k = 0; k < 64; ++k) {
        float a0 = Gf[ty * 68 + k];
        float a1 = Gf[(ty + 16) * 68 + k];
        float a2 = Gf[(ty + 32) * 68 + k];
        float a3 = Gf[(ty + 48) * 68 + k];
        float4 wv = *(const float4*)&Ws[k * 68 + 4 * tx];
        float b0 = wv.x, b1v = wv.y, b2v = wv.z, b3 = wv.w;
        { float b1 = b1v, b2 = b2v; FMA16 }
    }
    float4 bi1 = *(const float4*)&b1[4 * tx];
    #pragma unroll
    for (int i = 0; i < 4; ++i) {
        float v0 = acc[i][0] + bi1.x; v0 = v0 > 0.f ? v0 : 0.f;
        float v1 = acc[i][1] + bi1.y; v1 = v1 > 0.f ? v1 : 0.f;
        float v2 = acc[i][2] + bi1.z; v2 = v2 > 0.f ? v2 : 0.f;
        float v3 = acc[i][3] + bi1.w; v3 = v3 > 0.f ? v3 : 0.f;
        *(float4*)&Gr[(ty + 16 * i) * 68 + 4 * tx] = make_float4(v0, v1, v2, v3);
    }
    for (int ch = 0; ch < 4; ++ch) {
        __syncthreads();
        #pragma unroll
        for (int i = 0; i < 4; ++i) {
            int f4 = t + i * 256;
            int row = f4 >> 4, col = (f4 & 15) * 4;
            *(float4*)&Ws[row * 68 + col] =
                *(const float4*)&W2[(size_t)row * 256 + ch * 64 + col];
        }
        __syncthreads();
        float acc2[4][4];
        #pragma unroll
        for (int i = 0; i < 4; ++i)
            #pragma unroll
            for (int j = 0; j < 4; ++j) acc2[i][j] = 0.f;
        #pragma unroll 16
        for (int k = 0; k < 64; ++k) {
            float a0 = Gr[ty * 68 + k];
            float a1 = Gr[(ty + 16) * 68 + k];
            float a2 = Gr[(ty + 32) * 68 + k];
            float a3 = Gr[(ty + 48) * 68 + k];
            float4 wv = *(const float4*)&Ws[k * 68 + 4 * tx];
            float b0 = wv.x, b1v = wv.y, b2v = wv.z, b3 = wv.w;
            { float b1 = b1v, b2 = b2v; float (*acc)[4] = acc2; FMA16 }
        }
        float4 bi2 = *(const float4*)&b2[ch * 64 + 4 * tx];
        #pragma unroll
        for (int i = 0; i < 4; ++i) {
            int m = m0 + ty + 16 * i;
            float g0 = 1.f / (1.f + expf(-(acc2[i][0] + bi2.x)));
            float g1 = 1.f / (1.f + expf(-(acc2[i][1] + bi2.y)));
            float g2 = 1.f / (1.f + expf(-(acc2[i][2] + bi2.z)));
            float g3 = 1.f / (1.f + expf(-(acc2[i][3] + bi2.w)));
            *(float4*)&gate[(size_t)m * 256 + ch * 64 + 4 * tx] = make_float4(g0, g1, g2, g3);
        }
    }
}

// ---------------------------------------------------------------------------
// K2: layer 1 for BOTH stacks: gather A_adj@g and A_pea@g once (32-row tile),
// then 8 GEMMs (2 stacks x 4 c) -> G1a/G1p [M][256]. XCD-swizzled.
__global__ __launch_bounds__(256, 4) void k_layer1(
    const int*   __restrict__ cnt,    // [2N]  adj rows 0..N, pea rows N..2N
    const int*   __restrict__ cols,   // [2N][NNZCAP]
    const float* __restrict__ vals,
    const float* __restrict__ g_init, // [M][64]
    const float* __restrict__ wadj, const float* __restrict__ badj,
    const float* __restrict__ wpea, const float* __restrict__ bpea,
    float* __restrict__ G1a, float* __restrict__ G1p)   // [M][256]
{
    __shared__ float Ma[32 * 68];
    __shared__ float Mp[32 * 68];
    __shared__ float Ws[64 * 68];
    int t = threadIdx.x, lane = t & 63, w = t >> 6;
    // XCD swizzle: consecutive row-tiles on the same XCD
    int vb = (blockIdx.x & 7) * 82 + (blockIdx.x >> 3);
    if (vb >= 650) return;
    int m0 = vb * 32;

    // ---- gather: wave w owns rows w*8..w*8+7, both stacks, 2 rows in flight ----
    for (int pp = 0; pp < 8; pp += 2) {
        int ma = m0 + w * 8 + pp, mb = ma + 1;
        int na = ma % N_, nb = mb % N_;
        const float* ga = g_init + (size_t)(ma - na) * H_;
        const float* gb = g_init + (size_t)(mb - nb) * H_;
        const int   *cAa = cols + na * NNZCAP,        *cAb = cols + nb * NNZCAP;
        const float *vAa = vals + na * NNZCAP,        *vAb = vals + nb * NNZCAP;
        const int   *cPa = cols + (N_ + na) * NNZCAP, *cPb = cols + (N_ + nb) * NNZCAP;
        const float *vPa = vals + (N_ + na) * NNZCAP, *vPb = vals + (N_ + nb) * NNZCAP;
        int jm = max(max(cnt[na], cnt[nb]), max(cnt[N_ + na], cnt[N_ + nb]));
        float aA0 = 0.f, aA1 = 0.f, aP0 = 0.f, aP1 = 0.f;
        for (int j = 0; j < jm; j += 2) {     // zero-padded -> branch-free
            aA0 += vAa[j] * ga[cAa[j] * H_ + lane] + vAa[j+1] * ga[cAa[j+1] * H_ + lane];
            aA1 += vAb[j] * gb[cAb[j] * H_ + lane] + vAb[j+1] * gb[cAb[j+1] * H_ + lane];
            aP0 += vPa[j] * ga[cPa[j] * H_ + lane] + vPa[j+1] * ga[cPa[j+1] * H_ + lane];
            aP1 += vPb[j] * gb[cPb[j] * H_ + lane] + vPb[j+1] * gb[cPb[j+1] * H_ + lane];
        }
        int r0 = (w * 8 + pp) * 68 + lane;
        Ma[r0] = aA0;  Ma[r0 + 68] = aA1;
        Mp[r0] = aP0;  Mp[r0 + 68] = aP1;
    }

    int tx = t & 15, ty = t >> 4;
    for (int sc = 0; sc < 8; ++sc) {
        int stack = sc >> 2, c = sc & 3;
        const float* wb0 = (stack ? wpea : wadj) + (size_t)c * 16384;   // (c*2+0)*2*4096
        const float* wb1 = wb0 + 4096;
        __syncthreads();   // gather done (sc=0) / prev Ws reads done (sc>0)
        #pragma unroll
        for (int i = 0; i < 4; ++i) {
            int f4 = t + i * 256;
            int row = f4 >> 4, col = (f4 & 15) * 4;
            float4 x0 = *(const float4*)&wb0[row * 64 + col];
            float4 x1 = *(const float4*)&wb1[row * 64 + col];
            *(float4*)&Ws[row * 68 + col] = make_float4(x0.x + x1.x, x0.y + x1.y,
                                                        x0.z + x1.z, x0.w + x1.w);
        }
        __syncthreads();

        const float* Msrc = stack ? Mp : Ma;
        float4 acc0 = make_float4(0.f, 0.f, 0.f, 0.f);
        float4 acc1 = make_float4(0.f, 0.f, 0.f, 0.f);
        #pragma unroll 8
        for (int k4 = 0; k4 < 64; k4 += 4) {
            float4 A0 = *(const float4*)&Msrc[ty * 68 + k4];
            float4 A1 = *(const float4*)&Msrc[(ty + 16) * 68 + k4];
            float4 W0 = *(const float4*)&Ws[(k4 + 0) * 68 + 4 * tx];
            float4 W1 = *(const float4*)&Ws[(k4 + 1) * 68 + 4 * tx];
            float4 W2 = *(const float4*)&Ws[(k4 + 2) * 68 + 4 * tx];
            float4 W3 = *(const float4*)&Ws[(k4 + 3) * 68 + 4 * tx];
            acc0.x += A0.x*W0.x + A0.y*W1.x + A0.z*W2.x + A0.w*W3.x;
            acc0.y += A0.x*W0.y + A0.y*W1.y + A0.z*W2.y + A0.w*W3.y;
            acc0.z += A0.x*W0.z + A0.y*W1.z + A0.z*W2.z + A0.w*W3.z;
            acc0.w += A0.x*W0.w + A0.y*W1.w + A0.z*W2.w + A0.w*W3.w;
            acc1.x += A1.x*W0.x + A1.y*W1.x + A1.z*W2.x + A1.w*W3.x;
            acc1.y += A1.x*W0.y + A1.y*W1.y + A1.z*W2.y + A1.w*W3.y;
            acc1.z += A1.x*W0.z + A1.y*W1.z + A1.z*W2.z + A1.w*W3.z;
            acc1.w += A1.x*W0.w + A1.y*W1.w + A1.z*W2.w + A1.w*W3.w;
        }
        const float* bias = (stack ? bpea : badj) + c * L_ * H_;   // layer 0
        float4 bi = *(const float4*)&bias[4 * tx];
        float* Gout = stack ? G1p : G1a;
        #pragma unroll
        for (int r = 0; r < 2; ++r) {
            float4 a = r ? acc1 : acc0;
            float v0 = a.x + bi.x; v0 = v0 > 0.f ? v0 : 0.f;
            float v1 = a.y + bi.y; v1 = v1 > 0.f ? v1 : 0.f;
            float v2 = a.z + bi.z; v2 = v2 > 0.f ? v2 : 0.f;
            float v3 = a.w + bi.w; v3 = v3 > 0.f ? v3 : 0.f;
            *(float4*)&Gout[(size_t)(m0 + ty + 16 * r) * 256 + c * 64 + 4 * tx] =
                make_float4(v0, v1, v2, v3);
        }
    }
}

// ---------------------------------------------------------------------------
// K3: layer 2 + gate mix, both stacks, register-carry between stacks.
// Full-row float4 gather (4 b128 in flight) -> Mt[32x260]; per-c 32x64x64 GEMM.
// gr = gate * relu(Aa@G1a@WA + bA) + (1-gate) * relu(Ap@G1p@WP + bP)
__global__ __launch_bounds__(256, 3) void k_mix(
    const int*   __restrict__ cnt,
    const int*   __restrict__ cols,
    const float* __restrict__ vals,
    const float* __restrict__ G1a, const float* __restrict__ G1p,  // [M][256]
    const float* __restrict__ wadj, const float* __restrict__ badj,
    const float* __restrict__ wpea, const float* __restrict__ bpea,
    const float* __restrict__ gate,   // [M][256]
    float* __restrict__ gr)           // [M][256]
{
    __shared__ float Mt[32 * 260];
    __shared__ float Ws[64 * 68];
    int t = threadIdx.x, lane = t & 63, w = t >> 6;
    int vb = (blockIdx.x & 7) * 82 + (blockIdx.x >> 3);   // XCD swizzle
    if (vb >= 650) return;
    int m0 = vb * 32;
    int tx = t & 15, ty = t >> 4;

    float4 res[4][2];   // gate * relu(adj-stack value), carried across stacks
    float4 gsv[4][2];   // saved gate

    // ======== stack A: gather full 256-wide rows of A_adj @ G1a ========
    for (int pp = 0; pp < 8; pp += 2) {
        int ma = m0 + w * 8 + pp, mb = ma + 1;
        int na = ma % N_, nb = mb % N_;
        const float* ga = G1a + (size_t)(ma - na) * 256;
        const float* gb = G1a + (size_t)(mb - nb) * 256;
        const int   *cap = cols + na * NNZCAP, *cbp = cols + nb * NNZCAP;
        const float *vap = vals + na * NNZCAP, *vbp = vals + nb * NNZCAP;
        int jm = max(cnt[na], cnt[nb]);
        float4 a0 = make_float4(0.f,0.f,0.f,0.f), a1 = make_float4(0.f,0.f,0.f,0.f);
        for (int j = 0; j < jm; j += 2) {     // zero-padded -> branch-free
            float w00 = vap[j], w01 = vap[j+1];
            float w10 = vbp[j], w11 = vbp[j+1];
            float4 x00 = *(const float4*)&ga[cap[j] * 256 + lane * 4];
            float4 x01 = *(const float4*)&ga[cap[j+1] * 256 + lane * 4];
            float4 x10 = *(const float4*)&gb[cbp[j] * 256 + lane * 4];
            float4 x11 = *(const float4*)&gb[cbp[j+1] * 256 + lane * 4];
            a0.x += w00*x00.x + w01*x01.x;  a0.y += w00*x00.y + w01*x01.y;
            a0.z += w00*x00.z + w01*x01.z;  a0.w += w00*x00.w + w01*x01.w;
            a1.x += w10*x10.x + w11*x11.x;  a1.y += w10*x10.y + w11*x11.y;
            a1.z += w10*x10.z + w11*x11.z;  a1.w += w10*x10.w + w11*x11.w;
        }
        *(float4*)&Mt[(w * 8 + pp) * 260 + lane * 4]     = a0;
        *(float4*)&Mt[(w * 8 + pp + 1) * 260 + lane * 4] = a1;
    }

    #pragma unroll
    for (int c = 0; c < 4; ++c) {
        __syncthreads();   // gather visible (c=0) / prev Ws reads done (c>0)
        const float* w0 = wadj + (size_t)c * 16384 + 8192;   // layer 1
        const float* w1 = w0 + 4096;
        #pragma unroll
        for (int i = 0; i < 4; ++i) {
            int f4 = t + i * 256;
            int row = f4 >> 4, col = (f4 & 15) * 4;
            float4 x0 = *(const float4*)&w0[row * 64 + col];
            float4 x1 = *(const float4*)&w1[row * 64 + col];
            *(float4*)&Ws[row * 68 + col] = make_float4(x0.x + x1.x, x0.y + x1.y,
                                                        x0.z + x1.z, x0.w + x1.w);
        }
        __syncthreads();
        float4 acc0 = make_float4(0.f,0.f,0.f,0.f), acc1 = make_float4(0.f,0.f,0.f,0.f);
        #pragma unroll 8
        for (int k4 = 0; k4 < 64; k4 += 4) {
            float4 A0 = *(const float4*)&Mt[ty * 260 + c * 64 + k4];
            float4 A1 = *(const float4*)&Mt[(ty + 16) * 260 + c * 64 + k4];
            float4 W0 = *(const float4*)&Ws[(k4 + 0) * 68 + 4 * tx];
            float4 W1 = *(const float4*)&Ws[(k4 + 1) * 68 + 4 * tx];
            float4 W2 = *(const float4*)&Ws[(k4 + 2) * 68 + 4 * tx];
            float4 W3 = *(const float4*)&Ws[(k4 + 3) * 68 + 4 * tx];
            acc0.x += A0.x*W0.x + A0.y*W1.x + A0.z*W2.x + A0.w*W3.x;
            acc0.y += A0.x*W0.y + A0.y*W1.y + A0.z*W2.y + A0.w*W3.y;
            acc0.z += A0.x*W0.z + A0.y*W1.z + A0.z*W2.z + A0.w*W3.z;
            acc0.w += A0.x*W0.w + A0.y*W1.w + A0.z*W2.w + A0.w*W3.w;
            acc1.x += A1.x*W0.x + A1.y*W1.x + A1.z*W2.x + A1.w*W3.x;
            acc1.y += A1.x*W0.y + A1.y*W1.y + A1.z*W2.y + A1.w*W3.y;
            acc1.z += A1.x*W0.z + A1.y*W1.z + A1.z*W2.z + A1.w*W3.z;
            acc1.w += A1.x*W0.w + A1.y*W1.w + A1.z*W2.w + A1.w*W3.w;
        }
        float4 bA = *(const float4*)&badj[(c * L_ + 1) * H_ + 4 * tx];
        #pragma unroll
        for (int r = 0; r < 2; ++r) {
            float4 a = r ? acc1 : acc0;
            float v0 = a.x + bA.x; v0 = v0 > 0.f ? v0 : 0.f;
            float v1 = a.y + bA.y; v1 = v1 > 0.f ? v1 : 0.f;
            float v2 = a.z + bA.z; v2 = v2 > 0.f ? v2 : 0.f;
            float v3 = a.w + bA.w; v3 = v3 > 0.f ? v3 : 0.f;
            size_t o = (size_t)(m0 + ty + 16 * r) * 256 + c * 64 + 4 * tx;
            float4 g = *(const float4*)&gate[o];
            gsv[c][r] = g;
            res[c][r] = make_float4(g.x * v0, g.y * v1, g.z * v2, g.w * v3);
        }
    }

    // ======== stack P: re-gather into Mt, combine, write once ========
    __syncthreads();   // all Mt reads done before overwrite
    for (int pp = 0; pp < 8; pp += 2) {
        int ma = m0 + w * 8 + pp, mb = ma + 1;
        int na = ma % N_, nb = mb % N_;
        const float* ga = G1p + (size_t)(ma - na) * 256;
        const float* gb = G1p + (size_t)(mb - nb) * 256;
        const int   *cap = cols + (N_ + na) * NNZCAP, *cbp = cols + (N_ + nb) * NNZCAP;
        const float *vap = vals + (N_ + na) * NNZCAP, *vbp = vals + (N_ + nb) * NNZCAP;
        int jm = max(cnt[N_ + na], cnt[N_ + nb]);
        float4 a0 = make_float4(0.f,0.f,0.f,0.f), a1 = make_float4(0.f,0.f,0.f,0.f);
        for (int j = 0; j < jm; j += 2) {
            float w00 = vap[j], w01 = vap[j+1];
            float w10 = vbp[j], w11 = vbp[j+1];
            float4 x00 = *(const float4*)&ga[cap[j] * 256 + lane * 4];
            float4 x01 = *(const float4*)&ga[cap[j+1] * 256 + lane * 4];
            float4 x10 = *(const float4*)&gb[cbp[j] * 256 + lane * 4];
            float4 x11 = *(const float4*)&gb[cbp[j+1] * 256 + lane * 4];
            a0.x += w00*x00.x + w01*x01.x;  a0.y += w00*x00.y + w01*x01.y;
            a0.z += w00*x00.z + w01*x01.z;  a0.w += w00*x00.w + w01*x01.w;
            a1.x += w10*x10.x + w11*x11.x;  a1.y += w10*x10.y + w11*x11.y;
            a1.z += w10*x10.z + w11*x11.z;  a1.w += w10*x10.w + w11*x11.w;
        }
        *(float4*)&Mt[(w * 8 + pp) * 260 + lane * 4]     = a0;
        *(float4*)&Mt[(w * 8 + pp + 1) * 260 + lane * 4] = a1;
    }

    #pragma unroll
    for (int c = 0; c < 4; ++c) {
        __syncthreads();
        const float* w0 = wpea + (size_t)c * 16384 + 8192;   // layer 1
        const float* w1 = w0 + 4096;
        #pragma unroll
        for (int i = 0; i < 4; ++i) {
            int f4 = t + i * 256;
            int row = f4 >> 4, col = (f4 & 15) * 4;
            float4 x0 = *(const float4*)&w0[row * 64 + col];
            float4 x1 = *(const float4*)&w1[row * 64 + col];
            *(float4*)&Ws[row * 68 + col] = make_float4(x0.x + x1.x, x0.y + x1.y,
                                                        x0.z + x1.z, x0.w + x1.w);
        }
        __syncthreads();
        float4 acc0 = make_float4(0.f,0.f,0.f,0.f), acc1 = make_float4(0.f,0.f,0.f,0.f);
        #pragma unroll 8
        for (int k4 = 0; k4 < 64; k4 += 4) {
            float4 A0 = *(const float4*)&Mt[ty * 260 + c * 64 + k4];
            float4 A1 = *(const float4*)&Mt[(ty + 16) * 260 + c * 64 + k4];
            float4 W0 = *(const float4*)&Ws[(k4 + 0) * 68 + 4 * tx];
            float4 W1 = *(const float4*)&Ws[(k4 + 1) * 68 + 4 * tx];
            float4 W2 = *(const float4*)&Ws[(k4 + 2) * 68 + 4 * tx];
            float4 W3 = *(const float4*)&Ws[(k4 + 3) * 68 + 4 * tx];
            acc0.x += A0.x*W0.x + A0.y*W1.x + A0.z*W2.x + A0.w*W3.x;
            acc0.y += A0.x*W0.y + A0.y*W1.y + A0.z*W2.y + A0.w*W3.y;
            acc0.z += A0.x*W0.z + A0.y*W1.z + A0.z*W2.z + A0.w*W3.z;
            acc0.w += A0.x*W0.w + A0.y*W1.w + A0.z*W2.w + A0.w*W3.w;
            acc1.x += A1.x*W0.x + A1.y*W1.x + A1.z*W2.x + A1.w*W3.x;
            acc1.y += A1.x*W0.y + A1.y*W1.y + A1.z*W2.y + A1.w*W3.y;
            acc1.z += A1.x*W0.z + A1.y*W1.z + A1.z*W2.z + A1.w*W3.z;
            acc1.w += A1.x*W0.w + A1.y*W1.w + A1.z*W2.w + A1.w*W3.w;
        }
        float4 bP = *(const float4*)&bpea[(c * L_ + 1) * H_ + 4 * tx];
        #pragma unroll
        for (int r = 0; r < 2; ++r) {
            float4 p = r ? acc1 : acc0;
            float v0 = p.x + bP.x; v0 = v0 > 0.f ? v0 : 0.f;
            float v1 = p.y + bP.y; v1 = v1 > 0.f ? v1 : 0.f;
            float v2 = p.z + bP.z; v2 = v2 > 0.f ? v2 : 0.f;
            float v3 = p.w + bP.w; v3 = v3 > 0.f ? v3 : 0.f;
            float4 g  = gsv[c][r];
            float4 rr = res[c][r];
            size_t o = (size_t)(m0 + ty + 16 * r) * 256 + c * 64 + 4 * tx;
            *(float4*)&gr[o] = make_float4(rr.x + (1.f - g.x) * v0,
                                           rr.y + (1.f - g.y) * v1,
                                           rr.z + (1.f - g.z) * v2,
                                           rr.w + (1.f - g.w) * v3);
        }
    }
}

// ---------------------------------------------------------------------------
// K4: cr = gr @ reduce_w + reduce_b + residual, with fused partial sums
__global__ __launch_bounds__(256) void k_reduce(const float* __restrict__ in,
                                                const float* __restrict__ W,
                                                const float* __restrict__ bias,
                                                const float* __restrict__ residual,
                                                float* __restrict__ cr,
                                                float* __restrict__ partials) {
    __shared__ float Is[64][17];
    __shared__ float Ws[16][65];
    __shared__ float r1[256], r2[256];
    int t = threadIdx.x, tx = t & 15, ty = t >> 4;
    int m0 = blockIdx.x * 64;
    float acc[4][4];
    #pragma unroll
    for (int i = 0; i < 4; ++i)
        #pragma unroll
        for (int j = 0; j < 4; ++j) acc[i][j] = 0.f;
    for (int kk = 0; kk < 256; kk += 16) {
        #pragma unroll
        for (int i = 0; i < 4; ++i) { int e = t + i*256; int r = e>>4, kc = e&15;
            Is[r][kc] = in[(size_t)(m0 + r) * 256 + kk + kc]; }
        #pragma unroll
        for (int i = 0; i < 4; ++i) { int e = t + i*256; int r = e>>6, cc = e&63;
            Ws[r][cc] = W[(size_t)(kk + r) * 64 + cc]; }
        __syncthreads();
        #pragma unroll
        for (int k = 0; k < 16; ++k) {
            float a0 = Is[ty][k], a1 = Is[ty+16][k], a2 = Is[ty+32][k], a3 = Is[ty+48][k];
            float b0 = Ws[k][tx], b1 = Ws[k][tx+16], b2 = Ws[k][tx+32], b3 = Ws[k][tx+48];
            FMA16
        }
        __syncthreads();
    }
    float s = 0.f, s2 = 0.f;
    #pragma unroll
    for (int i = 0; i < 4; ++i) {
        int r = m0 + ty + 16 * i;
        #pragma unroll
        for (int j = 0; j < 4; ++j) {
            int cc = tx + 16 * j;
            float v = acc[i][j] + bias[cc] + residual[(size_t)r * 64 + cc];
            cr[(size_t)r * 64 + cc] = v;
            s += v; s2 += v * v;
        }
    }
    r1[t] = s; r2[t] = s2;
    __syncthreads();
    for (int off = 128; off > 0; off >>= 1) {
        if (t < off) { r1[t] += r1[t + off]; r2[t] += r2[t + off]; }
        __syncthreads();
    }
    if (t == 0) { partials[blockIdx.x] = r1[0]; partials[325 + blockIdx.x] = r2[0]; }
}

// K5: finalize mu/var (redundantly per block) + normalize (grid 325)
__global__ void k_norm(const float* __restrict__ cr, const float* __restrict__ partials,
                       float* __restrict__ last) {
    __shared__ float s1[256], s2[256];
    int t = threadIdx.x;
    float a = 0.f, b = 0.f;
    for (int i = t; i < 325; i += 256) { a += partials[i]; b += partials[325 + i]; }
    s1[t] = a; s2[t] = b;
    __syncthreads();
    for (int off = 128; off > 0; off >>= 1) {
        if (t < off) { s1[t] += s1[t + off]; s2[t] += s2[t + off]; }
        __syncthreads();
    }
    const float inv = 1.f / (float)(M_ * H_);
    float mu  = s1[0] * inv;
    float var = s2[0] * inv - mu * mu;
    float rs  = rsqrtf(var + 1e-5f);
    int base = blockIdx.x * 4096 + t * 4;
    #pragma unroll
    for (int i = 0; i < 4; ++i) {
        float4 v = *(const float4*)&cr[base + i * 1024];
        *(float4*)&last[base + i * 1024] =
            make_float4((v.x - mu) * rs, (v.y - mu) * rs, (v.z - mu) * rs, (v.w - mu) * rs);
    }
}

// ---------------------------------------------------------------------------
// K6: out[b,p,n] = sum_h relu(ocw[p]*last[b,n,h] + ocb[p]) * olw[h] + olb
__global__ void k_out(const float* __restrict__ last,
                      const float* __restrict__ ocw, const float* __restrict__ ocb,
                      const float* __restrict__ olw, const float* __restrict__ olb,
                      float* __restrict__ out) {
    int m = blockIdx.x * 256 + threadIdx.x;
    if (m >= M_) return;
    int b = m / N_, n = m % N_;
    float cw[P_], cb[P_], acc[P_];
    #pragma unroll
    for (int p = 0; p < P_; ++p) { cw[p] = ocw[p]; cb[p] = ocb[p]; acc[p] = 0.f; }
    const float* lr = last + (size_t)m * H_;
    for (int h = 0; h < H_; ++h) {
        float lv = lr[h], wv = olw[h];
        #pragma unroll
        for (int p = 0; p < P_; ++p) {
            float u = cw[p] * lv + cb[p];
            u = u > 0.f ? u : 0.f;
            acc[p] += u * wv;
        }
    }
    float ob = olb[0];
    #pragma unroll
    for (int p = 0; p < P_; ++p)
        out[(size_t)(b * P_ + p) * N_ + n] = acc[p] + ob;
}

// ---------------------------------------------------------------------------
extern "C" void kernel_launch(void* const* d_in, const int* in_sizes, int n_in,
                              void* d_out, int out_size, void* d_ws, size_t ws_size,
                              hipStream_t stream) {
    const float* inp      = (const float*)d_in[0];
    const float* adj_fwd  = (const float*)d_in[1];
    const float* pea_fwd  = (const float*)d_in[3];
    const float* w_in     = (const float*)d_in[5];
    const float* b_in     = (const float*)d_in[6];
    const float* res_w    = (const float*)d_in[7];
    const float* res_b    = (const float*)d_in[8];
    const float* gconv_w  = (const float*)d_in[9];
    const float* gconv_b  = (const float*)d_in[10];
    const float* gate1_w  = (const float*)d_in[11];
    const float* gate1_b  = (const float*)d_in[12];
    const float* gate2_w  = (const float*)d_in[13];
    const float* gate2_b  = (const float*)d_in[14];
    const float* reduce_w = (const float*)d_in[15];
    const float* reduce_b = (const float*)d_in[16];
    const float* gadj_w   = (const float*)d_in[17];
    const float* gadj_b   = (const float*)d_in[18];
    const float* gpea_w   = (const float*)d_in[19];
    const float* gpea_b   = (const float*)d_in[20];
    const float* ocw      = (const float*)d_in[21];
    const float* ocb      = (const float*)d_in[22];
    const float* olw      = (const float*)d_in[23];
    const float* olb      = (const float*)d_in[24];
    float* out = (float*)d_out;

    // workspace layout (floats) — ~96 MB
    float* ws       = (float*)d_ws;
    float* g_init   = ws;                              // M*64
    float* G1a      = g_init + (size_t)M_ * H_;        // M*256  (aliases `last`)
    float* G1p      = G1a + (size_t)M_ * 256;          // M*256
    float* gate     = G1p + (size_t)M_ * 256;          // M*256  (aliases `cr`)
    float* gr       = gate + (size_t)M_ * 256;         // M*256
    float* residual = gr + (size_t)M_ * 256;           // M*64
    float* partials = residual + (size_t)M_ * H_;      // 650
    int*   scnt  = (int*)(partials + 650);             // 2*325
    int*   scols = scnt + 2 * N_;                      // 2*325*64
    float* svals = (float*)(scols + 2 * N_ * NNZCAP);  // 2*325*64
    float* last = G1a;    // norm(it) -> k_gate(it+1) reads it -> k_layer1 overwrites
    float* cr   = gate;   // gate dead after k_mix; reduce writes, norm reads

    k_build_sparse<<<N_, 64, 0, stream>>>(adj_fwd, scnt,      scols,              svals);
    k_build_sparse<<<N_, 64, 0, stream>>>(pea_fwd, scnt + N_, scols + N_*NNZCAP,  svals + N_*NNZCAP);

    for (int it = 0; it < KCP; ++it) {
        k_gate<<<M_ / 64, 256, 0, stream>>>(
            inp, w_in, b_in, gconv_w, gconv_b, res_w, res_b, last, it,
            gate1_w, gate1_b, gate2_w, gate2_b, residual, g_init, gate);
        k_layer1<<<656, 256, 0, stream>>>(
            scnt, scols, svals, g_init, gadj_w, gadj_b, gpea_w, gpea_b, G1a, G1p);
        k_mix<<<656, 256, 0, stream>>>(
            scnt, scols, svals, G1a, G1p, gadj_w, gadj_b, gpea_w, gpea_b, gate, gr);
        k_reduce<<<M_ / 64, 256, 0, stream>>>(gr, reduce_w, reduce_b, residual, cr, partials);
        k_norm<<<325, 256, 0, stream>>>(cr, partials, last);
    }

    k_out<<<(M_ + 255) / 256, 256, 0, stream>>>(last, ocw, ocb, olw, olb, out);
}

// Round 9
// 817.961 us; speedup vs baseline: 1.8029x; 1.0970x over previous
//
#include <hip/hip_runtime.h>
#include <hip/hip_bf16.h>
#include <math.h>

// Problem constants
#define B_    64
#define T_    13
#define N_    325
#define H_    64
#define C_    4
#define L_    2
#define S_    4
#define P_    12
#define KCP   4            // checkpoints [4,7,10,13]
#define M_    (B_*N_)      // 20800 (= 650*32 exactly)
#define ADJLD 1300         // leading dim of combined adjacency inputs
#define NNZCAP 64          // max nonzeros per adjacency row (3% density -> mean ~10)

#define FMA16 \
  acc[0][0]+=a0*b0; acc[0][1]+=a0*b1; acc[0][2]+=a0*b2; acc[0][3]+=a0*b3; \
  acc[1][0]+=a1*b0; acc[1][1]+=a1*b1; acc[1][2]+=a1*b2; acc[1][3]+=a1*b3; \
  acc[2][0]+=a2*b0; acc[2][1]+=a2*b1; acc[2][2]+=a2*b2; acc[2][3]+=a2*b3; \
  acc[3][0]+=a3*b0; acc[3][1]+=a3*b1; acc[3][2]+=a3*b2; acc[3][3]+=a3*b3;

__device__ __forceinline__ void fma4(float4& a, float s, float4 x) {
    a.x += s * x.x; a.y += s * x.y; a.z += s * x.z; a.w += s * x.w;
}

// ---------------------------------------------------------------------------
// Build padded sparse rows (column-ordered, deterministic). One wave per row.
__global__ void k_build_sparse(const float* __restrict__ A,
                               int* __restrict__ cnt, int* __restrict__ cols,
                               float* __restrict__ vals) {
    int n    = blockIdx.x;
    int lane = threadIdx.x;
    const float* row = A + (size_t)n * ADJLD;
    int c = 0;
    for (int c0 = 0; c0 < 384; c0 += 64) {
        int col = c0 + lane;
        float v = (col < N_) ? row[col] : 0.f;
        unsigned long long m = __ballot(v != 0.f);
        int idx = c + __popcll(m & ((1ull << lane) - 1ull));
        if (v != 0.f && idx < NNZCAP) {
            cols[n * NNZCAP + idx] = col;
            vals[n * NNZCAP + idx] = v;
        }
        c += __popcll(m);
    }
    if (c + lane < NNZCAP) {                 // zero-pad tail -> branch-free consumers
        cols[n * NNZCAP + c + lane] = 0;
        vals[n * NNZCAP + c + lane] = 0.f;
    }
    if (lane == 0) cnt[n] = (c < NNZCAP) ? c : NNZCAP;
}

// ---------------------------------------------------------------------------
// K1: fused [norm of prev cr] + gf/residual/g_init + 2-layer gate MLP.
__global__ __launch_bounds__(256, 3) void k_gate(
    const float* __restrict__ inp,
    const float* __restrict__ w_in, const float* __restrict__ b_in,
    const float* __restrict__ gconv_w, const float* __restrict__ gconv_b,
    const float* __restrict__ res_w,   const float* __restrict__ res_b,
    const float* __restrict__ cr, const float* __restrict__ partials, int it,
    const float* __restrict__ W1, const float* __restrict__ b1,
    const float* __restrict__ W2, const float* __restrict__ b2,
    float* __restrict__ residual, float* __restrict__ g_init,
    float* __restrict__ gate)
{
    __shared__ float Gf[64 * 68];
    __shared__ float Ws[64 * 68];
    __shared__ float Gr[64 * 68];
    int t = threadIdx.x, lane = t & 63, w = t >> 6;
    int m0 = blockIdx.x * 64;

    // ---- phase -1: LayerNorm constants from partials (it>0) ----
    float mu = 0.f, rs = 0.f;
    if (it > 0) {
        float a = 0.f, b = 0.f;
        for (int i = t; i < 325; i += 256) { a += partials[i]; b += partials[325 + i]; }
        Ws[t] = a; Ws[256 + t] = b;
        __syncthreads();
        for (int off = 128; off > 0; off >>= 1) {
            if (t < off) { Ws[t] += Ws[t + off]; Ws[256 + t] += Ws[256 + t + off]; }
            __syncthreads();
        }
        const float inv = 1.f / (float)(M_ * H_);
        mu = Ws[0] * inv;
        float var = Ws[256] * inv - mu * mu;
        rs = rsqrtf(var + 1e-5f);
        __syncthreads();   // reduction reads done before W1 staging overwrites Ws
    }

    // ---- phase 0: gf / residual / g_init ----
    {
        float wa = w_in[lane], wb = w_in[H_ + lane], bi = b_in[lane];
        float gw0 = gconv_w[0], gw1 = gconv_w[1], gw2 = gconv_w[2], gw3 = gconv_w[3];
        float rw0 = res_w[0],   rw1 = res_w[1],   rw2 = res_w[2],   rw3 = res_w[3];
        float gb = gconv_b[0],  rb = res_b[0];
        int left = (it == 0) ? 0 : (3 * it + 1);
        for (int i = 0; i < 16; ++i) {
            int r = i * 4 + w;                  // wave-uniform row
            int m = m0 + r;
            int b = m / N_, n = m % N_;
            const float* ipb = inp + ((size_t)b * T_ * N_ + n) * 2;
            float v0;
            if (it > 0) v0 = (cr[(size_t)m * H_ + lane] - mu) * rs;
            else        { v0 = ipb[0] * wa + ipb[1] * wb + bi; }
            int t1 = (it == 0) ? 1 : left;
            const float* ip1 = ipb + (size_t)t1 * N_ * 2;
            const float* ip2 = ip1 + (size_t)N_ * 2;
            const float* ip3 = ip2 + (size_t)N_ * 2;
            float v1 = ip1[0] * wa + ip1[1] * wb + bi;
            float v2 = ip2[0] * wa + ip2[1] * wb + bi;
            float v3 = ip3[0] * wa + ip3[1] * wb + bi;
            Gf[r * 68 + lane] = gb + gw0 * v0 + gw1 * v1 + gw2 * v2 + gw3 * v3;
            residual[(size_t)m * H_ + lane] = rb + rw0 * v0 + rw1 * v1 + rw2 * v2 + rw3 * v3;
            g_init[(size_t)m * H_ + lane] = v3;
        }
    }
    // stage W1
    #pragma unroll
    for (int i = 0; i < 4; ++i) {
        int f4 = t + i * 256;
        int row = f4 >> 4, col = (f4 & 15) * 4;
        *(float4*)&Ws[row * 68 + col] = *(const float4*)&W1[row * 64 + col];
    }
    __syncthreads();

    int tx = t & 15, ty = t >> 4;
    float acc[4][4];
    #pragma unroll
    for (int i = 0; i < 4; ++i)
        #pragma unroll
        for (int j = 0; j < 4; ++j) acc[i][j] = 0.f;
    #pragma unroll 16
    for (int k = 0; k < 64; ++k) {
        float a0 = Gf[ty * 68 + k];
        float a1 = Gf[(ty + 16) * 68 + k];
        float a2 = Gf[(ty + 32) * 68 + k];
        float a3 = Gf[(ty + 48) * 68 + k];
        float4 wv = *(const float4*)&Ws[k * 68 + 4 * tx];
        float b0 = wv.x, b1v = wv.y, b2v = wv.z, b3 = wv.w;
        { float b1 = b1v, b2 = b2v; FMA16 }
    }
    float4 bi1 = *(const float4*)&b1[4 * tx];
    #pragma unroll
    for (int i = 0; i < 4; ++i) {
        float v0 = acc[i][0] + bi1.x; v0 = v0 > 0.f ? v0 : 0.f;
        float v1 = acc[i][1] + bi1.y; v1 = v1 > 0.f ? v1 : 0.f;
        float v2 = acc[i][2] + bi1.z; v2 = v2 > 0.f ? v2 : 0.f;
        float v3 = acc[i][3] + bi1.w; v3 = v3 > 0.f ? v3 : 0.f;
        *(float4*)&Gr[(ty + 16 * i) * 68 + 4 * tx] = make_float4(v0, v1, v2, v3);
    }
    for (int ch = 0; ch < 4; ++ch) {
        __syncthreads();
        #pragma unroll
        for (int i = 0; i < 4; ++i) {
            int f4 = t + i * 256;
            int row = f4 >> 4, col = (f4 & 15) * 4;
            *(float4*)&Ws[row * 68 + col] =
                *(const float4*)&W2[(size_t)row * 256 + ch * 64 + col];
        }
        __syncthreads();
        float acc2[4][4];
        #pragma unroll
        for (int i = 0; i < 4; ++i)
            #pragma unroll
            for (int j = 0; j < 4; ++j) acc2[i][j] = 0.f;
        #pragma unroll 16
        for (int k = 0; k < 64; ++k) {
            float a0 = Gr[ty * 68 + k];
            float a1 = Gr[(ty + 16) * 68 + k];
            float a2 = Gr[(ty + 32) * 68 + k];
            float a3 = Gr[(ty + 48) * 68 + k];
            float4 wv = *(const float4*)&Ws[k * 68 + 4 * tx];
            float b0 = wv.x, b1v = wv.y, b2v = wv.z, b3 = wv.w;
            { float b1 = b1v, b2 = b2v; float (*acc)[4] = acc2; FMA16 }
        }
        float4 bi2 = *(const float4*)&b2[ch * 64 + 4 * tx];
        #pragma unroll
        for (int i = 0; i < 4; ++i) {
            int m = m0 + ty + 16 * i;
            float g0 = 1.f / (1.f + expf(-(acc2[i][0] + bi2.x)));
            float g1 = 1.f / (1.f + expf(-(acc2[i][1] + bi2.y)));
            float g2 = 1.f / (1.f + expf(-(acc2[i][2] + bi2.z)));
            float g3 = 1.f / (1.f + expf(-(acc2[i][3] + bi2.w)));
            *(float4*)&gate[(size_t)m * 256 + ch * 64 + 4 * tx] = make_float4(g0, g1, g2, g3);
        }
    }
}

// ---------------------------------------------------------------------------
// K2: layer 1, both stacks. Gather with 4-rows-per-load float4 (16 lanes/row):
// 4 streams x unroll 2 = 8 x 1KB loads in flight. Then 8 GEMMs.
__global__ __launch_bounds__(256, 4) void k_layer1(
    const int*   __restrict__ cnt,    // [2N]  adj rows 0..N, pea rows N..2N
    const int*   __restrict__ cols,   // [2N][NNZCAP]
    const float* __restrict__ vals,
    const float* __restrict__ g_init, // [M][64]
    const float* __restrict__ wadj, const float* __restrict__ badj,
    const float* __restrict__ wpea, const float* __restrict__ bpea,
    float* __restrict__ G1a, float* __restrict__ G1p)   // [M][256]
{
    __shared__ float Ma[32 * 68];
    __shared__ float Mp[32 * 68];
    __shared__ float Ws[64 * 68];
    int t = threadIdx.x, lane = t & 63, w = t >> 6;
    int vb = (blockIdx.x & 7) * 82 + (blockIdx.x >> 3);   // XCD swizzle
    if (vb >= 650) return;
    int m0 = vb * 32;

    // ---- gather: lane=(rr,cl); rows w*8+rr and w*8+4+rr, both stacks ----
    {
        int cl = lane & 15, rr = lane >> 4;
        int mA = m0 + w * 8 + rr;
        int mB = mA + 4;
        int nA = mA % N_, nB = mB % N_;
        const float* gA = g_init + (size_t)(mA - nA) * H_ + cl * 4;
        const float* gB = g_init + (size_t)(mB - nB) * H_ + cl * 4;
        const int   *cA0 = cols + nA * NNZCAP,        *cB0 = cols + nB * NNZCAP;
        const float *vA0 = vals + nA * NNZCAP,        *vB0 = vals + nB * NNZCAP;
        const int   *cA1 = cols + (N_ + nA) * NNZCAP, *cB1 = cols + (N_ + nB) * NNZCAP;
        const float *vA1 = vals + (N_ + nA) * NNZCAP, *vB1 = vals + (N_ + nB) * NNZCAP;
        int jm = max(max(cnt[nA], cnt[nB]), max(cnt[N_ + nA], cnt[N_ + nB]));
        float4 aA0 = make_float4(0.f,0.f,0.f,0.f), aB0 = make_float4(0.f,0.f,0.f,0.f);
        float4 aA1 = make_float4(0.f,0.f,0.f,0.f), aB1 = make_float4(0.f,0.f,0.f,0.f);
        for (int j = 0; j < jm; j += 2) {     // zero-padded -> branch-free
            fma4(aA0, vA0[j],   *(const float4*)&gA[cA0[j]   * H_]);
            fma4(aA0, vA0[j+1], *(const float4*)&gA[cA0[j+1] * H_]);
            fma4(aB0, vB0[j],   *(const float4*)&gB[cB0[j]   * H_]);
            fma4(aB0, vB0[j+1], *(const float4*)&gB[cB0[j+1] * H_]);
            fma4(aA1, vA1[j],   *(const float4*)&gA[cA1[j]   * H_]);
            fma4(aA1, vA1[j+1], *(const float4*)&gA[cA1[j+1] * H_]);
            fma4(aB1, vB1[j],   *(const float4*)&gB[cB1[j]   * H_]);
            fma4(aB1, vB1[j+1], *(const float4*)&gB[cB1[j+1] * H_]);
        }
        *(float4*)&Ma[(w * 8 + rr) * 68 + cl * 4]     = aA0;
        *(float4*)&Ma[(w * 8 + 4 + rr) * 68 + cl * 4] = aB0;
        *(float4*)&Mp[(w * 8 + rr) * 68 + cl * 4]     = aA1;
        *(float4*)&Mp[(w * 8 + 4 + rr) * 68 + cl * 4] = aB1;
    }

    int tx = t & 15, ty = t >> 4;
    for (int sc = 0; sc < 8; ++sc) {
        int stack = sc >> 2, c = sc & 3;
        const float* wb0 = (stack ? wpea : wadj) + (size_t)c * 16384;   // layer 0
        const float* wb1 = wb0 + 4096;
        __syncthreads();   // gather done (sc=0) / prev Ws reads done (sc>0)
        #pragma unroll
        for (int i = 0; i < 4; ++i) {
            int f4 = t + i * 256;
            int row = f4 >> 4, col = (f4 & 15) * 4;
            float4 x0 = *(const float4*)&wb0[row * 64 + col];
            float4 x1 = *(const float4*)&wb1[row * 64 + col];
            *(float4*)&Ws[row * 68 + col] = make_float4(x0.x + x1.x, x0.y + x1.y,
                                                        x0.z + x1.z, x0.w + x1.w);
        }
        __syncthreads();

        const float* Msrc = stack ? Mp : Ma;
        float4 acc0 = make_float4(0.f, 0.f, 0.f, 0.f);
        float4 acc1 = make_float4(0.f, 0.f, 0.f, 0.f);
        #pragma unroll 8
        for (int k4 = 0; k4 < 64; k4 += 4) {
            float4 A0 = *(const float4*)&Msrc[ty * 68 + k4];
            float4 A1 = *(const float4*)&Msrc[(ty + 16) * 68 + k4];
            float4 W0 = *(const float4*)&Ws[(k4 + 0) * 68 + 4 * tx];
            float4 W1 = *(const float4*)&Ws[(k4 + 1) * 68 + 4 * tx];
            float4 W2 = *(const float4*)&Ws[(k4 + 2) * 68 + 4 * tx];
            float4 W3 = *(const float4*)&Ws[(k4 + 3) * 68 + 4 * tx];
            fma4(acc0, A0.x, W0); fma4(acc0, A0.y, W1); fma4(acc0, A0.z, W2); fma4(acc0, A0.w, W3);
            fma4(acc1, A1.x, W0); fma4(acc1, A1.y, W1); fma4(acc1, A1.z, W2); fma4(acc1, A1.w, W3);
        }
        const float* bias = (stack ? bpea : badj) + c * L_ * H_;   // layer 0
        float4 bi = *(const float4*)&bias[4 * tx];
        float* Gout = stack ? G1p : G1a;
        #pragma unroll
        for (int r = 0; r < 2; ++r) {
            float4 a = r ? acc1 : acc0;
            float v0 = a.x + bi.x; v0 = v0 > 0.f ? v0 : 0.f;
            float v1 = a.y + bi.y; v1 = v1 > 0.f ? v1 : 0.f;
            float v2 = a.z + bi.z; v2 = v2 > 0.f ? v2 : 0.f;
            float v3 = a.w + bi.w; v3 = v3 > 0.f ? v3 : 0.f;
            *(float4*)&Gout[(size_t)(m0 + ty + 16 * r) * 256 + c * 64 + 4 * tx] =
                make_float4(v0, v1, v2, v3);
        }
    }
}

// ---------------------------------------------------------------------------
// K3: layer 2 + gate mix, both stacks, register-carry between stacks.
// Gather: 4 rows concurrent x unroll 2 = 8 x 1KB loads in flight.
__global__ __launch_bounds__(256, 3) void k_mix(
    const int*   __restrict__ cnt,
    const int*   __restrict__ cols,
    const float* __restrict__ vals,
    const float* __restrict__ G1a, const float* __restrict__ G1p,  // [M][256]
    const float* __restrict__ wadj, const float* __restrict__ badj,
    const float* __restrict__ wpea, const float* __restrict__ bpea,
    const float* __restrict__ gate,   // [M][256]
    float* __restrict__ gr)           // [M][256]
{
    __shared__ float Mt[32 * 260];
    __shared__ float Ws[64 * 68];
    int t = threadIdx.x, lane = t & 63, w = t >> 6;
    int vb = (blockIdx.x & 7) * 82 + (blockIdx.x >> 3);   // XCD swizzle
    if (vb >= 650) return;
    int m0 = vb * 32;
    int tx = t & 15, ty = t >> 4;

    float4 res[4][2];   // gate * relu(adj-stack value), carried across stacks
    float4 gsv[4][2];   // saved gate

    // ======== stack A gather: 4 rows in flight ========
    for (int pp = 0; pp < 8; pp += 4) {
        int mr = m0 + w * 8 + pp;
        int n0 = mr % N_, n1 = (mr+1) % N_, n2 = (mr+2) % N_, n3 = (mr+3) % N_;
        const float* g0 = G1a + (size_t)(mr - n0) * 256 + lane * 4;
        const float* g1 = G1a + (size_t)(mr + 1 - n1) * 256 + lane * 4;
        const float* g2 = G1a + (size_t)(mr + 2 - n2) * 256 + lane * 4;
        const float* g3 = G1a + (size_t)(mr + 3 - n3) * 256 + lane * 4;
        const int *c0 = cols + n0*NNZCAP, *c1 = cols + n1*NNZCAP,
                  *c2 = cols + n2*NNZCAP, *c3 = cols + n3*NNZCAP;
        const float *v0 = vals + n0*NNZCAP, *v1 = vals + n1*NNZCAP,
                    *v2 = vals + n2*NNZCAP, *v3 = vals + n3*NNZCAP;
        int jm = max(max(cnt[n0], cnt[n1]), max(cnt[n2], cnt[n3]));
        float4 a0 = make_float4(0.f,0.f,0.f,0.f), a1 = make_float4(0.f,0.f,0.f,0.f);
        float4 a2 = make_float4(0.f,0.f,0.f,0.f), a3 = make_float4(0.f,0.f,0.f,0.f);
        for (int j = 0; j < jm; j += 2) {
            fma4(a0, v0[j],   *(const float4*)&g0[c0[j]   * 256]);
            fma4(a0, v0[j+1], *(const float4*)&g0[c0[j+1] * 256]);
            fma4(a1, v1[j],   *(const float4*)&g1[c1[j]   * 256]);
            fma4(a1, v1[j+1], *(const float4*)&g1[c1[j+1] * 256]);
            fma4(a2, v2[j],   *(const float4*)&g2[c2[j]   * 256]);
            fma4(a2, v2[j+1], *(const float4*)&g2[c2[j+1] * 256]);
            fma4(a3, v3[j],   *(const float4*)&g3[c3[j]   * 256]);
            fma4(a3, v3[j+1], *(const float4*)&g3[c3[j+1] * 256]);
        }
        *(float4*)&Mt[(w * 8 + pp + 0) * 260 + lane * 4] = a0;
        *(float4*)&Mt[(w * 8 + pp + 1) * 260 + lane * 4] = a1;
        *(float4*)&Mt[(w * 8 + pp + 2) * 260 + lane * 4] = a2;
        *(float4*)&Mt[(w * 8 + pp + 3) * 260 + lane * 4] = a3;
    }

    #pragma unroll
    for (int c = 0; c < 4; ++c) {
        __syncthreads();
        const float* w0 = wadj + (size_t)c * 16384 + 8192;   // layer 1
        const float* w1 = w0 + 4096;
        #pragma unroll
        for (int i = 0; i < 4; ++i) {
            int f4 = t + i * 256;
            int row = f4 >> 4, col = (f4 & 15) * 4;
            float4 x0 = *(const float4*)&w0[row * 64 + col];
            float4 x1 = *(const float4*)&w1[row * 64 + col];
            *(float4*)&Ws[row * 68 + col] = make_float4(x0.x + x1.x, x0.y + x1.y,
                                                        x0.z + x1.z, x0.w + x1.w);
        }
        __syncthreads();
        float4 acc0 = make_float4(0.f,0.f,0.f,0.f), acc1 = make_float4(0.f,0.f,0.f,0.f);
        #pragma unroll 8
        for (int k4 = 0; k4 < 64; k4 += 4) {
            float4 A0 = *(const float4*)&Mt[ty * 260 + c * 64 + k4];
            float4 A1 = *(const float4*)&Mt[(ty + 16) * 260 + c * 64 + k4];
            float4 W0 = *(const float4*)&Ws[(k4 + 0) * 68 + 4 * tx];
            float4 W1 = *(const float4*)&Ws[(k4 + 1) * 68 + 4 * tx];
            float4 W2 = *(const float4*)&Ws[(k4 + 2) * 68 + 4 * tx];
            float4 W3 = *(const float4*)&Ws[(k4 + 3) * 68 + 4 * tx];
            fma4(acc0, A0.x, W0); fma4(acc0, A0.y, W1); fma4(acc0, A0.z, W2); fma4(acc0, A0.w, W3);
            fma4(acc1, A1.x, W0); fma4(acc1, A1.y, W1); fma4(acc1, A1.z, W2); fma4(acc1, A1.w, W3);
        }
        float4 bA = *(const float4*)&badj[(c * L_ + 1) * H_ + 4 * tx];
        #pragma unroll
        for (int r = 0; r < 2; ++r) {
            float4 a = r ? acc1 : acc0;
            float v0 = a.x + bA.x; v0 = v0 > 0.f ? v0 : 0.f;
            float v1 = a.y + bA.y; v1 = v1 > 0.f ? v1 : 0.f;
            float v2 = a.z + bA.z; v2 = v2 > 0.f ? v2 : 0.f;
            float v3 = a.w + bA.w; v3 = v3 > 0.f ? v3 : 0.f;
            size_t o = (size_t)(m0 + ty + 16 * r) * 256 + c * 64 + 4 * tx;
            float4 g = *(const float4*)&gate[o];
            gsv[c][r] = g;
            res[c][r] = make_float4(g.x * v0, g.y * v1, g.z * v2, g.w * v3);
        }
    }

    // ======== stack P: re-gather, combine, write once ========
    __syncthreads();   // all Mt reads done before overwrite
    for (int pp = 0; pp < 8; pp += 4) {
        int mr = m0 + w * 8 + pp;
        int n0 = mr % N_, n1 = (mr+1) % N_, n2 = (mr+2) % N_, n3 = (mr+3) % N_;
        const float* g0 = G1p + (size_t)(mr - n0) * 256 + lane * 4;
        const float* g1 = G1p + (size_t)(mr + 1 - n1) * 256 + lane * 4;
        const float* g2 = G1p + (size_t)(mr + 2 - n2) * 256 + lane * 4;
        const float* g3 = G1p + (size_t)(mr + 3 - n3) * 256 + lane * 4;
        const int *c0 = cols + (N_+n0)*NNZCAP, *c1 = cols + (N_+n1)*NNZCAP,
                  *c2 = cols + (N_+n2)*NNZCAP, *c3 = cols + (N_+n3)*NNZCAP;
        const float *v0 = vals + (N_+n0)*NNZCAP, *v1 = vals + (N_+n1)*NNZCAP,
                    *v2 = vals + (N_+n2)*NNZCAP, *v3 = vals + (N_+n3)*NNZCAP;
        int jm = max(max(cnt[N_+n0], cnt[N_+n1]), max(cnt[N_+n2], cnt[N_+n3]));
        float4 a0 = make_float4(0.f,0.f,0.f,0.f), a1 = make_float4(0.f,0.f,0.f,0.f);
        float4 a2 = make_float4(0.f,0.f,0.f,0.f), a3 = make_float4(0.f,0.f,0.f,0.f);
        for (int j = 0; j < jm; j += 2) {
            fma4(a0, v0[j],   *(const float4*)&g0[c0[j]   * 256]);
            fma4(a0, v0[j+1], *(const float4*)&g0[c0[j+1] * 256]);
            fma4(a1, v1[j],   *(const float4*)&g1[c1[j]   * 256]);
            fma4(a1, v1[j+1], *(const float4*)&g1[c1[j+1] * 256]);
            fma4(a2, v2[j],   *(const float4*)&g2[c2[j]   * 256]);
            fma4(a2, v2[j+1], *(const float4*)&g2[c2[j+1] * 256]);
            fma4(a3, v3[j],   *(const float4*)&g3[c3[j]   * 256]);
            fma4(a3, v3[j+1], *(const float4*)&g3[c3[j+1] * 256]);
        }
        *(float4*)&Mt[(w * 8 + pp + 0) * 260 + lane * 4] = a0;
        *(float4*)&Mt[(w * 8 + pp + 1) * 260 + lane * 4] = a1;
        *(float4*)&Mt[(w * 8 + pp + 2) * 260 + lane * 4] = a2;
        *(float4*)&Mt[(w * 8 + pp + 3) * 260 + lane * 4] = a3;
    }

    #pragma unroll
    for (int c = 0; c < 4; ++c) {
        __syncthreads();
        const float* w0 = wpea + (size_t)c * 16384 + 8192;   // layer 1
        const float* w1 = w0 + 4096;
        #pragma unroll
        for (int i = 0; i < 4; ++i) {
            int f4 = t + i * 256;
            int row = f4 >> 4, col = (f4 & 15) * 4;
            float4 x0 = *(const float4*)&w0[row * 64 + col];
            float4 x1 = *(const float4*)&w1[row * 64 + col];
            *(float4*)&Ws[row * 68 + col] = make_float4(x0.x + x1.x, x0.y + x1.y,
                                                        x0.z + x1.z, x0.w + x1.w);
        }
        __syncthreads();
        float4 acc0 = make_float4(0.f,0.f,0.f,0.f), acc1 = make_float4(0.f,0.f,0.f,0.f);
        #pragma unroll 8
        for (int k4 = 0; k4 < 64; k4 += 4) {
            float4 A0 = *(const float4*)&Mt[ty * 260 + c * 64 + k4];
            float4 A1 = *(const float4*)&Mt[(ty + 16) * 260 + c * 64 + k4];
            float4 W0 = *(const float4*)&Ws[(k4 + 0) * 68 + 4 * tx];
            float4 W1 = *(const float4*)&Ws[(k4 + 1) * 68 + 4 * tx];
            float4 W2 = *(const float4*)&Ws[(k4 + 2) * 68 + 4 * tx];
            float4 W3 = *(const float4*)&Ws[(k4 + 3) * 68 + 4 * tx];
            fma4(acc0, A0.x, W0); fma4(acc0, A0.y, W1); fma4(acc0, A0.z, W2); fma4(acc0, A0.w, W3);
            fma4(acc1, A1.x, W0); fma4(acc1, A1.y, W1); fma4(acc1, A1.z, W2); fma4(acc1, A1.w, W3);
        }
        float4 bP = *(const float4*)&bpea[(c * L_ + 1) * H_ + 4 * tx];
        #pragma unroll
        for (int r = 0; r < 2; ++r) {
            float4 p = r ? acc1 : acc0;
            float v0 = p.x + bP.x; v0 = v0 > 0.f ? v0 : 0.f;
            float v1 = p.y + bP.y; v1 = v1 > 0.f ? v1 : 0.f;
            float v2 = p.z + bP.z; v2 = v2 > 0.f ? v2 : 0.f;
            float v3 = p.w + bP.w; v3 = v3 > 0.f ? v3 : 0.f;
            float4 g  = gsv[c][r];
            float4 rr = res[c][r];
            size_t o = (size_t)(m0 + ty + 16 * r) * 256 + c * 64 + 4 * tx;
            *(float4*)&gr[o] = make_float4(rr.x + (1.f - g.x) * v0,
                                           rr.y + (1.f - g.y) * v1,
                                           rr.z + (1.f - g.z) * v2,
                                           rr.w + (1.f - g.w) * v3);
        }
    }
}

// ---------------------------------------------------------------------------
// K4: cr = gr @ reduce_w + reduce_b + residual; float4 LDS GEMM, fused partials
__global__ __launch_bounds__(256, 4) void k_reduce(const float* __restrict__ in,
                                                   const float* __restrict__ W,
                                                   const float* __restrict__ bias,
                                                   const float* __restrict__ residual,
                                                   float* __restrict__ cr,
                                                   float* __restrict__ partials) {
    __shared__ float Is[64 * 68];
    __shared__ float Ws[64 * 68];
    __shared__ float r1[256], r2[256];
    int t = threadIdx.x, tx = t & 15, ty = t >> 4;
    int m0 = blockIdx.x * 64;
    float4 acc[4];
    #pragma unroll
    for (int i = 0; i < 4; ++i) acc[i] = make_float4(0.f, 0.f, 0.f, 0.f);
    for (int kk = 0; kk < 256; kk += 64) {
        if (kk) __syncthreads();
        #pragma unroll
        for (int i = 0; i < 4; ++i) {
            int f4 = t + i * 256;
            int row = f4 >> 4, col = (f4 & 15) * 4;
            *(float4*)&Is[row * 68 + col] =
                *(const float4*)&in[(size_t)(m0 + row) * 256 + kk + col];
            *(float4*)&Ws[row * 68 + col] =
                *(const float4*)&W[(size_t)(kk + row) * 64 + col];
        }
        __syncthreads();
        #pragma unroll 8
        for (int k4 = 0; k4 < 64; k4 += 4) {
            float4 A0 = *(const float4*)&Is[ty * 68 + k4];
            float4 A1 = *(const float4*)&Is[(ty + 16) * 68 + k4];
            float4 A2 = *(const float4*)&Is[(ty + 32) * 68 + k4];
            float4 A3 = *(const float4*)&Is[(ty + 48) * 68 + k4];
            float4 W0 = *(const float4*)&Ws[(k4 + 0) * 68 + 4 * tx];
            float4 W1 = *(const float4*)&Ws[(k4 + 1) * 68 + 4 * tx];
            float4 W2 = *(const float4*)&Ws[(k4 + 2) * 68 + 4 * tx];
            float4 W3 = *(const float4*)&Ws[(k4 + 3) * 68 + 4 * tx];
            fma4(acc[0], A0.x, W0); fma4(acc[0], A0.y, W1); fma4(acc[0], A0.z, W2); fma4(acc[0], A0.w, W3);
            fma4(acc[1], A1.x, W0); fma4(acc[1], A1.y, W1); fma4(acc[1], A1.z, W2); fma4(acc[1], A1.w, W3);
            fma4(acc[2], A2.x, W0); fma4(acc[2], A2.y, W1); fma4(acc[2], A2.z, W2); fma4(acc[2], A2.w, W3);
            fma4(acc[3], A3.x, W0); fma4(acc[3], A3.y, W1); fma4(acc[3], A3.z, W2); fma4(acc[3], A3.w, W3);
        }
    }
    float4 bi = *(const float4*)&bias[4 * tx];
    float s = 0.f, s2 = 0.f;
    #pragma unroll
    for (int i = 0; i < 4; ++i) {
        int r = m0 + ty + 16 * i;
        float4 rv = *(const float4*)&residual[(size_t)r * 64 + 4 * tx];
        float v0 = acc[i].x + bi.x + rv.x;
        float v1 = acc[i].y + bi.y + rv.y;
        float v2 = acc[i].z + bi.z + rv.z;
        float v3 = acc[i].w + bi.w + rv.w;
        *(float4*)&cr[(size_t)r * 64 + 4 * tx] = make_float4(v0, v1, v2, v3);
        s += v0 + v1 + v2 + v3;
        s2 += v0 * v0 + v1 * v1 + v2 * v2 + v3 * v3;
    }
    r1[t] = s; r2[t] = s2;
    __syncthreads();
    for (int off = 128; off > 0; off >>= 1) {
        if (t < off) { r1[t] += r1[t + off]; r2[t] += r2[t + off]; }
        __syncthreads();
    }
    if (t == 0) { partials[blockIdx.x] = r1[0]; partials[325 + blockIdx.x] = r2[0]; }
}

// ---------------------------------------------------------------------------
// K5: out = relu(ocw*norm(cr) + ocb) @ olw + olb, norm fused from partials
__global__ void k_out(const float* __restrict__ cr, const float* __restrict__ partials,
                      const float* __restrict__ ocw, const float* __restrict__ ocb,
                      const float* __restrict__ olw, const float* __restrict__ olb,
                      float* __restrict__ out) {
    __shared__ float s1[256], s2[256];
    int t = threadIdx.x;
    float a = 0.f, b2s = 0.f;
    for (int i = t; i < 325; i += 256) { a += partials[i]; b2s += partials[325 + i]; }
    s1[t] = a; s2[t] = b2s;
    __syncthreads();
    for (int off = 128; off > 0; off >>= 1) {
        if (t < off) { s1[t] += s1[t + off]; s2[t] += s2[t + off]; }
        __syncthreads();
    }
    const float inv = 1.f / (float)(M_ * H_);
    float mu  = s1[0] * inv;
    float var = s2[0] * inv - mu * mu;
    float rs  = rsqrtf(var + 1e-5f);

    int m = blockIdx.x * 256 + t;
    if (m >= M_) return;
    int b = m / N_, n = m % N_;
    float cw[P_], cb[P_], acc[P_];
    #pragma unroll
    for (int p = 0; p < P_; ++p) { cw[p] = ocw[p]; cb[p] = ocb[p]; acc[p] = 0.f; }
    const float* lr = cr + (size_t)m * H_;
    for (int h = 0; h < H_; ++h) {
        float lv = (lr[h] - mu) * rs;
        float wv = olw[h];
        #pragma unroll
        for (int p = 0; p < P_; ++p) {
            float u = cw[p] * lv + cb[p];
            u = u > 0.f ? u : 0.f;
            acc[p] += u * wv;
        }
    }
    float ob = olb[0];
    #pragma unroll
    for (int p = 0; p < P_; ++p)
        out[(size_t)(b * P_ + p) * N_ + n] = acc[p] + ob;
}

// ---------------------------------------------------------------------------
extern "C" void kernel_launch(void* const* d_in, const int* in_sizes, int n_in,
                              void* d_out, int out_size, void* d_ws, size_t ws_size,
                              hipStream_t stream) {
    const float* inp      = (const float*)d_in[0];
    const float* adj_fwd  = (const float*)d_in[1];
    const float* pea_fwd  = (const float*)d_in[3];
    const float* w_in     = (const float*)d_in[5];
    const float* b_in     = (const float*)d_in[6];
    const float* res_w    = (const float*)d_in[7];
    const float* res_b    = (const float*)d_in[8];
    const float* gconv_w  = (const float*)d_in[9];
    const float* gconv_b  = (const float*)d_in[10];
    const float* gate1_w  = (const float*)d_in[11];
    const float* gate1_b  = (const float*)d_in[12];
    const float* gate2_w  = (const float*)d_in[13];
    const float* gate2_b  = (const float*)d_in[14];
    const float* reduce_w = (const float*)d_in[15];
    const float* reduce_b = (const float*)d_in[16];
    const float* gadj_w   = (const float*)d_in[17];
    const float* gadj_b   = (const float*)d_in[18];
    const float* gpea_w   = (const float*)d_in[19];
    const float* gpea_b   = (const float*)d_in[20];
    const float* ocw      = (const float*)d_in[21];
    const float* ocb      = (const float*)d_in[22];
    const float* olw      = (const float*)d_in[23];
    const float* olb      = (const float*)d_in[24];
    float* out = (float*)d_out;

    // workspace layout (floats) — ~101 MB
    float* ws       = (float*)d_ws;
    float* g_init   = ws;                              // M*64
    float* G1a      = g_init + (size_t)M_ * H_;        // M*256
    float* G1p      = G1a + (size_t)M_ * 256;          // M*256
    float* gate     = G1p + (size_t)M_ * 256;          // M*256
    float* gr       = gate + (size_t)M_ * 256;         // M*256
    float* residual = gr + (size_t)M_ * 256;           // M*64
    float* cr       = residual + (size_t)M_ * H_;      // M*64
    float* partials = cr + (size_t)M_ * H_;            // 650
    int*   scnt  = (int*)(partials + 650);             // 2*325
    int*   scols = scnt + 2 * N_;                      // 2*325*64
    float* svals = (float*)(scols + 2 * N_ * NNZCAP);  // 2*325*64

    k_build_sparse<<<N_, 64, 0, stream>>>(adj_fwd, scnt,      scols,              svals);
    k_build_sparse<<<N_, 64, 0, stream>>>(pea_fwd, scnt + N_, scols + N_*NNZCAP,  svals + N_*NNZCAP);

    for (int it = 0; it < KCP; ++it) {
        k_gate<<<M_ / 64, 256, 0, stream>>>(
            inp, w_in, b_in, gconv_w, gconv_b, res_w, res_b, cr, partials, it,
            gate1_w, gate1_b, gate2_w, gate2_b, residual, g_init, gate);
        k_layer1<<<656, 256, 0, stream>>>(
            scnt, scols, svals, g_init, gadj_w, gadj_b, gpea_w, gpea_b, G1a, G1p);
        k_mix<<<656, 256, 0, stream>>>(
            scnt, scols, svals, G1a, G1p, gadj_w, gadj_b, gpea_w, gpea_b, gate, gr);
        k_reduce<<<M_ / 64, 256, 0, stream>>>(gr, reduce_w, reduce_b, residual, cr, partials);
    }

    k_out<<<(M_ + 255) / 256, 256, 0, stream>>>(cr, partials, ocw, ocb, olw, olb, out);
}

// Round 10
// 816.266 us; speedup vs baseline: 1.8066x; 1.0021x over previous
//
#include <hip/hip_runtime.h>
#include <hip/hip_bf16.h>
#include <math.h>

// Problem constants
#define B_    64
#define T_    13
#define N_    325
#define H_    64
#define C_    4
#define L_    2
#define S_    4
#define P_    12
#define KCP   4            // checkpoints [4,7,10,13]
#define M_    (B_*N_)      // 20800 (= 650*32 exactly)
#define ADJLD 1300         // leading dim of combined adjacency inputs
#define NNZCAP 64          // max nonzeros per adjacency row (3% density -> mean ~10)

#define FMA16 \
  acc[0][0]+=a0*b0; acc[0][1]+=a0*b1; acc[0][2]+=a0*b2; acc[0][3]+=a0*b3; \
  acc[1][0]+=a1*b0; acc[1][1]+=a1*b1; acc[1][2]+=a1*b2; acc[1][3]+=a1*b3; \
  acc[2][0]+=a2*b0; acc[2][1]+=a2*b1; acc[2][2]+=a2*b2; acc[2][3]+=a2*b3; \
  acc[3][0]+=a3*b0; acc[3][1]+=a3*b1; acc[3][2]+=a3*b2; acc[3][3]+=a3*b3;

__device__ __forceinline__ void fma4(float4& a, float s, float4 x) {
    a.x += s * x.x; a.y += s * x.y; a.z += s * x.z; a.w += s * x.w;
}
// bf16x4 pack (RNE) / unpack
__device__ __forceinline__ uint2 pack_bf4(float4 v) {
    unsigned a = __float_as_uint(v.x), b = __float_as_uint(v.y);
    unsigned c = __float_as_uint(v.z), d = __float_as_uint(v.w);
    a = (a + 0x7fffu + ((a >> 16) & 1u)) >> 16;
    b = (b + 0x7fffu + ((b >> 16) & 1u)) >> 16;
    c = (c + 0x7fffu + ((c >> 16) & 1u)) >> 16;
    d = (d + 0x7fffu + ((d >> 16) & 1u)) >> 16;
    return make_uint2(a | (b << 16), c | (d << 16));
}
__device__ __forceinline__ float4 unpack_bf4(uint2 p) {
    return make_float4(__uint_as_float(p.x << 16),
                       __uint_as_float(p.x & 0xffff0000u),
                       __uint_as_float(p.y << 16),
                       __uint_as_float(p.y & 0xffff0000u));
}

// ---------------------------------------------------------------------------
// Build padded sparse rows (column-ordered, deterministic). One wave per row.
__global__ void k_build_sparse(const float* __restrict__ A,
                               int* __restrict__ cnt, int* __restrict__ cols,
                               float* __restrict__ vals) {
    int n    = blockIdx.x;
    int lane = threadIdx.x;
    const float* row = A + (size_t)n * ADJLD;
    int c = 0;
    for (int c0 = 0; c0 < 384; c0 += 64) {
        int col = c0 + lane;
        float v = (col < N_) ? row[col] : 0.f;
        unsigned long long m = __ballot(v != 0.f);
        int idx = c + __popcll(m & ((1ull << lane) - 1ull));
        if (v != 0.f && idx < NNZCAP) {
            cols[n * NNZCAP + idx] = col;
            vals[n * NNZCAP + idx] = v;
        }
        c += __popcll(m);
    }
    if (c + lane < NNZCAP) {                 // zero-pad tail -> branch-free consumers
        cols[n * NNZCAP + c + lane] = 0;
        vals[n * NNZCAP + c + lane] = 0.f;
    }
    if (lane == 0) cnt[n] = (c < NNZCAP) ? c : NNZCAP;
}

// ---------------------------------------------------------------------------
// K1: fused [norm of prev cr] + gf/residual/g_init + 2-layer gate MLP.
__global__ __launch_bounds__(256, 3) void k_gate(
    const float* __restrict__ inp,
    const float* __restrict__ w_in, const float* __restrict__ b_in,
    const float* __restrict__ gconv_w, const float* __restrict__ gconv_b,
    const float* __restrict__ res_w,   const float* __restrict__ res_b,
    const float* __restrict__ cr, const float* __restrict__ partials, int it,
    const float* __restrict__ W1, const float* __restrict__ b1,
    const float* __restrict__ W2, const float* __restrict__ b2,
    float* __restrict__ residual, float* __restrict__ g_init,
    float* __restrict__ gate)
{
    __shared__ float Gf[64 * 68];
    __shared__ float Ws[64 * 68];
    __shared__ float Gr[64 * 68];
    int t = threadIdx.x, lane = t & 63, w = t >> 6;
    int m0 = blockIdx.x * 64;

    // ---- phase -1: LayerNorm constants from partials (it>0) ----
    float mu = 0.f, rs = 0.f;
    if (it > 0) {
        float a = 0.f, b = 0.f;
        for (int i = t; i < 325; i += 256) { a += partials[i]; b += partials[325 + i]; }
        Ws[t] = a; Ws[256 + t] = b;
        __syncthreads();
        for (int off = 128; off > 0; off >>= 1) {
            if (t < off) { Ws[t] += Ws[t + off]; Ws[256 + t] += Ws[256 + t + off]; }
            __syncthreads();
        }
        const float inv = 1.f / (float)(M_ * H_);
        mu = Ws[0] * inv;
        float var = Ws[256] * inv - mu * mu;
        rs = rsqrtf(var + 1e-5f);
        __syncthreads();   // reduction reads done before W1 staging overwrites Ws
    }

    // ---- phase 0: gf / residual / g_init ----
    {
        float wa = w_in[lane], wb = w_in[H_ + lane], bi = b_in[lane];
        float gw0 = gconv_w[0], gw1 = gconv_w[1], gw2 = gconv_w[2], gw3 = gconv_w[3];
        float rw0 = res_w[0],   rw1 = res_w[1],   rw2 = res_w[2],   rw3 = res_w[3];
        float gb = gconv_b[0],  rb = res_b[0];
        int left = (it == 0) ? 0 : (3 * it + 1);
        for (int i = 0; i < 16; ++i) {
            int r = i * 4 + w;                  // wave-uniform row
            int m = m0 + r;
            int b = m / N_, n = m % N_;
            const float* ipb = inp + ((size_t)b * T_ * N_ + n) * 2;
            float v0;
            if (it > 0) v0 = (cr[(size_t)m * H_ + lane] - mu) * rs;
            else        { v0 = ipb[0] * wa + ipb[1] * wb + bi; }
            int t1 = (it == 0) ? 1 : left;
            const float* ip1 = ipb + (size_t)t1 * N_ * 2;
            const float* ip2 = ip1 + (size_t)N_ * 2;
            const float* ip3 = ip2 + (size_t)N_ * 2;
            float v1 = ip1[0] * wa + ip1[1] * wb + bi;
            float v2 = ip2[0] * wa + ip2[1] * wb + bi;
            float v3 = ip3[0] * wa + ip3[1] * wb + bi;
            Gf[r * 68 + lane] = gb + gw0 * v0 + gw1 * v1 + gw2 * v2 + gw3 * v3;
            residual[(size_t)m * H_ + lane] = rb + rw0 * v0 + rw1 * v1 + rw2 * v2 + rw3 * v3;
            g_init[(size_t)m * H_ + lane] = v3;
        }
    }
    // stage W1
    #pragma unroll
    for (int i = 0; i < 4; ++i) {
        int f4 = t + i * 256;
        int row = f4 >> 4, col = (f4 & 15) * 4;
        *(float4*)&Ws[row * 68 + col] = *(const float4*)&W1[row * 64 + col];
    }
    __syncthreads();

    int tx = t & 15, ty = t >> 4;
    float acc[4][4];
    #pragma unroll
    for (int i = 0; i < 4; ++i)
        #pragma unroll
        for (int j = 0; j < 4; ++j) acc[i][j] = 0.f;
    #pragma unroll 16
    for (int k = 0; k < 64; ++k) {
        float a0 = Gf[ty * 68 + k];
        float a1 = Gf[(ty + 16) * 68 + k];
        float a2 = Gf[(ty + 32) * 68 + k];
        float a3 = Gf[(ty + 48) * 68 + k];
        float4 wv = *(const float4*)&Ws[k * 68 + 4 * tx];
        float b0 = wv.x, b1v = wv.y, b2v = wv.z, b3 = wv.w;
        { float b1 = b1v, b2 = b2v; FMA16 }
    }
    float4 bi1 = *(const float4*)&b1[4 * tx];
    #pragma unroll
    for (int i = 0; i < 4; ++i) {
        float v0 = acc[i][0] + bi1.x; v0 = v0 > 0.f ? v0 : 0.f;
        float v1 = acc[i][1] + bi1.y; v1 = v1 > 0.f ? v1 : 0.f;
        float v2 = acc[i][2] + bi1.z; v2 = v2 > 0.f ? v2 : 0.f;
        float v3 = acc[i][3] + bi1.w; v3 = v3 > 0.f ? v3 : 0.f;
        *(float4*)&Gr[(ty + 16 * i) * 68 + 4 * tx] = make_float4(v0, v1, v2, v3);
    }
    for (int ch = 0; ch < 4; ++ch) {
        __syncthreads();
        #pragma unroll
        for (int i = 0; i < 4; ++i) {
            int f4 = t + i * 256;
            int row = f4 >> 4, col = (f4 & 15) * 4;
            *(float4*)&Ws[row * 68 + col] =
                *(const float4*)&W2[(size_t)row * 256 + ch * 64 + col];
        }
        __syncthreads();
        float acc2[4][4];
        #pragma unroll
        for (int i = 0; i < 4; ++i)
            #pragma unroll
            for (int j = 0; j < 4; ++j) acc2[i][j] = 0.f;
        #pragma unroll 16
        for (int k = 0; k < 64; ++k) {
            float a0 = Gr[ty * 68 + k];
            float a1 = Gr[(ty + 16) * 68 + k];
            float a2 = Gr[(ty + 32) * 68 + k];
            float a3 = Gr[(ty + 48) * 68 + k];
            float4 wv = *(const float4*)&Ws[k * 68 + 4 * tx];
            float b0 = wv.x, b1v = wv.y, b2v = wv.z, b3 = wv.w;
            { float b1 = b1v, b2 = b2v; float (*acc)[4] = acc2; FMA16 }
        }
        float4 bi2 = *(const float4*)&b2[ch * 64 + 4 * tx];
        #pragma unroll
        for (int i = 0; i < 4; ++i) {
            int m = m0 + ty + 16 * i;
            float g0 = 1.f / (1.f + expf(-(acc2[i][0] + bi2.x)));
            float g1 = 1.f / (1.f + expf(-(acc2[i][1] + bi2.y)));
            float g2 = 1.f / (1.f + expf(-(acc2[i][2] + bi2.z)));
            float g3 = 1.f / (1.f + expf(-(acc2[i][3] + bi2.w)));
            *(float4*)&gate[(size_t)m * 256 + ch * 64 + 4 * tx] = make_float4(g0, g1, g2, g3);
        }
    }
}

// ---------------------------------------------------------------------------
// K2: layer 1, both stacks; G1 output packed to bf16 (halves k_mix gather lines).
__global__ __launch_bounds__(256, 4) void k_layer1(
    const int*   __restrict__ cnt,    // [2N]  adj rows 0..N, pea rows N..2N
    const int*   __restrict__ cols,   // [2N][NNZCAP]
    const float* __restrict__ vals,
    const float* __restrict__ g_init, // [M][64]
    const float* __restrict__ wadj, const float* __restrict__ badj,
    const float* __restrict__ wpea, const float* __restrict__ bpea,
    ushort* __restrict__ G1a, ushort* __restrict__ G1p)   // [M][256] bf16
{
    __shared__ float Ma[32 * 68];
    __shared__ float Mp[32 * 68];
    __shared__ float Ws[64 * 68];
    int t = threadIdx.x, lane = t & 63, w = t >> 6;
    int vb = (blockIdx.x & 7) * 82 + (blockIdx.x >> 3);   // XCD swizzle
    if (vb >= 650) return;
    int m0 = vb * 32;

    // ---- gather: lane=(rr,cl); rows w*8+rr and w*8+4+rr, both stacks ----
    {
        int cl = lane & 15, rr = lane >> 4;
        int mA = m0 + w * 8 + rr;
        int mB = mA + 4;
        int nA = mA % N_, nB = mB % N_;
        const float* gA = g_init + (size_t)(mA - nA) * H_ + cl * 4;
        const float* gB = g_init + (size_t)(mB - nB) * H_ + cl * 4;
        const int   *cA0 = cols + nA * NNZCAP,        *cB0 = cols + nB * NNZCAP;
        const float *vA0 = vals + nA * NNZCAP,        *vB0 = vals + nB * NNZCAP;
        const int   *cA1 = cols + (N_ + nA) * NNZCAP, *cB1 = cols + (N_ + nB) * NNZCAP;
        const float *vA1 = vals + (N_ + nA) * NNZCAP, *vB1 = vals + (N_ + nB) * NNZCAP;
        int jm = max(max(cnt[nA], cnt[nB]), max(cnt[N_ + nA], cnt[N_ + nB]));
        float4 aA0 = make_float4(0.f,0.f,0.f,0.f), aB0 = make_float4(0.f,0.f,0.f,0.f);
        float4 aA1 = make_float4(0.f,0.f,0.f,0.f), aB1 = make_float4(0.f,0.f,0.f,0.f);
        for (int j = 0; j < jm; j += 2) {     // zero-padded -> branch-free
            fma4(aA0, vA0[j],   *(const float4*)&gA[cA0[j]   * H_]);
            fma4(aA0, vA0[j+1], *(const float4*)&gA[cA0[j+1] * H_]);
            fma4(aB0, vB0[j],   *(const float4*)&gB[cB0[j]   * H_]);
            fma4(aB0, vB0[j+1], *(const float4*)&gB[cB0[j+1] * H_]);
            fma4(aA1, vA1[j],   *(const float4*)&gA[cA1[j]   * H_]);
            fma4(aA1, vA1[j+1], *(const float4*)&gA[cA1[j+1] * H_]);
            fma4(aB1, vB1[j],   *(const float4*)&gB[cB1[j]   * H_]);
            fma4(aB1, vB1[j+1], *(const float4*)&gB[cB1[j+1] * H_]);
        }
        *(float4*)&Ma[(w * 8 + rr) * 68 + cl * 4]     = aA0;
        *(float4*)&Ma[(w * 8 + 4 + rr) * 68 + cl * 4] = aB0;
        *(float4*)&Mp[(w * 8 + rr) * 68 + cl * 4]     = aA1;
        *(float4*)&Mp[(w * 8 + 4 + rr) * 68 + cl * 4] = aB1;
    }

    int tx = t & 15, ty = t >> 4;
    for (int sc = 0; sc < 8; ++sc) {
        int stack = sc >> 2, c = sc & 3;
        const float* wb0 = (stack ? wpea : wadj) + (size_t)c * 16384;   // layer 0
        const float* wb1 = wb0 + 4096;
        __syncthreads();   // gather done (sc=0) / prev Ws reads done (sc>0)
        #pragma unroll
        for (int i = 0; i < 4; ++i) {
            int f4 = t + i * 256;
            int row = f4 >> 4, col = (f4 & 15) * 4;
            float4 x0 = *(const float4*)&wb0[row * 64 + col];
            float4 x1 = *(const float4*)&wb1[row * 64 + col];
            *(float4*)&Ws[row * 68 + col] = make_float4(x0.x + x1.x, x0.y + x1.y,
                                                        x0.z + x1.z, x0.w + x1.w);
        }
        __syncthreads();

        const float* Msrc = stack ? Mp : Ma;
        float4 acc0 = make_float4(0.f, 0.f, 0.f, 0.f);
        float4 acc1 = make_float4(0.f, 0.f, 0.f, 0.f);
        #pragma unroll 8
        for (int k4 = 0; k4 < 64; k4 += 4) {
            float4 A0 = *(const float4*)&Msrc[ty * 68 + k4];
            float4 A1 = *(const float4*)&Msrc[(ty + 16) * 68 + k4];
            float4 W0 = *(const float4*)&Ws[(k4 + 0) * 68 + 4 * tx];
            float4 W1 = *(const float4*)&Ws[(k4 + 1) * 68 + 4 * tx];
            float4 W2 = *(const float4*)&Ws[(k4 + 2) * 68 + 4 * tx];
            float4 W3 = *(const float4*)&Ws[(k4 + 3) * 68 + 4 * tx];
            fma4(acc0, A0.x, W0); fma4(acc0, A0.y, W1); fma4(acc0, A0.z, W2); fma4(acc0, A0.w, W3);
            fma4(acc1, A1.x, W0); fma4(acc1, A1.y, W1); fma4(acc1, A1.z, W2); fma4(acc1, A1.w, W3);
        }
        const float* bias = (stack ? bpea : badj) + c * L_ * H_;   // layer 0
        float4 bi = *(const float4*)&bias[4 * tx];
        ushort* Gout = stack ? G1p : G1a;
        #pragma unroll
        for (int r = 0; r < 2; ++r) {
            float4 a = r ? acc1 : acc0;
            float v0 = a.x + bi.x; v0 = v0 > 0.f ? v0 : 0.f;
            float v1 = a.y + bi.y; v1 = v1 > 0.f ? v1 : 0.f;
            float v2 = a.z + bi.z; v2 = v2 > 0.f ? v2 : 0.f;
            float v3 = a.w + bi.w; v3 = v3 > 0.f ? v3 : 0.f;
            *(uint2*)&Gout[(size_t)(m0 + ty + 16 * r) * 256 + c * 64 + 4 * tx] =
                pack_bf4(make_float4(v0, v1, v2, v3));
        }
    }
}

// ---------------------------------------------------------------------------
// K3: layer 2 + gate mix, both stacks, register-carry between stacks.
// Gather: R8-proven 2-row x unroll-2 pattern (4 loads in flight), bf16 G1.
__global__ __launch_bounds__(256, 3) void k_mix(
    const int*   __restrict__ cnt,
    const int*   __restrict__ cols,
    const float* __restrict__ vals,
    const ushort* __restrict__ G1a, const ushort* __restrict__ G1p,  // [M][256] bf16
    const float* __restrict__ wadj, const float* __restrict__ badj,
    const float* __restrict__ wpea, const float* __restrict__ bpea,
    const float* __restrict__ gate,   // [M][256]
    float* __restrict__ gr)           // [M][256]
{
    __shared__ float Mt[32 * 260];
    __shared__ float Ws[64 * 68];
    int t = threadIdx.x, lane = t & 63, w = t >> 6;
    int vb = (blockIdx.x & 7) * 82 + (blockIdx.x >> 3);   // XCD swizzle
    if (vb >= 650) return;
    int m0 = vb * 32;
    int tx = t & 15, ty = t >> 4;

    float4 res[4][2];   // gate * relu(adj-stack value), carried across stacks
    float4 gsv[4][2];   // saved gate

    // ======== stack A gather: 2 rows x unroll 2, bf16 unpack ========
    for (int pp = 0; pp < 8; pp += 2) {
        int ma = m0 + w * 8 + pp, mb = ma + 1;
        int na = ma % N_, nb = mb % N_;
        const ushort* ga = G1a + (size_t)(ma - na) * 256 + lane * 4;
        const ushort* gb = G1a + (size_t)(mb - nb) * 256 + lane * 4;
        const int   *cap = cols + na * NNZCAP, *cbp = cols + nb * NNZCAP;
        const float *vap = vals + na * NNZCAP, *vbp = vals + nb * NNZCAP;
        int jm = max(cnt[na], cnt[nb]);
        float4 a0 = make_float4(0.f,0.f,0.f,0.f), a1 = make_float4(0.f,0.f,0.f,0.f);
        for (int j = 0; j < jm; j += 2) {     // zero-padded -> branch-free
            float w00 = vap[j], w01 = vap[j+1];
            float w10 = vbp[j], w11 = vbp[j+1];
            float4 x00 = unpack_bf4(*(const uint2*)&ga[cap[j]   * 256]);
            float4 x01 = unpack_bf4(*(const uint2*)&ga[cap[j+1] * 256]);
            float4 x10 = unpack_bf4(*(const uint2*)&gb[cbp[j]   * 256]);
            float4 x11 = unpack_bf4(*(const uint2*)&gb[cbp[j+1] * 256]);
            fma4(a0, w00, x00); fma4(a0, w01, x01);
            fma4(a1, w10, x10); fma4(a1, w11, x11);
        }
        *(float4*)&Mt[(w * 8 + pp) * 260 + lane * 4]     = a0;
        *(float4*)&Mt[(w * 8 + pp + 1) * 260 + lane * 4] = a1;
    }

    #pragma unroll
    for (int c = 0; c < 4; ++c) {
        __syncthreads();
        const float* w0 = wadj + (size_t)c * 16384 + 8192;   // layer 1
        const float* w1 = w0 + 4096;
        #pragma unroll
        for (int i = 0; i < 4; ++i) {
            int f4 = t + i * 256;
            int row = f4 >> 4, col = (f4 & 15) * 4;
            float4 x0 = *(const float4*)&w0[row * 64 + col];
            float4 x1 = *(const float4*)&w1[row * 64 + col];
            *(float4*)&Ws[row * 68 + col] = make_float4(x0.x + x1.x, x0.y + x1.y,
                                                        x0.z + x1.z, x0.w + x1.w);
        }
        __syncthreads();
        float4 acc0 = make_float4(0.f,0.f,0.f,0.f), acc1 = make_float4(0.f,0.f,0.f,0.f);
        #pragma unroll 8
        for (int k4 = 0; k4 < 64; k4 += 4) {
            float4 A0 = *(const float4*)&Mt[ty * 260 + c * 64 + k4];
            float4 A1 = *(const float4*)&Mt[(ty + 16) * 260 + c * 64 + k4];
            float4 W0 = *(const float4*)&Ws[(k4 + 0) * 68 + 4 * tx];
            float4 W1 = *(const float4*)&Ws[(k4 + 1) * 68 + 4 * tx];
            float4 W2 = *(const float4*)&Ws[(k4 + 2) * 68 + 4 * tx];
            float4 W3 = *(const float4*)&Ws[(k4 + 3) * 68 + 4 * tx];
            fma4(acc0, A0.x, W0); fma4(acc0, A0.y, W1); fma4(acc0, A0.z, W2); fma4(acc0, A0.w, W3);
            fma4(acc1, A1.x, W0); fma4(acc1, A1.y, W1); fma4(acc1, A1.z, W2); fma4(acc1, A1.w, W3);
        }
        float4 bA = *(const float4*)&badj[(c * L_ + 1) * H_ + 4 * tx];
        #pragma unroll
        for (int r = 0; r < 2; ++r) {
            float4 a = r ? acc1 : acc0;
            float v0 = a.x + bA.x; v0 = v0 > 0.f ? v0 : 0.f;
            float v1 = a.y + bA.y; v1 = v1 > 0.f ? v1 : 0.f;
            float v2 = a.z + bA.z; v2 = v2 > 0.f ? v2 : 0.f;
            float v3 = a.w + bA.w; v3 = v3 > 0.f ? v3 : 0.f;
            size_t o = (size_t)(m0 + ty + 16 * r) * 256 + c * 64 + 4 * tx;
            float4 g = *(const float4*)&gate[o];
            gsv[c][r] = g;
            res[c][r] = make_float4(g.x * v0, g.y * v1, g.z * v2, g.w * v3);
        }
    }

    // ======== stack P: re-gather, combine, write once ========
    __syncthreads();   // all Mt reads done before overwrite
    for (int pp = 0; pp < 8; pp += 2) {
        int ma = m0 + w * 8 + pp, mb = ma + 1;
        int na = ma % N_, nb = mb % N_;
        const ushort* ga = G1p + (size_t)(ma - na) * 256 + lane * 4;
        const ushort* gb = G1p + (size_t)(mb - nb) * 256 + lane * 4;
        const int   *cap = cols + (N_ + na) * NNZCAP, *cbp = cols + (N_ + nb) * NNZCAP;
        const float *vap = vals + (N_ + na) * NNZCAP, *vbp = vals + (N_ + nb) * NNZCAP;
        int jm = max(cnt[N_ + na], cnt[N_ + nb]);
        float4 a0 = make_float4(0.f,0.f,0.f,0.f), a1 = make_float4(0.f,0.f,0.f,0.f);
        for (int j = 0; j < jm; j += 2) {
            float w00 = vap[j], w01 = vap[j+1];
            float w10 = vbp[j], w11 = vbp[j+1];
            float4 x00 = unpack_bf4(*(const uint2*)&ga[cap[j]   * 256]);
            float4 x01 = unpack_bf4(*(const uint2*)&ga[cap[j+1] * 256]);
            float4 x10 = unpack_bf4(*(const uint2*)&gb[cbp[j]   * 256]);
            float4 x11 = unpack_bf4(*(const uint2*)&gb[cbp[j+1] * 256]);
            fma4(a0, w00, x00); fma4(a0, w01, x01);
            fma4(a1, w10, x10); fma4(a1, w11, x11);
        }
        *(float4*)&Mt[(w * 8 + pp) * 260 + lane * 4]     = a0;
        *(float4*)&Mt[(w * 8 + pp + 1) * 260 + lane * 4] = a1;
    }

    #pragma unroll
    for (int c = 0; c < 4; ++c) {
        __syncthreads();
        const float* w0 = wpea + (size_t)c * 16384 + 8192;   // layer 1
        const float* w1 = w0 + 4096;
        #pragma unroll
        for (int i = 0; i < 4; ++i) {
            int f4 = t + i * 256;
            int row = f4 >> 4, col = (f4 & 15) * 4;
            float4 x0 = *(const float4*)&w0[row * 64 + col];
            float4 x1 = *(const float4*)&w1[row * 64 + col];
            *(float4*)&Ws[row * 68 + col] = make_float4(x0.x + x1.x, x0.y + x1.y,
                                                        x0.z + x1.z, x0.w + x1.w);
        }
        __syncthreads();
        float4 acc0 = make_float4(0.f,0.f,0.f,0.f), acc1 = make_float4(0.f,0.f,0.f,0.f);
        #pragma unroll 8
        for (int k4 = 0; k4 < 64; k4 += 4) {
            float4 A0 = *(const float4*)&Mt[ty * 260 + c * 64 + k4];
            float4 A1 = *(const float4*)&Mt[(ty + 16) * 260 + c * 64 + k4];
            float4 W0 = *(const float4*)&Ws[(k4 + 0) * 68 + 4 * tx];
            float4 W1 = *(const float4*)&Ws[(k4 + 1) * 68 + 4 * tx];
            float4 W2 = *(const float4*)&Ws[(k4 + 2) * 68 + 4 * tx];
            float4 W3 = *(const float4*)&Ws[(k4 + 3) * 68 + 4 * tx];
            fma4(acc0, A0.x, W0); fma4(acc0, A0.y, W1); fma4(acc0, A0.z, W2); fma4(acc0, A0.w, W3);
            fma4(acc1, A1.x, W0); fma4(acc1, A1.y, W1); fma4(acc1, A1.z, W2); fma4(acc1, A1.w, W3);
        }
        float4 bP = *(const float4*)&bpea[(c * L_ + 1) * H_ + 4 * tx];
        #pragma unroll
        for (int r = 0; r < 2; ++r) {
            float4 p = r ? acc1 : acc0;
            float v0 = p.x + bP.x; v0 = v0 > 0.f ? v0 : 0.f;
            float v1 = p.y + bP.y; v1 = v1 > 0.f ? v1 : 0.f;
            float v2 = p.z + bP.z; v2 = v2 > 0.f ? v2 : 0.f;
            float v3 = p.w + bP.w; v3 = v3 > 0.f ? v3 : 0.f;
            float4 g  = gsv[c][r];
            float4 rr = res[c][r];
            size_t o = (size_t)(m0 + ty + 16 * r) * 256 + c * 64 + 4 * tx;
            *(float4*)&gr[o] = make_float4(rr.x + (1.f - g.x) * v0,
                                           rr.y + (1.f - g.y) * v1,
                                           rr.z + (1.f - g.z) * v2,
                                           rr.w + (1.f - g.w) * v3);
        }
    }
}

// ---------------------------------------------------------------------------
// K4: cr = gr @ reduce_w + reduce_b + residual; float4 LDS GEMM, fused partials
__global__ __launch_bounds__(256, 4) void k_reduce(const float* __restrict__ in,
                                                   const float* __restrict__ W,
                                                   const float* __restrict__ bias,
                                                   const float* __restrict__ residual,
                                                   float* __restrict__ cr,
                                                   float* __restrict__ partials) {
    __shared__ float Is[64 * 68];
    __shared__ float Ws[64 * 68];
    __shared__ float r1[256], r2[256];
    int t = threadIdx.x, tx = t & 15, ty = t >> 4;
    int m0 = blockIdx.x * 64;
    float4 acc[4];
    #pragma unroll
    for (int i = 0; i < 4; ++i) acc[i] = make_float4(0.f, 0.f, 0.f, 0.f);
    for (int kk = 0; kk < 256; kk += 64) {
        if (kk) __syncthreads();
        #pragma unroll
        for (int i = 0; i < 4; ++i) {
            int f4 = t + i * 256;
            int row = f4 >> 4, col = (f4 & 15) * 4;
            *(float4*)&Is[row * 68 + col] =
                *(const float4*)&in[(size_t)(m0 + row) * 256 + kk + col];
            *(float4*)&Ws[row * 68 + col] =
                *(const float4*)&W[(size_t)(kk + row) * 64 + col];
        }
        __syncthreads();
        #pragma unroll 8
        for (int k4 = 0; k4 < 64; k4 += 4) {
            float4 A0 = *(const float4*)&Is[ty * 68 + k4];
            float4 A1 = *(const float4*)&Is[(ty + 16) * 68 + k4];
            float4 A2 = *(const float4*)&Is[(ty + 32) * 68 + k4];
            float4 A3 = *(const float4*)&Is[(ty + 48) * 68 + k4];
            float4 W0 = *(const float4*)&Ws[(k4 + 0) * 68 + 4 * tx];
            float4 W1 = *(const float4*)&Ws[(k4 + 1) * 68 + 4 * tx];
            float4 W2 = *(const float4*)&Ws[(k4 + 2) * 68 + 4 * tx];
            float4 W3 = *(const float4*)&Ws[(k4 + 3) * 68 + 4 * tx];
            fma4(acc[0], A0.x, W0); fma4(acc[0], A0.y, W1); fma4(acc[0], A0.z, W2); fma4(acc[0], A0.w, W3);
            fma4(acc[1], A1.x, W0); fma4(acc[1], A1.y, W1); fma4(acc[1], A1.z, W2); fma4(acc[1], A1.w, W3);
            fma4(acc[2], A2.x, W0); fma4(acc[2], A2.y, W1); fma4(acc[2], A2.z, W2); fma4(acc[2], A2.w, W3);
            fma4(acc[3], A3.x, W0); fma4(acc[3], A3.y, W1); fma4(acc[3], A3.z, W2); fma4(acc[3], A3.w, W3);
        }
    }
    float4 bi = *(const float4*)&bias[4 * tx];
    float s = 0.f, s2 = 0.f;
    #pragma unroll
    for (int i = 0; i < 4; ++i) {
        int r = m0 + ty + 16 * i;
        float4 rv = *(const float4*)&residual[(size_t)r * 64 + 4 * tx];
        float v0 = acc[i].x + bi.x + rv.x;
        float v1 = acc[i].y + bi.y + rv.y;
        float v2 = acc[i].z + bi.z + rv.z;
        float v3 = acc[i].w + bi.w + rv.w;
        *(float4*)&cr[(size_t)r * 64 + 4 * tx] = make_float4(v0, v1, v2, v3);
        s += v0 + v1 + v2 + v3;
        s2 += v0 * v0 + v1 * v1 + v2 * v2 + v3 * v3;
    }
    r1[t] = s; r2[t] = s2;
    __syncthreads();
    for (int off = 128; off > 0; off >>= 1) {
        if (t < off) { r1[t] += r1[t + off]; r2[t] += r2[t + off]; }
        __syncthreads();
    }
    if (t == 0) { partials[blockIdx.x] = r1[0]; partials[325 + blockIdx.x] = r2[0]; }
}

// ---------------------------------------------------------------------------
// K5: out = relu(ocw*norm(cr) + ocb) @ olw + olb, norm fused from partials
__global__ void k_out(const float* __restrict__ cr, const float* __restrict__ partials,
                      const float* __restrict__ ocw, const float* __restrict__ ocb,
                      const float* __restrict__ olw, const float* __restrict__ olb,
                      float* __restrict__ out) {
    __shared__ float s1[256], s2[256];
    int t = threadIdx.x;
    float a = 0.f, b2s = 0.f;
    for (int i = t; i < 325; i += 256) { a += partials[i]; b2s += partials[325 + i]; }
    s1[t] = a; s2[t] = b2s;
    __syncthreads();
    for (int off = 128; off > 0; off >>= 1) {
        if (t < off) { s1[t] += s1[t + off]; s2[t] += s2[t + off]; }
        __syncthreads();
    }
    const float inv = 1.f / (float)(M_ * H_);
    float mu  = s1[0] * inv;
    float var = s2[0] * inv - mu * mu;
    float rs  = rsqrtf(var + 1e-5f);

    int m = blockIdx.x * 256 + t;
    if (m >= M_) return;
    int b = m / N_, n = m % N_;
    float cw[P_], cb[P_], acc[P_];
    #pragma unroll
    for (int p = 0; p < P_; ++p) { cw[p] = ocw[p]; cb[p] = ocb[p]; acc[p] = 0.f; }
    const float* lr = cr + (size_t)m * H_;
    for (int h = 0; h < H_; ++h) {
        float lv = (lr[h] - mu) * rs;
        float wv = olw[h];
        #pragma unroll
        for (int p = 0; p < P_; ++p) {
            float u = cw[p] * lv + cb[p];
            u = u > 0.f ? u : 0.f;
            acc[p] += u * wv;
        }
    }
    float ob = olb[0];
    #pragma unroll
    for (int p = 0; p < P_; ++p)
        out[(size_t)(b * P_ + p) * N_ + n] = acc[p] + ob;
}

// ---------------------------------------------------------------------------
extern "C" void kernel_launch(void* const* d_in, const int* in_sizes, int n_in,
                              void* d_out, int out_size, void* d_ws, size_t ws_size,
                              hipStream_t stream) {
    const float* inp      = (const float*)d_in[0];
    const float* adj_fwd  = (const float*)d_in[1];
    const float* pea_fwd  = (const float*)d_in[3];
    const float* w_in     = (const float*)d_in[5];
    const float* b_in     = (const float*)d_in[6];
    const float* res_w    = (const float*)d_in[7];
    const float* res_b    = (const float*)d_in[8];
    const float* gconv_w  = (const float*)d_in[9];
    const float* gconv_b  = (const float*)d_in[10];
    const float* gate1_w  = (const float*)d_in[11];
    const float* gate1_b  = (const float*)d_in[12];
    const float* gate2_w  = (const float*)d_in[13];
    const float* gate2_b  = (const float*)d_in[14];
    const float* reduce_w = (const float*)d_in[15];
    const float* reduce_b = (const float*)d_in[16];
    const float* gadj_w   = (const float*)d_in[17];
    const float* gadj_b   = (const float*)d_in[18];
    const float* gpea_w   = (const float*)d_in[19];
    const float* gpea_b   = (const float*)d_in[20];
    const float* ocw      = (const float*)d_in[21];
    const float* ocb      = (const float*)d_in[22];
    const float* olw      = (const float*)d_in[23];
    const float* olb      = (const float*)d_in[24];
    float* out = (float*)d_out;

    // workspace layout — fp32 region then bf16 G1 buffers (~80 MB total)
    float* ws       = (float*)d_ws;
    float* g_init   = ws;                              // M*64
    float* gate     = g_init + (size_t)M_ * H_;        // M*256
    float* gr       = gate + (size_t)M_ * 256;         // M*256
    float* residual = gr + (size_t)M_ * 256;           // M*64
    float* cr       = residual + (size_t)M_ * H_;      // M*64
    float* partials = cr + (size_t)M_ * H_;            // 650
    int*   scnt  = (int*)(partials + 650);             // 2*325
    int*   scols = scnt + 2 * N_;                      // 2*325*64
    float* svals = (float*)(scols + 2 * N_ * NNZCAP);  // 2*325*64
    ushort* G1a  = (ushort*)(svals + 2 * N_ * NNZCAP); // M*256 bf16
    ushort* G1p  = G1a + (size_t)M_ * 256;             // M*256 bf16

    k_build_sparse<<<N_, 64, 0, stream>>>(adj_fwd, scnt,      scols,              svals);
    k_build_sparse<<<N_, 64, 0, stream>>>(pea_fwd, scnt + N_, scols + N_*NNZCAP,  svals + N_*NNZCAP);

    for (int it = 0; it < KCP; ++it) {
        k_gate<<<M_ / 64, 256, 0, stream>>>(
            inp, w_in, b_in, gconv_w, gconv_b, res_w, res_b, cr, partials, it,
            gate1_w, gate1_b, gate2_w, gate2_b, residual, g_init, gate);
        k_layer1<<<656, 256, 0, stream>>>(
            scnt, scols, svals, g_init, gadj_w, gadj_b, gpea_w, gpea_b, G1a, G1p);
        k_mix<<<656, 256, 0, stream>>>(
            scnt, scols, svals, G1a, G1p, gadj_w, gadj_b, gpea_w, gpea_b, gate, gr);
        k_reduce<<<M_ / 64, 256, 0, stream>>>(gr, reduce_w, reduce_b, residual, cr, partials);
    }

    k_out<<<(M_ + 255) / 256, 256, 0, stream>>>(cr, partials, ocw, ocb, olw, olb, out);
}

// Round 11
// 783.555 us; speedup vs baseline: 1.8820x; 1.0417x over previous
//
#include <hip/hip_runtime.h>
#include <hip/hip_bf16.h>
#include <math.h>

// Problem constants
#define B_    64
#define T_    13
#define N_    325
#define H_    64
#define C_    4
#define L_    2
#define S_    4
#define P_    12
#define KCP   4            // checkpoints [4,7,10,13]
#define M_    (B_*N_)      // 20800 (= 650*32 exactly)
#define ADJLD 1300         // leading dim of combined adjacency inputs
#define NNZCAP 64          // max nonzeros per adjacency row (3% density -> mean ~10)

#define FMA16 \
  acc[0][0]+=a0*b0; acc[0][1]+=a0*b1; acc[0][2]+=a0*b2; acc[0][3]+=a0*b3; \
  acc[1][0]+=a1*b0; acc[1][1]+=a1*b1; acc[1][2]+=a1*b2; acc[1][3]+=a1*b3; \
  acc[2][0]+=a2*b0; acc[2][1]+=a2*b1; acc[2][2]+=a2*b2; acc[2][3]+=a2*b3; \
  acc[3][0]+=a3*b0; acc[3][1]+=a3*b1; acc[3][2]+=a3*b2; acc[3][3]+=a3*b3;

__device__ __forceinline__ void fma4(float4& a, float s, float4 x) {
    a.x += s * x.x; a.y += s * x.y; a.z += s * x.z; a.w += s * x.w;
}
// bf16x4 pack (RNE) / unpack
__device__ __forceinline__ uint2 pack_bf4(float4 v) {
    unsigned a = __float_as_uint(v.x), b = __float_as_uint(v.y);
    unsigned c = __float_as_uint(v.z), d = __float_as_uint(v.w);
    a = (a + 0x7fffu + ((a >> 16) & 1u)) >> 16;
    b = (b + 0x7fffu + ((b >> 16) & 1u)) >> 16;
    c = (c + 0x7fffu + ((c >> 16) & 1u)) >> 16;
    d = (d + 0x7fffu + ((d >> 16) & 1u)) >> 16;
    return make_uint2(a | (b << 16), c | (d << 16));
}
__device__ __forceinline__ float4 unpack_bf4(uint2 p) {
    return make_float4(__uint_as_float(p.x << 16),
                       __uint_as_float(p.x & 0xffff0000u),
                       __uint_as_float(p.y << 16),
                       __uint_as_float(p.y & 0xffff0000u));
}

// ---------------------------------------------------------------------------
// Build padded sparse rows (column-ordered, deterministic). One wave per row.
__global__ void k_build_sparse(const float* __restrict__ A,
                               int* __restrict__ cnt, int* __restrict__ cols,
                               float* __restrict__ vals) {
    int n    = blockIdx.x;
    int lane = threadIdx.x;
    const float* row = A + (size_t)n * ADJLD;
    int c = 0;
    for (int c0 = 0; c0 < 384; c0 += 64) {
        int col = c0 + lane;
        float v = (col < N_) ? row[col] : 0.f;
        unsigned long long m = __ballot(v != 0.f);
        int idx = c + __popcll(m & ((1ull << lane) - 1ull));
        if (v != 0.f && idx < NNZCAP) {
            cols[n * NNZCAP + idx] = col;
            vals[n * NNZCAP + idx] = v;
        }
        c += __popcll(m);
    }
    if (c + lane < NNZCAP) {                 // zero-pad tail -> branch-free consumers
        cols[n * NNZCAP + c + lane] = 0;
        vals[n * NNZCAP + c + lane] = 0.f;
    }
    if (lane == 0) cnt[n] = (c < NNZCAP) ? c : NNZCAP;
}

// ---------------------------------------------------------------------------
// K1: fused [norm of prev cr] + gf/residual/g_init + 2-layer gate MLP.
__global__ __launch_bounds__(256, 3) void k_gate(
    const float* __restrict__ inp,
    const float* __restrict__ w_in, const float* __restrict__ b_in,
    const float* __restrict__ gconv_w, const float* __restrict__ gconv_b,
    const float* __restrict__ res_w,   const float* __restrict__ res_b,
    const float* __restrict__ cr, const float* __restrict__ partials, int it,
    const float* __restrict__ W1, const float* __restrict__ b1,
    const float* __restrict__ W2, const float* __restrict__ b2,
    float* __restrict__ residual, float* __restrict__ g_init,
    float* __restrict__ gate)
{
    __shared__ float Gf[64 * 68];
    __shared__ float Ws[64 * 68];
    __shared__ float Gr[64 * 68];
    int t = threadIdx.x, lane = t & 63, w = t >> 6;
    int m0 = blockIdx.x * 64;

    // ---- phase -1: LayerNorm constants from partials (it>0, 650 blocks) ----
    float mu = 0.f, rs = 0.f;
    if (it > 0) {
        float a = 0.f, b = 0.f;
        for (int i = t; i < 650; i += 256) { a += partials[i]; b += partials[650 + i]; }
        Ws[t] = a; Ws[256 + t] = b;
        __syncthreads();
        for (int off = 128; off > 0; off >>= 1) {
            if (t < off) { Ws[t] += Ws[t + off]; Ws[256 + t] += Ws[256 + t + off]; }
            __syncthreads();
        }
        const float inv = 1.f / (float)(M_ * H_);
        mu = Ws[0] * inv;
        float var = Ws[256] * inv - mu * mu;
        rs = rsqrtf(var + 1e-5f);
        __syncthreads();   // reduction reads done before W1 staging overwrites Ws
    }

    // ---- phase 0: gf / residual / g_init ----
    {
        float wa = w_in[lane], wb = w_in[H_ + lane], bi = b_in[lane];
        float gw0 = gconv_w[0], gw1 = gconv_w[1], gw2 = gconv_w[2], gw3 = gconv_w[3];
        float rw0 = res_w[0],   rw1 = res_w[1],   rw2 = res_w[2],   rw3 = res_w[3];
        float gb = gconv_b[0],  rb = res_b[0];
        int left = (it == 0) ? 0 : (3 * it + 1);
        for (int i = 0; i < 16; ++i) {
            int r = i * 4 + w;                  // wave-uniform row
            int m = m0 + r;
            int b = m / N_, n = m % N_;
            const float* ipb = inp + ((size_t)b * T_ * N_ + n) * 2;
            float v0;
            if (it > 0) v0 = (cr[(size_t)m * H_ + lane] - mu) * rs;
            else        { v0 = ipb[0] * wa + ipb[1] * wb + bi; }
            int t1 = (it == 0) ? 1 : left;
            const float* ip1 = ipb + (size_t)t1 * N_ * 2;
            const float* ip2 = ip1 + (size_t)N_ * 2;
            const float* ip3 = ip2 + (size_t)N_ * 2;
            float v1 = ip1[0] * wa + ip1[1] * wb + bi;
            float v2 = ip2[0] * wa + ip2[1] * wb + bi;
            float v3 = ip3[0] * wa + ip3[1] * wb + bi;
            Gf[r * 68 + lane] = gb + gw0 * v0 + gw1 * v1 + gw2 * v2 + gw3 * v3;
            residual[(size_t)m * H_ + lane] = rb + rw0 * v0 + rw1 * v1 + rw2 * v2 + rw3 * v3;
            g_init[(size_t)m * H_ + lane] = v3;
        }
    }
    // stage W1
    #pragma unroll
    for (int i = 0; i < 4; ++i) {
        int f4 = t + i * 256;
        int row = f4 >> 4, col = (f4 & 15) * 4;
        *(float4*)&Ws[row * 68 + col] = *(const float4*)&W1[row * 64 + col];
    }
    __syncthreads();

    int tx = t & 15, ty = t >> 4;
    float acc[4][4];
    #pragma unroll
    for (int i = 0; i < 4; ++i)
        #pragma unroll
        for (int j = 0; j < 4; ++j) acc[i][j] = 0.f;
    #pragma unroll 16
    for (int k = 0; k < 64; ++k) {
        float a0 = Gf[ty * 68 + k];
        float a1 = Gf[(ty + 16) * 68 + k];
        float a2 = Gf[(ty + 32) * 68 + k];
        float a3 = Gf[(ty + 48) * 68 + k];
        float4 wv = *(const float4*)&Ws[k * 68 + 4 * tx];
        float b0 = wv.x, b1v = wv.y, b2v = wv.z, b3 = wv.w;
        { float b1 = b1v, b2 = b2v; FMA16 }
    }
    float4 bi1 = *(const float4*)&b1[4 * tx];
    #pragma unroll
    for (int i = 0; i < 4; ++i) {
        float v0 = acc[i][0] + bi1.x; v0 = v0 > 0.f ? v0 : 0.f;
        float v1 = acc[i][1] + bi1.y; v1 = v1 > 0.f ? v1 : 0.f;
        float v2 = acc[i][2] + bi1.z; v2 = v2 > 0.f ? v2 : 0.f;
        float v3 = acc[i][3] + bi1.w; v3 = v3 > 0.f ? v3 : 0.f;
        *(float4*)&Gr[(ty + 16 * i) * 68 + 4 * tx] = make_float4(v0, v1, v2, v3);
    }
    for (int ch = 0; ch < 4; ++ch) {
        __syncthreads();
        #pragma unroll
        for (int i = 0; i < 4; ++i) {
            int f4 = t + i * 256;
            int row = f4 >> 4, col = (f4 & 15) * 4;
            *(float4*)&Ws[row * 68 + col] =
                *(const float4*)&W2[(size_t)row * 256 + ch * 64 + col];
        }
        __syncthreads();
        float acc2[4][4];
        #pragma unroll
        for (int i = 0; i < 4; ++i)
            #pragma unroll
            for (int j = 0; j < 4; ++j) acc2[i][j] = 0.f;
        #pragma unroll 16
        for (int k = 0; k < 64; ++k) {
            float a0 = Gr[ty * 68 + k];
            float a1 = Gr[(ty + 16) * 68 + k];
            float a2 = Gr[(ty + 32) * 68 + k];
            float a3 = Gr[(ty + 48) * 68 + k];
            float4 wv = *(const float4*)&Ws[k * 68 + 4 * tx];
            float b0 = wv.x, b1v = wv.y, b2v = wv.z, b3 = wv.w;
            { float b1 = b1v, b2 = b2v; float (*acc)[4] = acc2; FMA16 }
        }
        float4 bi2 = *(const float4*)&b2[ch * 64 + 4 * tx];
        #pragma unroll
        for (int i = 0; i < 4; ++i) {
            int m = m0 + ty + 16 * i;
            float g0 = 1.f / (1.f + expf(-(acc2[i][0] + bi2.x)));
            float g1 = 1.f / (1.f + expf(-(acc2[i][1] + bi2.y)));
            float g2 = 1.f / (1.f + expf(-(acc2[i][2] + bi2.z)));
            float g3 = 1.f / (1.f + expf(-(acc2[i][3] + bi2.w)));
            *(float4*)&gate[(size_t)m * 256 + ch * 64 + 4 * tx] = make_float4(g0, g1, g2, g3);
        }
    }
}

// ---------------------------------------------------------------------------
// K2: layer 1, both stacks; G1 output packed to bf16 (halves k_mix gather lines).
__global__ __launch_bounds__(256, 4) void k_layer1(
    const int*   __restrict__ cnt,    // [2N]  adj rows 0..N, pea rows N..2N
    const int*   __restrict__ cols,   // [2N][NNZCAP]
    const float* __restrict__ vals,
    const float* __restrict__ g_init, // [M][64]
    const float* __restrict__ wadj, const float* __restrict__ badj,
    const float* __restrict__ wpea, const float* __restrict__ bpea,
    ushort* __restrict__ G1a, ushort* __restrict__ G1p)   // [M][256] bf16
{
    __shared__ float Ma[32 * 68];
    __shared__ float Mp[32 * 68];
    __shared__ float Ws[64 * 68];
    int t = threadIdx.x, lane = t & 63, w = t >> 6;
    int vb = (blockIdx.x & 7) * 82 + (blockIdx.x >> 3);   // XCD swizzle
    if (vb >= 650) return;
    int m0 = vb * 32;

    // ---- gather: lane=(rr,cl); rows w*8+rr and w*8+4+rr, both stacks ----
    {
        int cl = lane & 15, rr = lane >> 4;
        int mA = m0 + w * 8 + rr;
        int mB = mA + 4;
        int nA = mA % N_, nB = mB % N_;
        const float* gA = g_init + (size_t)(mA - nA) * H_ + cl * 4;
        const float* gB = g_init + (size_t)(mB - nB) * H_ + cl * 4;
        const int   *cA0 = cols + nA * NNZCAP,        *cB0 = cols + nB * NNZCAP;
        const float *vA0 = vals + nA * NNZCAP,        *vB0 = vals + nB * NNZCAP;
        const int   *cA1 = cols + (N_ + nA) * NNZCAP, *cB1 = cols + (N_ + nB) * NNZCAP;
        const float *vA1 = vals + (N_ + nA) * NNZCAP, *vB1 = vals + (N_ + nB) * NNZCAP;
        int jm = max(max(cnt[nA], cnt[nB]), max(cnt[N_ + nA], cnt[N_ + nB]));
        float4 aA0 = make_float4(0.f,0.f,0.f,0.f), aB0 = make_float4(0.f,0.f,0.f,0.f);
        float4 aA1 = make_float4(0.f,0.f,0.f,0.f), aB1 = make_float4(0.f,0.f,0.f,0.f);
        for (int j = 0; j < jm; j += 2) {     // zero-padded -> branch-free
            fma4(aA0, vA0[j],   *(const float4*)&gA[cA0[j]   * H_]);
            fma4(aA0, vA0[j+1], *(const float4*)&gA[cA0[j+1] * H_]);
            fma4(aB0, vB0[j],   *(const float4*)&gB[cB0[j]   * H_]);
            fma4(aB0, vB0[j+1], *(const float4*)&gB[cB0[j+1] * H_]);
            fma4(aA1, vA1[j],   *(const float4*)&gA[cA1[j]   * H_]);
            fma4(aA1, vA1[j+1], *(const float4*)&gA[cA1[j+1] * H_]);
            fma4(aB1, vB1[j],   *(const float4*)&gB[cB1[j]   * H_]);
            fma4(aB1, vB1[j+1], *(const float4*)&gB[cB1[j+1] * H_]);
        }
        *(float4*)&Ma[(w * 8 + rr) * 68 + cl * 4]     = aA0;
        *(float4*)&Ma[(w * 8 + 4 + rr) * 68 + cl * 4] = aB0;
        *(float4*)&Mp[(w * 8 + rr) * 68 + cl * 4]     = aA1;
        *(float4*)&Mp[(w * 8 + 4 + rr) * 68 + cl * 4] = aB1;
    }

    int tx = t & 15, ty = t >> 4;
    for (int sc = 0; sc < 8; ++sc) {
        int stack = sc >> 2, c = sc & 3;
        const float* wb0 = (stack ? wpea : wadj) + (size_t)c * 16384;   // layer 0
        const float* wb1 = wb0 + 4096;
        __syncthreads();   // gather done (sc=0) / prev Ws reads done (sc>0)
        #pragma unroll
        for (int i = 0; i < 4; ++i) {
            int f4 = t + i * 256;
            int row = f4 >> 4, col = (f4 & 15) * 4;
            float4 x0 = *(const float4*)&wb0[row * 64 + col];
            float4 x1 = *(const float4*)&wb1[row * 64 + col];
            *(float4*)&Ws[row * 68 + col] = make_float4(x0.x + x1.x, x0.y + x1.y,
                                                        x0.z + x1.z, x0.w + x1.w);
        }
        __syncthreads();

        const float* Msrc = stack ? Mp : Ma;
        float4 acc0 = make_float4(0.f, 0.f, 0.f, 0.f);
        float4 acc1 = make_float4(0.f, 0.f, 0.f, 0.f);
        #pragma unroll 8
        for (int k4 = 0; k4 < 64; k4 += 4) {
            float4 A0 = *(const float4*)&Msrc[ty * 68 + k4];
            float4 A1 = *(const float4*)&Msrc[(ty + 16) * 68 + k4];
            float4 W0 = *(const float4*)&Ws[(k4 + 0) * 68 + 4 * tx];
            float4 W1 = *(const float4*)&Ws[(k4 + 1) * 68 + 4 * tx];
            float4 W2 = *(const float4*)&Ws[(k4 + 2) * 68 + 4 * tx];
            float4 W3 = *(const float4*)&Ws[(k4 + 3) * 68 + 4 * tx];
            fma4(acc0, A0.x, W0); fma4(acc0, A0.y, W1); fma4(acc0, A0.z, W2); fma4(acc0, A0.w, W3);
            fma4(acc1, A1.x, W0); fma4(acc1, A1.y, W1); fma4(acc1, A1.z, W2); fma4(acc1, A1.w, W3);
        }
        const float* bias = (stack ? bpea : badj) + c * L_ * H_;   // layer 0
        float4 bi = *(const float4*)&bias[4 * tx];
        ushort* Gout = stack ? G1p : G1a;
        #pragma unroll
        for (int r = 0; r < 2; ++r) {
            float4 a = r ? acc1 : acc0;
            float v0 = a.x + bi.x; v0 = v0 > 0.f ? v0 : 0.f;
            float v1 = a.y + bi.y; v1 = v1 > 0.f ? v1 : 0.f;
            float v2 = a.z + bi.z; v2 = v2 > 0.f ? v2 : 0.f;
            float v3 = a.w + bi.w; v3 = v3 > 0.f ? v3 : 0.f;
            *(uint2*)&Gout[(size_t)(m0 + ty + 16 * r) * 256 + c * 64 + 4 * tx] =
                pack_bf4(make_float4(v0, v1, v2, v3));
        }
    }
}

// ---------------------------------------------------------------------------
// K3: layer 2 + gate mix + reduce GEMM + partial sums, all fused.
// Mix result committed in-place into Mt's per-channel slice (each channel's
// GEMM is the only reader of its slice; existing barriers give ordering);
// then cr = Mt[32x256] @ reduce_w + bias + residual, with per-block sums.
__global__ __launch_bounds__(256, 3) void k_mix(
    const int*   __restrict__ cnt,
    const int*   __restrict__ cols,
    const float* __restrict__ vals,
    const ushort* __restrict__ G1a, const ushort* __restrict__ G1p,  // [M][256] bf16
    const float* __restrict__ wadj, const float* __restrict__ badj,
    const float* __restrict__ wpea, const float* __restrict__ bpea,
    const float* __restrict__ gate,     // [M][256]
    const float* __restrict__ reduce_w, // [256][64]
    const float* __restrict__ reduce_b, // [64]
    const float* __restrict__ residual, // [M][64]
    float* __restrict__ cr,             // [M][64]
    float* __restrict__ partials)       // [2*650]
{
    __shared__ float Mt[32 * 260];
    __shared__ float Ws[64 * 68];
    int t = threadIdx.x, lane = t & 63, w = t >> 6;
    int vb = (blockIdx.x & 7) * 82 + (blockIdx.x >> 3);   // XCD swizzle
    if (vb >= 650) return;
    int m0 = vb * 32;
    int tx = t & 15, ty = t >> 4;

    float4 res[4][2];   // gate*relu(adj) -> then full mix, carried in regs
    float4 gsv[4][2];   // saved gate

    // ======== stack A gather: 2 rows x unroll 2, bf16 unpack ========
    for (int pp = 0; pp < 8; pp += 2) {
        int ma = m0 + w * 8 + pp, mb = ma + 1;
        int na = ma % N_, nb = mb % N_;
        const ushort* ga = G1a + (size_t)(ma - na) * 256 + lane * 4;
        const ushort* gb = G1a + (size_t)(mb - nb) * 256 + lane * 4;
        const int   *cap = cols + na * NNZCAP, *cbp = cols + nb * NNZCAP;
        const float *vap = vals + na * NNZCAP, *vbp = vals + nb * NNZCAP;
        int jm = max(cnt[na], cnt[nb]);
        float4 a0 = make_float4(0.f,0.f,0.f,0.f), a1 = make_float4(0.f,0.f,0.f,0.f);
        for (int j = 0; j < jm; j += 2) {     // zero-padded -> branch-free
            float w00 = vap[j], w01 = vap[j+1];
            float w10 = vbp[j], w11 = vbp[j+1];
            float4 x00 = unpack_bf4(*(const uint2*)&ga[cap[j]   * 256]);
            float4 x01 = unpack_bf4(*(const uint2*)&ga[cap[j+1] * 256]);
            float4 x10 = unpack_bf4(*(const uint2*)&gb[cbp[j]   * 256]);
            float4 x11 = unpack_bf4(*(const uint2*)&gb[cbp[j+1] * 256]);
            fma4(a0, w00, x00); fma4(a0, w01, x01);
            fma4(a1, w10, x10); fma4(a1, w11, x11);
        }
        *(float4*)&Mt[(w * 8 + pp) * 260 + lane * 4]     = a0;
        *(float4*)&Mt[(w * 8 + pp + 1) * 260 + lane * 4] = a1;
    }

    #pragma unroll
    for (int c = 0; c < 4; ++c) {
        __syncthreads();
        const float* w0 = wadj + (size_t)c * 16384 + 8192;   // layer 1
        const float* w1 = w0 + 4096;
        #pragma unroll
        for (int i = 0; i < 4; ++i) {
            int f4 = t + i * 256;
            int row = f4 >> 4, col = (f4 & 15) * 4;
            float4 x0 = *(const float4*)&w0[row * 64 + col];
            float4 x1 = *(const float4*)&w1[row * 64 + col];
            *(float4*)&Ws[row * 68 + col] = make_float4(x0.x + x1.x, x0.y + x1.y,
                                                        x0.z + x1.z, x0.w + x1.w);
        }
        __syncthreads();
        float4 acc0 = make_float4(0.f,0.f,0.f,0.f), acc1 = make_float4(0.f,0.f,0.f,0.f);
        #pragma unroll 8
        for (int k4 = 0; k4 < 64; k4 += 4) {
            float4 A0 = *(const float4*)&Mt[ty * 260 + c * 64 + k4];
            float4 A1 = *(const float4*)&Mt[(ty + 16) * 260 + c * 64 + k4];
            float4 W0 = *(const float4*)&Ws[(k4 + 0) * 68 + 4 * tx];
            float4 W1 = *(const float4*)&Ws[(k4 + 1) * 68 + 4 * tx];
            float4 W2 = *(const float4*)&Ws[(k4 + 2) * 68 + 4 * tx];
            float4 W3 = *(const float4*)&Ws[(k4 + 3) * 68 + 4 * tx];
            fma4(acc0, A0.x, W0); fma4(acc0, A0.y, W1); fma4(acc0, A0.z, W2); fma4(acc0, A0.w, W3);
            fma4(acc1, A1.x, W0); fma4(acc1, A1.y, W1); fma4(acc1, A1.z, W2); fma4(acc1, A1.w, W3);
        }
        float4 bA = *(const float4*)&badj[(c * L_ + 1) * H_ + 4 * tx];
        #pragma unroll
        for (int r = 0; r < 2; ++r) {
            float4 a = r ? acc1 : acc0;
            float v0 = a.x + bA.x; v0 = v0 > 0.f ? v0 : 0.f;
            float v1 = a.y + bA.y; v1 = v1 > 0.f ? v1 : 0.f;
            float v2 = a.z + bA.z; v2 = v2 > 0.f ? v2 : 0.f;
            float v3 = a.w + bA.w; v3 = v3 > 0.f ? v3 : 0.f;
            size_t o = (size_t)(m0 + ty + 16 * r) * 256 + c * 64 + 4 * tx;
            float4 g = *(const float4*)&gate[o];
            gsv[c][r] = g;
            res[c][r] = make_float4(g.x * v0, g.y * v1, g.z * v2, g.w * v3);
        }
    }

    // ======== stack P: re-gather, mix into registers, commit to Mt ========
    __syncthreads();   // all Mt reads done before overwrite
    for (int pp = 0; pp < 8; pp += 2) {
        int ma = m0 + w * 8 + pp, mb = ma + 1;
        int na = ma % N_, nb = mb % N_;
        const ushort* ga = G1p + (size_t)(ma - na) * 256 + lane * 4;
        const ushort* gb = G1p + (size_t)(mb - nb) * 256 + lane * 4;
        const int   *cap = cols + (N_ + na) * NNZCAP, *cbp = cols + (N_ + nb) * NNZCAP;
        const float *vap = vals + (N_ + na) * NNZCAP, *vbp = vals + (N_ + nb) * NNZCAP;
        int jm = max(cnt[N_ + na], cnt[N_ + nb]);
        float4 a0 = make_float4(0.f,0.f,0.f,0.f), a1 = make_float4(0.f,0.f,0.f,0.f);
        for (int j = 0; j < jm; j += 2) {
            float w00 = vap[j], w01 = vap[j+1];
            float w10 = vbp[j], w11 = vbp[j+1];
            float4 x00 = unpack_bf4(*(const uint2*)&ga[cap[j]   * 256]);
            float4 x01 = unpack_bf4(*(const uint2*)&ga[cap[j+1] * 256]);
            float4 x10 = unpack_bf4(*(const uint2*)&gb[cbp[j]   * 256]);
            float4 x11 = unpack_bf4(*(const uint2*)&gb[cbp[j+1] * 256]);
            fma4(a0, w00, x00); fma4(a0, w01, x01);
            fma4(a1, w10, x10); fma4(a1, w11, x11);
        }
        *(float4*)&Mt[(w * 8 + pp) * 260 + lane * 4]     = a0;
        *(float4*)&Mt[(w * 8 + pp + 1) * 260 + lane * 4] = a1;
    }

    #pragma unroll
    for (int c = 0; c < 4; ++c) {
        __syncthreads();   // prev GEMM's slice reads done -> safe to commit c-1
        if (c > 0) {
            *(float4*)&Mt[ty * 260 + (c - 1) * 64 + 4 * tx]        = res[c - 1][0];
            *(float4*)&Mt[(ty + 16) * 260 + (c - 1) * 64 + 4 * tx] = res[c - 1][1];
        }
        const float* w0 = wpea + (size_t)c * 16384 + 8192;   // layer 1
        const float* w1 = w0 + 4096;
        #pragma unroll
        for (int i = 0; i < 4; ++i) {
            int f4 = t + i * 256;
            int row = f4 >> 4, col = (f4 & 15) * 4;
            float4 x0 = *(const float4*)&w0[row * 64 + col];
            float4 x1 = *(const float4*)&w1[row * 64 + col];
            *(float4*)&Ws[row * 68 + col] = make_float4(x0.x + x1.x, x0.y + x1.y,
                                                        x0.z + x1.z, x0.w + x1.w);
        }
        __syncthreads();
        float4 acc0 = make_float4(0.f,0.f,0.f,0.f), acc1 = make_float4(0.f,0.f,0.f,0.f);
        #pragma unroll 8
        for (int k4 = 0; k4 < 64; k4 += 4) {
            float4 A0 = *(const float4*)&Mt[ty * 260 + c * 64 + k4];
            float4 A1 = *(const float4*)&Mt[(ty + 16) * 260 + c * 64 + k4];
            float4 W0 = *(const float4*)&Ws[(k4 + 0) * 68 + 4 * tx];
            float4 W1 = *(const float4*)&Ws[(k4 + 1) * 68 + 4 * tx];
            float4 W2 = *(const float4*)&Ws[(k4 + 2) * 68 + 4 * tx];
            float4 W3 = *(const float4*)&Ws[(k4 + 3) * 68 + 4 * tx];
            fma4(acc0, A0.x, W0); fma4(acc0, A0.y, W1); fma4(acc0, A0.z, W2); fma4(acc0, A0.w, W3);
            fma4(acc1, A1.x, W0); fma4(acc1, A1.y, W1); fma4(acc1, A1.z, W2); fma4(acc1, A1.w, W3);
        }
        float4 bP = *(const float4*)&bpea[(c * L_ + 1) * H_ + 4 * tx];
        #pragma unroll
        for (int r = 0; r < 2; ++r) {
            float4 p = r ? acc1 : acc0;
            float v0 = p.x + bP.x; v0 = v0 > 0.f ? v0 : 0.f;
            float v1 = p.y + bP.y; v1 = v1 > 0.f ? v1 : 0.f;
            float v2 = p.z + bP.z; v2 = v2 > 0.f ? v2 : 0.f;
            float v3 = p.w + bP.w; v3 = v3 > 0.f ? v3 : 0.f;
            float4 g  = gsv[c][r];
            float4 rr = res[c][r];
            res[c][r] = make_float4(rr.x + (1.f - g.x) * v0,
                                    rr.y + (1.f - g.y) * v1,
                                    rr.z + (1.f - g.z) * v2,
                                    rr.w + (1.f - g.w) * v3);
        }
    }
    __syncthreads();   // last GEMM's slice-3 reads done
    *(float4*)&Mt[ty * 260 + 3 * 64 + 4 * tx]        = res[3][0];
    *(float4*)&Mt[(ty + 16) * 260 + 3 * 64 + 4 * tx] = res[3][1];

    // ======== reduce GEMM: cr = Mt[32x256] @ reduce_w + bias + residual ======
    float4 racc0 = make_float4(0.f,0.f,0.f,0.f), racc1 = make_float4(0.f,0.f,0.f,0.f);
    for (int kk = 0; kk < 4; ++kk) {
        __syncthreads();   // Mt commits visible (kk=0) / prev Ws reads done
        #pragma unroll
        for (int i = 0; i < 4; ++i) {
            int f4 = t + i * 256;
            int row = f4 >> 4, col = (f4 & 15) * 4;
            *(float4*)&Ws[row * 68 + col] =
                *(const float4*)&reduce_w[(size_t)(kk * 64 + row) * 64 + col];
        }
        __syncthreads();
        #pragma unroll 8
        for (int k4 = 0; k4 < 64; k4 += 4) {
            float4 A0 = *(const float4*)&Mt[ty * 260 + kk * 64 + k4];
            float4 A1 = *(const float4*)&Mt[(ty + 16) * 260 + kk * 64 + k4];
            float4 W0 = *(const float4*)&Ws[(k4 + 0) * 68 + 4 * tx];
            float4 W1 = *(const float4*)&Ws[(k4 + 1) * 68 + 4 * tx];
            float4 W2 = *(const float4*)&Ws[(k4 + 2) * 68 + 4 * tx];
            float4 W3 = *(const float4*)&Ws[(k4 + 3) * 68 + 4 * tx];
            fma4(racc0, A0.x, W0); fma4(racc0, A0.y, W1); fma4(racc0, A0.z, W2); fma4(racc0, A0.w, W3);
            fma4(racc1, A1.x, W0); fma4(racc1, A1.y, W1); fma4(racc1, A1.z, W2); fma4(racc1, A1.w, W3);
        }
    }
    float4 bi = *(const float4*)&reduce_b[4 * tx];
    float s = 0.f, s2 = 0.f;
    #pragma unroll
    for (int r = 0; r < 2; ++r) {
        int m = m0 + ty + 16 * r;
        float4 a = r ? racc1 : racc0;
        float4 rv = *(const float4*)&residual[(size_t)m * 64 + 4 * tx];
        float v0 = a.x + bi.x + rv.x;
        float v1 = a.y + bi.y + rv.y;
        float v2 = a.z + bi.z + rv.z;
        float v3 = a.w + bi.w + rv.w;
        *(float4*)&cr[(size_t)m * 64 + 4 * tx] = make_float4(v0, v1, v2, v3);
        s += v0 + v1 + v2 + v3;
        s2 += v0 * v0 + v1 * v1 + v2 * v2 + v3 * v3;
    }
    __syncthreads();   // Ws reads done; reuse as reduction scratch
    float* r1 = Ws;
    float* r2 = Ws + 256;
    r1[t] = s; r2[t] = s2;
    __syncthreads();
    for (int off = 128; off > 0; off >>= 1) {
        if (t < off) { r1[t] += r1[t + off]; r2[t] += r2[t + off]; }
        __syncthreads();
    }
    if (t == 0) { partials[vb] = r1[0]; partials[650 + vb] = r2[0]; }
}

// ---------------------------------------------------------------------------
// K5: out = relu(ocw*norm(cr) + ocb) @ olw + olb, norm fused from partials
__global__ void k_out(const float* __restrict__ cr, const float* __restrict__ partials,
                      const float* __restrict__ ocw, const float* __restrict__ ocb,
                      const float* __restrict__ olw, const float* __restrict__ olb,
                      float* __restrict__ out) {
    __shared__ float s1[256], s2[256];
    int t = threadIdx.x;
    float a = 0.f, b2s = 0.f;
    for (int i = t; i < 650; i += 256) { a += partials[i]; b2s += partials[650 + i]; }
    s1[t] = a; s2[t] = b2s;
    __syncthreads();
    for (int off = 128; off > 0; off >>= 1) {
        if (t < off) { s1[t] += s1[t + off]; s2[t] += s2[t + off]; }
        __syncthreads();
    }
    const float inv = 1.f / (float)(M_ * H_);
    float mu  = s1[0] * inv;
    float var = s2[0] * inv - mu * mu;
    float rs  = rsqrtf(var + 1e-5f);

    int m = blockIdx.x * 256 + t;
    if (m >= M_) return;
    int b = m / N_, n = m % N_;
    float cw[P_], cb[P_], acc[P_];
    #pragma unroll
    for (int p = 0; p < P_; ++p) { cw[p] = ocw[p]; cb[p] = ocb[p]; acc[p] = 0.f; }
    const float* lr = cr + (size_t)m * H_;
    for (int h = 0; h < H_; ++h) {
        float lv = (lr[h] - mu) * rs;
        float wv = olw[h];
        #pragma unroll
        for (int p = 0; p < P_; ++p) {
            float u = cw[p] * lv + cb[p];
            u = u > 0.f ? u : 0.f;
            acc[p] += u * wv;
        }
    }
    float ob = olb[0];
    #pragma unroll
    for (int p = 0; p < P_; ++p)
        out[(size_t)(b * P_ + p) * N_ + n] = acc[p] + ob;
}

// ---------------------------------------------------------------------------
extern "C" void kernel_launch(void* const* d_in, const int* in_sizes, int n_in,
                              void* d_out, int out_size, void* d_ws, size_t ws_size,
                              hipStream_t stream) {
    const float* inp      = (const float*)d_in[0];
    const float* adj_fwd  = (const float*)d_in[1];
    const float* pea_fwd  = (const float*)d_in[3];
    const float* w_in     = (const float*)d_in[5];
    const float* b_in     = (const float*)d_in[6];
    const float* res_w    = (const float*)d_in[7];
    const float* res_b    = (const float*)d_in[8];
    const float* gconv_w  = (const float*)d_in[9];
    const float* gconv_b  = (const float*)d_in[10];
    const float* gate1_w  = (const float*)d_in[11];
    const float* gate1_b  = (const float*)d_in[12];
    const float* gate2_w  = (const float*)d_in[13];
    const float* gate2_b  = (const float*)d_in[14];
    const float* reduce_w = (const float*)d_in[15];
    const float* reduce_b = (const float*)d_in[16];
    const float* gadj_w   = (const float*)d_in[17];
    const float* gadj_b   = (const float*)d_in[18];
    const float* gpea_w   = (const float*)d_in[19];
    const float* gpea_b   = (const float*)d_in[20];
    const float* ocw      = (const float*)d_in[21];
    const float* ocb      = (const float*)d_in[22];
    const float* olw      = (const float*)d_in[23];
    const float* olb      = (const float*)d_in[24];
    float* out = (float*)d_out;

    // workspace layout — fp32 region then bf16 G1 buffers (~60 MB total)
    float* ws       = (float*)d_ws;
    float* g_init   = ws;                              // M*64
    float* gate     = g_init + (size_t)M_ * H_;        // M*256
    float* residual = gate + (size_t)M_ * 256;         // M*64
    float* cr       = residual + (size_t)M_ * H_;      // M*64
    float* partials = cr + (size_t)M_ * H_;            // 1300
    int*   scnt  = (int*)(partials + 1300);            // 2*325
    int*   scols = scnt + 2 * N_;                      // 2*325*64
    float* svals = (float*)(scols + 2 * N_ * NNZCAP);  // 2*325*64
    ushort* G1a  = (ushort*)(svals + 2 * N_ * NNZCAP); // M*256 bf16
    ushort* G1p  = G1a + (size_t)M_ * 256;             // M*256 bf16

    k_build_sparse<<<N_, 64, 0, stream>>>(adj_fwd, scnt,      scols,              svals);
    k_build_sparse<<<N_, 64, 0, stream>>>(pea_fwd, scnt + N_, scols + N_*NNZCAP,  svals + N_*NNZCAP);

    for (int it = 0; it < KCP; ++it) {
        k_gate<<<M_ / 64, 256, 0, stream>>>(
            inp, w_in, b_in, gconv_w, gconv_b, res_w, res_b, cr, partials, it,
            gate1_w, gate1_b, gate2_w, gate2_b, residual, g_init, gate);
        k_layer1<<<656, 256, 0, stream>>>(
            scnt, scols, svals, g_init, gadj_w, gadj_b, gpea_w, gpea_b, G1a, G1p);
        k_mix<<<656, 256, 0, stream>>>(
            scnt, scols, svals, G1a, G1p, gadj_w, gadj_b, gpea_w, gpea_b, gate,
            reduce_w, reduce_b, residual, cr, partials);
    }

    k_out<<<(M_ + 255) / 256, 256, 0, stream>>>(cr, partials, ocw, ocb, olw, olb, out);
}